// Round 6
// baseline (49116.052 us; speedup 1.0000x reference)
//
#include <hip/hip_runtime.h>
#include <hip/hip_bf16.h>

// ---------------------------------------------------------------------------
// Decoder_SICA — ROUND 5: naive literal translation, fp32 OUTPUT.
// fp32 inputs, fp32 intermediates in d_ws, fp32 stores to d_out.
//   einsum -> conv3x3(s1,p1) -> conv3x3(s2,p1) -> conv3x3(s1,p1)
//   -> conv5x5(valid)=dot -> linear
// ---------------------------------------------------------------------------

// out: (Bc, 384, 10, 10) fp32. channel = n*48+g*3+o ; pixel (h*5+p, w*5+q)
// out[b,ch,row,col] = sum_c A[b, n*64+g*4+c, h, w] * S[b, g*4+c, o, p, q]
__global__ void einsum_kernel(const float* __restrict__ A, const float* __restrict__ S,
                              float* __restrict__ out, int total)
{
    int idx = blockIdx.x * blockDim.x + threadIdx.x;
    if (idx >= total) return;
    int b  = idx / 38400;
    int r  = idx - b * 38400;
    int ch = r / 100;
    int px = r - ch * 100;
    int row = px / 10, col = px - row * 10;
    int h = row / 5, p = row - h * 5;
    int w = col / 5, q = col - w * 5;
    int n = ch / 48;
    int g = (ch / 3) % 16;
    int o = ch % 3;
    const float* Ab = A + (size_t)b * 2048 + (size_t)(n * 64 + g * 4) * 4 + h * 2 + w;
    const float* Sb = S + ((size_t)(b * 64 + g * 4) * 3 + o) * 25 + p * 5 + q;
    float s = 0.f;
    #pragma unroll
    for (int c = 0; c < 4; ++c)
        s += Ab[c * 4] * Sb[c * 75];
    out[idx] = s;
}

// Naive 3x3 conv, pad 1, stride ST, square images IHxIH -> OHxOH, bias+ReLU.
// One thread per output element. idx = ((b*OC+oc)*OH+oy)*OH+ox.
template<int IC, int OC, int IH, int OH, int ST>
__global__ void conv3x3_naive(const float* __restrict__ in, const float* __restrict__ wgt,
                              const float* __restrict__ bias, float* __restrict__ out,
                              int total)
{
    int idx = blockIdx.x * blockDim.x + threadIdx.x;
    if (idx >= total) return;
    int b  = idx / (OC * OH * OH);
    int r  = idx - b * (OC * OH * OH);
    int oc = r / (OH * OH);
    int p  = r - oc * (OH * OH);
    int oy = p / OH, ox = p - oy * OH;

    float acc = bias[oc];
    for (int ic = 0; ic < IC; ++ic) {
        const float* ip = in  + ((size_t)b * IC + ic) * (IH * IH);
        const float* wp = wgt + ((size_t)oc * IC + ic) * 9;
        #pragma unroll
        for (int ky = 0; ky < 3; ++ky) {
            int iy = oy * ST + ky - 1;
            if (iy < 0 || iy >= IH) continue;
            #pragma unroll
            for (int kx = 0; kx < 3; ++kx) {
                int ix = ox * ST + kx - 1;
                if (ix < 0 || ix >= IH) continue;
                acc += ip[iy * IH + ix] * wp[ky * 3 + kx];
            }
        }
    }
    out[idx] = acc > 0.f ? acc : 0.f;
}

// conv5x5 valid on 5x5 input: per-(b,oc) full dot over 512*25=12800.
__global__ void conv4_naive(const float* __restrict__ x, const float* __restrict__ W4,
                            const float* __restrict__ b4, float* __restrict__ out,
                            int total)
{
    int idx = blockIdx.x * blockDim.x + threadIdx.x;
    if (idx >= total) return;
    int b = idx / 512, oc = idx - b * 512;
    const float* xb = x  + (size_t)b  * 12800;
    const float* wp = W4 + (size_t)oc * 12800;
    float acc = b4[oc];
    for (int k = 0; k < 12800; ++k)
        acc += xb[k] * wp[k];
    out[idx] = acc > 0.f ? acc : 0.f;
}

// Final linear: fp32 in, fp32 OUT (reference output dtype is float32).
__global__ void linear_naive(const float* __restrict__ x, const float* __restrict__ Wl,
                             const float* __restrict__ bl,
                             float* __restrict__ out, int total)
{
    int idx = blockIdx.x * blockDim.x + threadIdx.x;
    if (idx >= total) return;
    int b = idx / 10, j = idx - b * 10;
    const float* xb = x  + (size_t)b * 512;
    const float* wj = Wl + (size_t)j * 512;
    float s = bl[j];
    for (int k = 0; k < 512; ++k)
        s += xb[k] * wj[k];
    out[idx] = s;
}

extern "C" void kernel_launch(void* const* d_in, const int* in_sizes, int n_in,
                              void* d_out, int out_size, void* d_ws, size_t ws_size,
                              hipStream_t stream)
{
    const float* A  = (const float*)d_in[0];
    const float* S  = (const float*)d_in[1];
    const float* W1 = (const float*)d_in[2];
    const float* b1 = (const float*)d_in[3];
    const float* W2 = (const float*)d_in[4];
    const float* b2 = (const float*)d_in[5];
    const float* W3 = (const float*)d_in[6];
    const float* b3 = (const float*)d_in[7];
    const float* W4 = (const float*)d_in[8];
    const float* b4 = (const float*)d_in[9];
    const float* Wl = (const float*)d_in[10];
    const float* bl = (const float*)d_in[11];
    float* outp = (float*)d_out;
    float* ws = (float*)d_ws;

    const int Btot = 512;
    // Two ping-pong fp32 regions of Bc*38400 floats each; never exceed ws_size.
    int Bc = 512;
    while (Bc > 8 && (size_t)Bc * 38400ull * 8ull > ws_size) Bc >>= 1;

    for (int b0 = 0; b0 < Btot; b0 += Bc) {
        float* x0 = ws;                            // (Bc,384,10,10)
        float* x1 = ws + (size_t)Bc * 38400;       // (Bc,384,10,10)
        float* x2 = ws;                            // (Bc,384,5,5)   overwrites dead x0
        float* x3 = ws + (size_t)Bc * 38400;       // (Bc,512,5,5)   overwrites dead x1
        float* x4 = ws;                            // (Bc,512)       overwrites dead x2

        int t0 = Bc * 38400;
        einsum_kernel<<<(t0 + 255) / 256, 256, 0, stream>>>(
            A + (size_t)b0 * 2048, S + (size_t)b0 * 4800, x0, t0);

        int t1 = Bc * 384 * 100;
        conv3x3_naive<384, 384, 10, 10, 1><<<(t1 + 255) / 256, 256, 0, stream>>>(
            x0, W1, b1, x1, t1);

        int t2 = Bc * 384 * 25;
        conv3x3_naive<384, 384, 10, 5, 2><<<(t2 + 255) / 256, 256, 0, stream>>>(
            x1, W2, b2, x2, t2);

        int t3 = Bc * 512 * 25;
        conv3x3_naive<384, 512, 5, 5, 1><<<(t3 + 255) / 256, 256, 0, stream>>>(
            x2, W3, b3, x3, t3);

        int t4 = Bc * 512;
        conv4_naive<<<(t4 + 255) / 256, 256, 0, stream>>>(x3, W4, b4, x4, t4);

        int t5 = Bc * 10;
        linear_naive<<<(t5 + 255) / 256, 256, 0, stream>>>(
            x4, Wl, bl, outp + (size_t)b0 * 10, t5);
    }
}

// Round 7
// 7340.982 us; speedup vs baseline: 6.6907x; 6.6907x over previous
//
#include <hip/hip_runtime.h>
#include <hip/hip_bf16.h>

// ---------------------------------------------------------------------------
// Decoder_SICA — ROUND 6: LDS-tiled fp32 convs (verified-baseline upgrade).
// fp32 inputs, fp32 intermediates in d_ws, fp32 output.
//   einsum -> conv3x3(s1,p1) -> conv3x3(s2,p1) -> conv3x3(s1,p1)
//   -> conv5x5(valid)=GEMM -> linear
// ---------------------------------------------------------------------------

__global__ void einsum_kernel(const float* __restrict__ A, const float* __restrict__ S,
                              float* __restrict__ out, int total)
{
    int idx = blockIdx.x * blockDim.x + threadIdx.x;
    if (idx >= total) return;
    int b  = idx / 38400;
    int r  = idx - b * 38400;
    int ch = r / 100;
    int px = r - ch * 100;
    int row = px / 10, col = px - row * 10;
    int h = row / 5, p = row - h * 5;
    int w = col / 5, q = col - w * 5;
    int n = ch / 48;
    int g = (ch / 3) % 16;
    int o = ch % 3;
    const float* Ab = A + (size_t)b * 2048 + (size_t)(n * 64 + g * 4) * 4 + h * 2 + w;
    const float* Sb = S + ((size_t)(b * 64 + g * 4) * 3 + o) * 25 + p * 5 + q;
    float s = 0.f;
    #pragma unroll
    for (int c = 0; c < 4; ++c)
        s += Ab[c * 4] * Sb[c * 75];
    out[idx] = s;
}

// 3x3 stride-1 pad-1 conv on HxH images, bias+ReLU. Thread owns a 5x5 tile.
template<int IC, int OC, int H, int NB, int OCT, int ICT>
__global__ void __launch_bounds__(NB * OCT * (H / 5) * (H / 5))
conv_s1_tiled(const float* __restrict__ in, const float* __restrict__ wgt,
              const float* __restrict__ bias, float* __restrict__ out)
{
    constexpr int TILES = (H / 5) * (H / 5);
    constexpr int TPB = NB * OCT * TILES;
    constexpr int HP = H + 2;
    __shared__ float s_in[NB][ICT][HP][HP];
    __shared__ float s_w[OCT][ICT * 9 + 1];   // stride 73/145: odd -> conflict-free

    const int tid  = threadIdx.x;
    const int quad = tid % TILES;
    const int oc_l = (tid / TILES) % OCT;
    const int b_l  = tid / (TILES * OCT);
    const int nOCg = OC / OCT;
    const int ocg  = blockIdx.x % nOCg;
    const int b0   = (blockIdx.x / nOCg) * NB;
    const int oc   = ocg * OCT + oc_l;
    const int y0   = (TILES > 1) ? (quad >> 1) * 5 : 0;
    const int x0   = (TILES > 1) ? (quad & 1) * 5 : 0;

    float acc[5][5] = {};
    for (int ic0 = 0; ic0 < IC; ic0 += ICT) {
        // stage input tile (padded, zero borders)
        constexpr int IN_ELEMS = NB * ICT * HP * HP;
        for (int i = tid; i < IN_ELEMS; i += TPB) {
            int bl  = i / (ICT * HP * HP);
            int r   = i - bl * (ICT * HP * HP);
            int icl = r / (HP * HP);
            int r2  = r - icl * (HP * HP);
            int y = r2 / HP, x = r2 - y * HP;
            int iy = y - 1, ix = x - 1;
            float v = 0.f;
            if (iy >= 0 && iy < H && ix >= 0 && ix < H)
                v = in[((size_t)(b0 + bl) * IC + ic0 + icl) * (H * H) + iy * H + ix];
            s_in[bl][icl][y][x] = v;
        }
        // stage weights
        constexpr int W_ELEMS = OCT * ICT * 9;
        for (int i = tid; i < W_ELEMS; i += TPB) {
            int ocl = i / (ICT * 9);
            int r   = i - ocl * (ICT * 9);
            int icl = r / 9, t = r - icl * 9;
            s_w[ocl][r] = wgt[((size_t)(ocg * OCT + ocl) * IC + ic0 + icl) * 9 + t];
        }
        __syncthreads();

        for (int ic = 0; ic < ICT; ++ic) {
            float wv[9];
            #pragma unroll
            for (int t = 0; t < 9; ++t) wv[t] = s_w[oc_l][ic * 9 + t];
            #pragma unroll
            for (int pr = 0; pr < 7; ++pr) {          // padded rows y0..y0+6
                float rowv[7];
                #pragma unroll
                for (int x = 0; x < 7; ++x) rowv[x] = s_in[b_l][ic][y0 + pr][x0 + x];
                #pragma unroll
                for (int ky = 0; ky < 3; ++ky) {
                    int oy = pr - ky;                  // compile-time constant
                    if (oy >= 0 && oy < 5) {
                        #pragma unroll
                        for (int kx = 0; kx < 3; ++kx)
                            #pragma unroll
                            for (int ox = 0; ox < 5; ++ox)
                                acc[oy][ox] += wv[ky * 3 + kx] * rowv[ox + kx];
                    }
                }
            }
        }
        __syncthreads();
    }
    float bv = bias[oc];
    #pragma unroll
    for (int oy = 0; oy < 5; ++oy)
        #pragma unroll
        for (int ox = 0; ox < 5; ++ox) {
            float v = acc[oy][ox] + bv;
            out[((size_t)(b0 + b_l) * OC + oc) * (H * H) + (y0 + oy) * H + (x0 + ox)]
                = v > 0.f ? v : 0.f;
        }
}

// 3x3 stride-2 pad-1, 10x10 -> 5x5, bias+ReLU. Thread owns full 5x5 output.
template<int IC, int OC, int NB, int OCT, int ICT>
__global__ void __launch_bounds__(NB * OCT)
conv_s2_tiled(const float* __restrict__ in, const float* __restrict__ wgt,
              const float* __restrict__ bias, float* __restrict__ out)
{
    constexpr int TPB = NB * OCT;
    __shared__ float s_in[NB][ICT][12][12];
    __shared__ float s_w[OCT][ICT * 9 + 1];
    const int tid  = threadIdx.x;
    const int oc_l = tid % OCT;
    const int b_l  = tid / OCT;
    const int nOCg = OC / OCT;
    const int ocg  = blockIdx.x % nOCg;
    const int b0   = (blockIdx.x / nOCg) * NB;
    const int oc   = ocg * OCT + oc_l;

    float acc[5][5] = {};
    for (int ic0 = 0; ic0 < IC; ic0 += ICT) {
        constexpr int IN_ELEMS = NB * ICT * 144;
        for (int i = tid; i < IN_ELEMS; i += TPB) {
            int bl  = i / (ICT * 144);
            int r   = i - bl * (ICT * 144);
            int icl = r / 144;
            int r2  = r - icl * 144;
            int y = r2 / 12, x = r2 - y * 12;
            int iy = y - 1, ix = x - 1;
            float v = 0.f;
            if (iy >= 0 && iy < 10 && ix >= 0 && ix < 10)
                v = in[((size_t)(b0 + bl) * IC + ic0 + icl) * 100 + iy * 10 + ix];
            s_in[bl][icl][y][x] = v;
        }
        constexpr int W_ELEMS = OCT * ICT * 9;
        for (int i = tid; i < W_ELEMS; i += TPB) {
            int ocl = i / (ICT * 9);
            int r   = i - ocl * (ICT * 9);
            int icl = r / 9, t = r - icl * 9;
            s_w[ocl][r] = wgt[((size_t)(ocg * OCT + ocl) * IC + ic0 + icl) * 9 + t];
        }
        __syncthreads();
        for (int ic = 0; ic < ICT; ++ic) {
            float wv[9];
            #pragma unroll
            for (int t = 0; t < 9; ++t) wv[t] = s_w[oc_l][ic * 9 + t];
            #pragma unroll
            for (int pr = 0; pr < 11; ++pr) {          // padded rows 0..10
                float rowv[11];
                #pragma unroll
                for (int x = 0; x < 11; ++x) rowv[x] = s_in[b_l][ic][pr][x];
                #pragma unroll
                for (int ky = 0; ky < 3; ++ky) {
                    int t2 = pr - ky;                   // padded row = 2*oy+ky
                    if (t2 >= 0 && (t2 & 1) == 0 && (t2 >> 1) < 5) {
                        int oy = t2 >> 1;
                        #pragma unroll
                        for (int kx = 0; kx < 3; ++kx)
                            #pragma unroll
                            for (int ox = 0; ox < 5; ++ox)
                                acc[oy][ox] += wv[ky * 3 + kx] * rowv[2 * ox + kx];
                    }
                }
            }
        }
        __syncthreads();
    }
    float bv = bias[oc];
    #pragma unroll
    for (int oy = 0; oy < 5; ++oy)
        #pragma unroll
        for (int ox = 0; ox < 5; ++ox) {
            float v = acc[oy][ox] + bv;
            out[((size_t)(b0 + b_l) * OC + oc) * 25 + oy * 5 + ox] = v > 0.f ? v : 0.f;
        }
}

// conv5x5(valid) as GEMM: out[b][oc] = relu(b4[oc] + dot(x3[b,:], W4[oc,:])), K=12800.
// Amat M x K row-major (M = batch), Bmat N x K row-major. 64x64 tile, 4x4/thread.
template<int KTOT>
__global__ void __launch_bounds__(256)
gemm_relu_64x64(const float* __restrict__ Amat, const float* __restrict__ Bmat,
                const float* __restrict__ bias, float* __restrict__ out, int N)
{
    __shared__ float s_a[32][65];
    __shared__ float s_b[32][65];
    const int tid = threadIdx.x;
    const int tx = tid % 16, ty = tid / 16;
    const int nN = N / 64;
    const int bn = blockIdx.x % nN;
    const int bm = blockIdx.x / nN;
    const int row0 = bm * 64, col0 = bn * 64;
    float acc[4][4] = {};
    for (int k0 = 0; k0 < KTOT; k0 += 32) {
        for (int i = tid; i < 64 * 32; i += 256) {
            int r = i / 32, k = i - r * 32;
            s_a[k][r] = Amat[(size_t)(row0 + r) * KTOT + k0 + k];
        }
        for (int i = tid; i < 64 * 32; i += 256) {
            int r = i / 32, k = i - r * 32;
            s_b[k][r] = Bmat[(size_t)(col0 + r) * KTOT + k0 + k];
        }
        __syncthreads();
        for (int k = 0; k < 32; ++k) {
            float av[4], bv[4];
            #pragma unroll
            for (int u = 0; u < 4; ++u) av[u] = s_a[k][ty * 4 + u];
            #pragma unroll
            for (int u = 0; u < 4; ++u) bv[u] = s_b[k][tx * 4 + u];
            #pragma unroll
            for (int i = 0; i < 4; ++i)
                #pragma unroll
                for (int j = 0; j < 4; ++j)
                    acc[i][j] += av[i] * bv[j];
        }
        __syncthreads();
    }
    #pragma unroll
    for (int i = 0; i < 4; ++i) {
        int r = row0 + ty * 4 + i;
        #pragma unroll
        for (int j = 0; j < 4; ++j) {
            int c = col0 + tx * 4 + j;
            float v = acc[i][j] + bias[c];
            out[(size_t)r * N + c] = v > 0.f ? v : 0.f;
        }
    }
}

// Fallback for small batch chunks.
__global__ void conv4_naive(const float* __restrict__ x, const float* __restrict__ W4,
                            const float* __restrict__ b4, float* __restrict__ out,
                            int total)
{
    int idx = blockIdx.x * blockDim.x + threadIdx.x;
    if (idx >= total) return;
    int b = idx / 512, oc = idx - b * 512;
    const float* xb = x  + (size_t)b  * 12800;
    const float* wp = W4 + (size_t)oc * 12800;
    float acc = b4[oc];
    for (int k = 0; k < 12800; ++k)
        acc += xb[k] * wp[k];
    out[idx] = acc > 0.f ? acc : 0.f;
}

__global__ void linear_naive(const float* __restrict__ x, const float* __restrict__ Wl,
                             const float* __restrict__ bl,
                             float* __restrict__ out, int total)
{
    int idx = blockIdx.x * blockDim.x + threadIdx.x;
    if (idx >= total) return;
    int b = idx / 10, j = idx - b * 10;
    const float* xb = x  + (size_t)b * 512;
    const float* wj = Wl + (size_t)j * 512;
    float s = bl[j];
    for (int k = 0; k < 512; ++k)
        s += xb[k] * wj[k];
    out[idx] = s;
}

extern "C" void kernel_launch(void* const* d_in, const int* in_sizes, int n_in,
                              void* d_out, int out_size, void* d_ws, size_t ws_size,
                              hipStream_t stream)
{
    const float* A  = (const float*)d_in[0];
    const float* S  = (const float*)d_in[1];
    const float* W1 = (const float*)d_in[2];
    const float* b1 = (const float*)d_in[3];
    const float* W2 = (const float*)d_in[4];
    const float* b2 = (const float*)d_in[5];
    const float* W3 = (const float*)d_in[6];
    const float* b3 = (const float*)d_in[7];
    const float* W4 = (const float*)d_in[8];
    const float* b4 = (const float*)d_in[9];
    const float* Wl = (const float*)d_in[10];
    const float* bl = (const float*)d_in[11];
    float* outp = (float*)d_out;
    float* ws = (float*)d_ws;

    const int Btot = 512;
    int Bc = 512;
    while (Bc > 8 && (size_t)Bc * 38400ull * 8ull > ws_size) Bc >>= 1;

    for (int b0 = 0; b0 < Btot; b0 += Bc) {
        float* x0 = ws;                            // (Bc,384,10,10)
        float* x1 = ws + (size_t)Bc * 38400;       // (Bc,384,10,10)
        float* x2 = ws;                            // (Bc,384,5,5)
        float* x3 = ws + (size_t)Bc * 38400;       // (Bc,512,5,5)
        float* x4 = ws;                            // (Bc,512)

        int t0 = Bc * 38400;
        einsum_kernel<<<(t0 + 255) / 256, 256, 0, stream>>>(
            A + (size_t)b0 * 2048, S + (size_t)b0 * 4800, x0, t0);

        conv_s1_tiled<384, 384, 10, 2, 32, 16>            // LDS 37.0 KB
            <<<dim3((Bc / 2) * 12), 256, 0, stream>>>(x0, W1, b1, x1);

        conv_s2_tiled<384, 384, 4, 64, 8>                 // LDS 37.1 KB
            <<<dim3((Bc / 4) * 6), 256, 0, stream>>>(x1, W2, b2, x2);

        conv_s1_tiled<384, 512, 5, 8, 32, 16>             // LDS 43.6 KB
            <<<dim3((Bc / 8) * 16), 256, 0, stream>>>(x2, W3, b3, x3);

        if (Bc >= 64) {
            gemm_relu_64x64<12800>
                <<<dim3((Bc / 64) * 8), 256, 0, stream>>>(x3, W4, b4, x4, 512);
        } else {
            int t4 = Bc * 512;
            conv4_naive<<<(t4 + 255) / 256, 256, 0, stream>>>(x3, W4, b4, x4, t4);
        }

        int t5 = Bc * 10;
        linear_naive<<<(t5 + 255) / 256, 256, 0, stream>>>(
            x4, Wl, bl, outp + (size_t)b0 * 10, t5);
    }
}

// Round 8
// 4673.293 us; speedup vs baseline: 10.5099x; 1.5708x over previous
//
#include <hip/hip_runtime.h>
#include <hip/hip_bf16.h>

// ---------------------------------------------------------------------------
// Decoder_SICA — ROUND 7: round-6 verified pipeline + split-K conv4 GEMM.
// fp32 inputs, fp32 intermediates in d_ws, fp32 output.
// ---------------------------------------------------------------------------

__global__ void einsum_kernel(const float* __restrict__ A, const float* __restrict__ S,
                              float* __restrict__ out, int total)
{
    int idx = blockIdx.x * blockDim.x + threadIdx.x;
    if (idx >= total) return;
    int b  = idx / 38400;
    int r  = idx - b * 38400;
    int ch = r / 100;
    int px = r - ch * 100;
    int row = px / 10, col = px - row * 10;
    int h = row / 5, p = row - h * 5;
    int w = col / 5, q = col - w * 5;
    int n = ch / 48;
    int g = (ch / 3) % 16;
    int o = ch % 3;
    const float* Ab = A + (size_t)b * 2048 + (size_t)(n * 64 + g * 4) * 4 + h * 2 + w;
    const float* Sb = S + ((size_t)(b * 64 + g * 4) * 3 + o) * 25 + p * 5 + q;
    float s = 0.f;
    #pragma unroll
    for (int c = 0; c < 4; ++c)
        s += Ab[c * 4] * Sb[c * 75];
    out[idx] = s;
}

// 3x3 stride-1 pad-1 conv on HxH images, bias+ReLU. Thread owns a 5x5 tile.
template<int IC, int OC, int H, int NB, int OCT, int ICT>
__global__ void __launch_bounds__(NB * OCT * (H / 5) * (H / 5))
conv_s1_tiled(const float* __restrict__ in, const float* __restrict__ wgt,
              const float* __restrict__ bias, float* __restrict__ out)
{
    constexpr int TILES = (H / 5) * (H / 5);
    constexpr int TPB = NB * OCT * TILES;
    constexpr int HP = H + 2;
    __shared__ float s_in[NB][ICT][HP][HP];
    __shared__ float s_w[OCT][ICT * 9 + 1];

    const int tid  = threadIdx.x;
    const int quad = tid % TILES;
    const int oc_l = (tid / TILES) % OCT;
    const int b_l  = tid / (TILES * OCT);
    const int nOCg = OC / OCT;
    const int ocg  = blockIdx.x % nOCg;
    const int b0   = (blockIdx.x / nOCg) * NB;
    const int oc   = ocg * OCT + oc_l;
    const int y0   = (TILES > 1) ? (quad >> 1) * 5 : 0;
    const int x0   = (TILES > 1) ? (quad & 1) * 5 : 0;

    float acc[5][5] = {};
    for (int ic0 = 0; ic0 < IC; ic0 += ICT) {
        constexpr int IN_ELEMS = NB * ICT * HP * HP;
        for (int i = tid; i < IN_ELEMS; i += TPB) {
            int bl  = i / (ICT * HP * HP);
            int r   = i - bl * (ICT * HP * HP);
            int icl = r / (HP * HP);
            int r2  = r - icl * (HP * HP);
            int y = r2 / HP, x = r2 - y * HP;
            int iy = y - 1, ix = x - 1;
            float v = 0.f;
            if (iy >= 0 && iy < H && ix >= 0 && ix < H)
                v = in[((size_t)(b0 + bl) * IC + ic0 + icl) * (H * H) + iy * H + ix];
            s_in[bl][icl][y][x] = v;
        }
        constexpr int W_ELEMS = OCT * ICT * 9;
        for (int i = tid; i < W_ELEMS; i += TPB) {
            int ocl = i / (ICT * 9);
            int r   = i - ocl * (ICT * 9);
            s_w[ocl][r] = wgt[((size_t)(ocg * OCT + ocl) * IC + ic0 + r / 9) * 9 + r % 9];
        }
        __syncthreads();

        for (int ic = 0; ic < ICT; ++ic) {
            float wv[9];
            #pragma unroll
            for (int t = 0; t < 9; ++t) wv[t] = s_w[oc_l][ic * 9 + t];
            #pragma unroll
            for (int pr = 0; pr < 7; ++pr) {
                float rowv[7];
                #pragma unroll
                for (int x = 0; x < 7; ++x) rowv[x] = s_in[b_l][ic][y0 + pr][x0 + x];
                #pragma unroll
                for (int ky = 0; ky < 3; ++ky) {
                    int oy = pr - ky;
                    if (oy >= 0 && oy < 5) {
                        #pragma unroll
                        for (int kx = 0; kx < 3; ++kx)
                            #pragma unroll
                            for (int ox = 0; ox < 5; ++ox)
                                acc[oy][ox] += wv[ky * 3 + kx] * rowv[ox + kx];
                    }
                }
            }
        }
        __syncthreads();
    }
    float bv = bias[oc];
    #pragma unroll
    for (int oy = 0; oy < 5; ++oy)
        #pragma unroll
        for (int ox = 0; ox < 5; ++ox) {
            float v = acc[oy][ox] + bv;
            out[((size_t)(b0 + b_l) * OC + oc) * (H * H) + (y0 + oy) * H + (x0 + ox)]
                = v > 0.f ? v : 0.f;
        }
}

// 3x3 stride-2 pad-1, 10x10 -> 5x5, bias+ReLU. Thread owns full 5x5 output.
template<int IC, int OC, int NB, int OCT, int ICT>
__global__ void __launch_bounds__(NB * OCT)
conv_s2_tiled(const float* __restrict__ in, const float* __restrict__ wgt,
              const float* __restrict__ bias, float* __restrict__ out)
{
    constexpr int TPB = NB * OCT;
    __shared__ float s_in[NB][ICT][12][12];
    __shared__ float s_w[OCT][ICT * 9 + 1];
    const int tid  = threadIdx.x;
    const int oc_l = tid % OCT;
    const int b_l  = tid / OCT;
    const int nOCg = OC / OCT;
    const int ocg  = blockIdx.x % nOCg;
    const int b0   = (blockIdx.x / nOCg) * NB;
    const int oc   = ocg * OCT + oc_l;

    float acc[5][5] = {};
    for (int ic0 = 0; ic0 < IC; ic0 += ICT) {
        constexpr int IN_ELEMS = NB * ICT * 144;
        for (int i = tid; i < IN_ELEMS; i += TPB) {
            int bl  = i / (ICT * 144);
            int r   = i - bl * (ICT * 144);
            int icl = r / 144;
            int r2  = r - icl * 144;
            int y = r2 / 12, x = r2 - y * 12;
            int iy = y - 1, ix = x - 1;
            float v = 0.f;
            if (iy >= 0 && iy < 10 && ix >= 0 && ix < 10)
                v = in[((size_t)(b0 + bl) * IC + ic0 + icl) * 100 + iy * 10 + ix];
            s_in[bl][icl][y][x] = v;
        }
        constexpr int W_ELEMS = OCT * ICT * 9;
        for (int i = tid; i < W_ELEMS; i += TPB) {
            int ocl = i / (ICT * 9);
            int r   = i - ocl * (ICT * 9);
            s_w[ocl][r] = wgt[((size_t)(ocg * OCT + ocl) * IC + ic0 + r / 9) * 9 + r % 9];
        }
        __syncthreads();
        for (int ic = 0; ic < ICT; ++ic) {
            float wv[9];
            #pragma unroll
            for (int t = 0; t < 9; ++t) wv[t] = s_w[oc_l][ic * 9 + t];
            #pragma unroll
            for (int pr = 0; pr < 11; ++pr) {
                float rowv[11];
                #pragma unroll
                for (int x = 0; x < 11; ++x) rowv[x] = s_in[b_l][ic][pr][x];
                #pragma unroll
                for (int ky = 0; ky < 3; ++ky) {
                    int t2 = pr - ky;
                    if (t2 >= 0 && (t2 & 1) == 0 && (t2 >> 1) < 5) {
                        int oy = t2 >> 1;
                        #pragma unroll
                        for (int kx = 0; kx < 3; ++kx)
                            #pragma unroll
                            for (int ox = 0; ox < 5; ++ox)
                                acc[oy][ox] += wv[ky * 3 + kx] * rowv[2 * ox + kx];
                    }
                }
            }
        }
        __syncthreads();
    }
    float bv = bias[oc];
    #pragma unroll
    for (int oy = 0; oy < 5; ++oy)
        #pragma unroll
        for (int ox = 0; ox < 5; ++ox) {
            float v = acc[oy][ox] + bv;
            out[((size_t)(b0 + b_l) * OC + oc) * 25 + oy * 5 + ox] = v > 0.f ? v : 0.f;
        }
}

// Split-K GEMM partials for conv4: Cpart[ks][m][n] = sum_{k in chunk} A[m][k]*B[n][k].
// A: M x KTOT row-major (x3), B: N x KTOT row-major (W4). 64x64 tile per block.
template<int KTOT, int KS>
__global__ void __launch_bounds__(256)
gemm_splitk(const float* __restrict__ Amat, const float* __restrict__ Bmat,
            float* __restrict__ Cpart, int M, int N)
{
    constexpr int KC = KTOT / KS;            // k-chunk per split (640 for KS=20)
    __shared__ float s_a[32][65];
    __shared__ float s_b[32][65];
    const int tid = threadIdx.x;
    const int tx = tid % 16, ty = tid / 16;
    const int nN = N / 64;
    const int nM = M / 64;
    const int ks = blockIdx.x / (nM * nN);
    const int rb = blockIdx.x % (nM * nN);
    const int bm = rb / nN;
    const int bn = rb % nN;
    const int row0 = bm * 64, col0 = bn * 64;
    const int kbase = ks * KC;

    float acc[4][4] = {};
    for (int k0 = 0; k0 < KC; k0 += 32) {
        // stage 64x32 of A and B; float4 global loads, transposed LDS writes
        for (int i = tid; i < 64 * 8; i += 256) {
            int r = i / 8, c4 = (i % 8) * 4;
            const float4 va = *(const float4*)&Amat[(size_t)(row0 + r) * KTOT + kbase + k0 + c4];
            s_a[c4 + 0][r] = va.x; s_a[c4 + 1][r] = va.y;
            s_a[c4 + 2][r] = va.z; s_a[c4 + 3][r] = va.w;
            const float4 vb = *(const float4*)&Bmat[(size_t)(col0 + r) * KTOT + kbase + k0 + c4];
            s_b[c4 + 0][r] = vb.x; s_b[c4 + 1][r] = vb.y;
            s_b[c4 + 2][r] = vb.z; s_b[c4 + 3][r] = vb.w;
        }
        __syncthreads();
        for (int k = 0; k < 32; ++k) {
            float av[4], bv[4];
            #pragma unroll
            for (int u = 0; u < 4; ++u) av[u] = s_a[k][ty * 4 + u];
            #pragma unroll
            for (int u = 0; u < 4; ++u) bv[u] = s_b[k][tx * 4 + u];
            #pragma unroll
            for (int i = 0; i < 4; ++i)
                #pragma unroll
                for (int j = 0; j < 4; ++j)
                    acc[i][j] += av[i] * bv[j];
        }
        __syncthreads();
    }
    float* cp = Cpart + (size_t)ks * M * N;
    #pragma unroll
    for (int i = 0; i < 4; ++i) {
        int r = row0 + ty * 4 + i;
        #pragma unroll
        for (int j = 0; j < 4; ++j)
            cp[(size_t)r * N + col0 + tx * 4 + j] = acc[i][j];
    }
}

// Reduce split-K partials + bias + ReLU.
template<int KS>
__global__ void splitk_reduce_relu(const float* __restrict__ Cpart,
                                   const float* __restrict__ bias,
                                   float* __restrict__ out, int M, int N)
{
    int idx = blockIdx.x * blockDim.x + threadIdx.x;
    if (idx >= M * N) return;
    int oc = idx % N;
    float s = bias[oc];
    #pragma unroll
    for (int ks = 0; ks < KS; ++ks)
        s += Cpart[(size_t)ks * M * N + idx];
    out[idx] = s > 0.f ? s : 0.f;
}

// Fallback for small batch chunks.
__global__ void conv4_naive(const float* __restrict__ x, const float* __restrict__ W4,
                            const float* __restrict__ b4, float* __restrict__ out,
                            int total)
{
    int idx = blockIdx.x * blockDim.x + threadIdx.x;
    if (idx >= total) return;
    int b = idx / 512, oc = idx - b * 512;
    const float* xb = x  + (size_t)b  * 12800;
    const float* wp = W4 + (size_t)oc * 12800;
    float acc = b4[oc];
    for (int k = 0; k < 12800; ++k)
        acc += xb[k] * wp[k];
    out[idx] = acc > 0.f ? acc : 0.f;
}

__global__ void linear_naive(const float* __restrict__ x, const float* __restrict__ Wl,
                             const float* __restrict__ bl,
                             float* __restrict__ out, int total)
{
    int idx = blockIdx.x * blockDim.x + threadIdx.x;
    if (idx >= total) return;
    int b = idx / 10, j = idx - b * 10;
    const float* xb = x  + (size_t)b * 512;
    const float* wj = Wl + (size_t)j * 512;
    float s = bl[j];
    for (int k = 0; k < 512; ++k)
        s += xb[k] * wj[k];
    out[idx] = s;
}

extern "C" void kernel_launch(void* const* d_in, const int* in_sizes, int n_in,
                              void* d_out, int out_size, void* d_ws, size_t ws_size,
                              hipStream_t stream)
{
    const float* A  = (const float*)d_in[0];
    const float* S  = (const float*)d_in[1];
    const float* W1 = (const float*)d_in[2];
    const float* b1 = (const float*)d_in[3];
    const float* W2 = (const float*)d_in[4];
    const float* b2 = (const float*)d_in[5];
    const float* W3 = (const float*)d_in[6];
    const float* b3 = (const float*)d_in[7];
    const float* W4 = (const float*)d_in[8];
    const float* b4 = (const float*)d_in[9];
    const float* Wl = (const float*)d_in[10];
    const float* bl = (const float*)d_in[11];
    float* outp = (float*)d_out;
    float* ws = (float*)d_ws;

    const int Btot = 512;
    constexpr int KS = 20;                      // split-K factor (12800/20 = 640)
    int Bc = 512;
    while (Bc > 8 && (size_t)Bc * 38400ull * 8ull > ws_size) Bc >>= 1;

    for (int b0 = 0; b0 < Btot; b0 += Bc) {
        float* x0 = ws;                            // (Bc,384,10,10)
        float* x1 = ws + (size_t)Bc * 38400;       // (Bc,384,10,10)
        float* x2 = ws;                            // (Bc,384,5,5)
        float* x3 = ws + (size_t)Bc * 38400;       // (Bc,512,5,5)
        float* cp = ws;                            // (KS,Bc,512) partials (x2 dead)
        float* x4 = ws + (size_t)KS * Bc * 512;    // (Bc,512)

        int t0 = Bc * 38400;
        einsum_kernel<<<(t0 + 255) / 256, 256, 0, stream>>>(
            A + (size_t)b0 * 2048, S + (size_t)b0 * 4800, x0, t0);

        conv_s1_tiled<384, 384, 10, 2, 32, 16>            // LDS 37.0 KB
            <<<dim3((Bc / 2) * 12), 256, 0, stream>>>(x0, W1, b1, x1);

        conv_s2_tiled<384, 384, 4, 64, 8>                 // LDS 37.1 KB
            <<<dim3((Bc / 4) * 6), 256, 0, stream>>>(x1, W2, b2, x2);

        conv_s1_tiled<384, 512, 5, 8, 32, 16>             // LDS 43.6 KB
            <<<dim3((Bc / 8) * 16), 256, 0, stream>>>(x2, W3, b3, x3);

        if (Bc >= 64) {
            int nblk = (Bc / 64) * 8 * KS;
            gemm_splitk<12800, KS><<<dim3(nblk), 256, 0, stream>>>(
                x3, W4, cp, Bc, 512);
            int tr = Bc * 512;
            splitk_reduce_relu<KS><<<(tr + 255) / 256, 256, 0, stream>>>(
                cp, b4, x4, Bc, 512);
        } else {
            int t4 = Bc * 512;
            conv4_naive<<<(t4 + 255) / 256, 256, 0, stream>>>(x3, W4, b4, x4, t4);
        }

        int t5 = Bc * 10;
        linear_naive<<<(t5 + 255) / 256, 256, 0, stream>>>(
            x4, Wl, bl, outp + (size_t)b0 * 10, t5);
    }
}

// Round 9
// 1564.117 us; speedup vs baseline: 31.4018x; 2.9878x over previous
//
#include <hip/hip_runtime.h>
#include <hip/hip_bf16.h>

// ---------------------------------------------------------------------------
// Decoder_SICA — ROUND 8: MFMA (bf16 hi/lo split) implicit-GEMM convs.
// fp32 inputs, padded-NHWC bf16 hi/lo plane intermediates, fp32 output.
//   einsum(pack) -> conv1(10x10,s1) -> conv2(->5x5,s2) -> conv3(5x5,s1,NCHW)
//   -> conv4 split-K fp32 GEMM -> linear
// ---------------------------------------------------------------------------

typedef __attribute__((ext_vector_type(8))) short bf16x8;
typedef __attribute__((ext_vector_type(4))) float f32x4;

__device__ __forceinline__ void split_bf16(float v, short& hs, short& ls) {
    __hip_bfloat16 h = __float2bfloat16(v);
    float hf = __bfloat162float(h);
    __hip_bfloat16 l = __float2bfloat16(v - hf);
    hs = __builtin_bit_cast(short, h);
    ls = __builtin_bit_cast(short, l);
}

__global__ void zero_kernel(unsigned int* __restrict__ p, long long nwords)
{
    long long i = (long long)blockIdx.x * blockDim.x + threadIdx.x;
    long long stride = (long long)gridDim.x * blockDim.x;
    for (; i < nwords; i += stride) p[i] = 0u;
}

// W (OC,384,3,3) fp32 -> hi/lo bf16 [oc][t*384+ic], t = ky*3+kx.
__global__ void pack_w_kernel(const float* __restrict__ W,
                              short* __restrict__ wh, short* __restrict__ wl, int total)
{
    int idx = blockIdx.x * blockDim.x + threadIdx.x;
    if (idx >= total) return;
    int oc = idx / 3456, k = idx - oc * 3456;
    int t = k / 384, ic = k - t * 384;
    float v = W[((size_t)oc * 384 + ic) * 9 + t];
    short hs, ls; split_bf16(v, hs, ls);
    wh[idx] = hs; wl[idx] = ls;
}

// einsum -> padded NHWC planes x0[b][12][12][384] (hi/lo), interior only.
__global__ void einsum_pack(const float* __restrict__ A, const float* __restrict__ S,
                            short* __restrict__ oh, short* __restrict__ ol, int total)
{
    int idx = blockIdx.x * blockDim.x + threadIdx.x;
    if (idx >= total) return;
    int b   = idx / 38400;
    int r   = idx - b * 38400;
    int pix = r / 384;
    int ch  = r - pix * 384;
    int y = pix / 10, x = pix - y * 10;
    int h = y / 5, p = y - h * 5;
    int w = x / 5, q = x - w * 5;
    int n = ch / 48, g = (ch / 3) % 16, o = ch % 3;
    const float* Ab = A + (size_t)b * 2048 + (size_t)(n * 64 + g * 4) * 4 + h * 2 + w;
    const float* Sb = S + ((size_t)(b * 64 + g * 4) * 3 + o) * 25 + p * 5 + q;
    float s = 0.f;
    #pragma unroll
    for (int c = 0; c < 4; ++c)
        s += Ab[c * 4] * Sb[c * 75];
    short hs, ls; split_bf16(s, hs, ls);
    size_t d = ((size_t)(b * 12 + y + 1) * 12 + (x + 1)) * 384 + ch;
    oh[d] = hs; ol[d] = ls;
}

// Implicit-GEMM 3x3 conv via MFMA, hi/lo split. IC=384 fixed (K=3456).
// Block: 128 pixels x 128 oc, 4 waves each 64x64. MODE 0: write padded NHWC
// hi/lo planes (HPOUT). MODE 1: write NCHW fp32.
template<int OC_T, int HOUT, int HPIN, int HPOUT, int STRIDE, int MODE>
__global__ void __launch_bounds__(256)
conv_mfma(const short* __restrict__ in_h, const short* __restrict__ in_l,
          const short* __restrict__ w_h,  const short* __restrict__ w_l,
          const float* __restrict__ bias,
          short* __restrict__ out_h, short* __restrict__ out_l,
          float* __restrict__ out_f, int M_total)
{
    constexpr int IC = 384, K3 = 3456;
    __shared__ short s_ah[128 * 40], s_al[128 * 40];
    __shared__ short s_wh[128 * 40], s_wl[128 * 40];

    const int tid = threadIdx.x;
    const int M0 = blockIdx.x * 128;
    const int n0 = blockIdx.y * 128;

    // staging role: thread -> (row sp, 16-elem half sh)
    const int sp = tid >> 1;
    const int sh = tid & 1;
    int P = M0 + sp; if (P > M_total - 1) P = M_total - 1;
    const int bb = P / (HOUT * HOUT);
    const int pr = P % (HOUT * HOUT);
    const int py = pr / HOUT, px = pr - py * HOUT;
    const size_t wrow = (size_t)(n0 + sp) * K3 + sh * 16;
    const int sdst = sp * 40 + sh * 16;

    // compute role
    const int lane = tid & 63;
    const int wid  = tid >> 6;
    const int wm = (wid & 1) * 64, wn = (wid >> 1) * 64;
    const int l15 = lane & 15, kg = lane >> 4;

    f32x4 acc[4][4];
    #pragma unroll
    for (int i = 0; i < 4; ++i)
        #pragma unroll
        for (int j = 0; j < 4; ++j)
            acc[i][j] = (f32x4){0.f, 0.f, 0.f, 0.f};

    for (int t = 0; t < 9; ++t) {
        const int ky = t / 3, kx = t - ky * 3;
        const size_t asrc =
            ((size_t)(bb * HPIN + py * STRIDE + ky) * HPIN + (px * STRIDE + kx)) * IC + sh * 16;
        const size_t wsrc = wrow + t * IC;
        for (int ic0 = 0; ic0 < IC; ic0 += 32) {
            *(bf16x8*)&s_ah[sdst]     = *(const bf16x8*)&in_h[asrc + ic0];
            *(bf16x8*)&s_ah[sdst + 8] = *(const bf16x8*)&in_h[asrc + ic0 + 8];
            *(bf16x8*)&s_al[sdst]     = *(const bf16x8*)&in_l[asrc + ic0];
            *(bf16x8*)&s_al[sdst + 8] = *(const bf16x8*)&in_l[asrc + ic0 + 8];
            *(bf16x8*)&s_wh[sdst]     = *(const bf16x8*)&w_h[wsrc + ic0];
            *(bf16x8*)&s_wh[sdst + 8] = *(const bf16x8*)&w_h[wsrc + ic0 + 8];
            *(bf16x8*)&s_wl[sdst]     = *(const bf16x8*)&w_l[wsrc + ic0];
            *(bf16x8*)&s_wl[sdst + 8] = *(const bf16x8*)&w_l[wsrc + ic0 + 8];
            __syncthreads();

            bf16x8 ah[4], al[4];
            #pragma unroll
            for (int mf = 0; mf < 4; ++mf) {
                int ar = (wm + mf * 16 + l15) * 40 + kg * 8;
                ah[mf] = *(const bf16x8*)&s_ah[ar];
                al[mf] = *(const bf16x8*)&s_al[ar];
            }
            #pragma unroll
            for (int nf = 0; nf < 4; ++nf) {
                int br = (wn + nf * 16 + l15) * 40 + kg * 8;
                bf16x8 bh = *(const bf16x8*)&s_wh[br];
                bf16x8 bl = *(const bf16x8*)&s_wl[br];
                #pragma unroll
                for (int mf = 0; mf < 4; ++mf) {
                    acc[mf][nf] = __builtin_amdgcn_mfma_f32_16x16x32_bf16(ah[mf], bh, acc[mf][nf], 0, 0, 0);
                    acc[mf][nf] = __builtin_amdgcn_mfma_f32_16x16x32_bf16(al[mf], bh, acc[mf][nf], 0, 0, 0);
                    acc[mf][nf] = __builtin_amdgcn_mfma_f32_16x16x32_bf16(ah[mf], bl, acc[mf][nf], 0, 0, 0);
                }
            }
            __syncthreads();
        }
    }

    #pragma unroll
    for (int nf = 0; nf < 4; ++nf) {
        const int oc = n0 + wn + nf * 16 + l15;
        const float bv = bias[oc];
        #pragma unroll
        for (int mf = 0; mf < 4; ++mf) {
            #pragma unroll
            for (int j = 0; j < 4; ++j) {
                int m = M0 + wm + mf * 16 + kg * 4 + j;
                if (m < M_total) {
                    float v = acc[mf][nf][j] + bv;
                    v = v > 0.f ? v : 0.f;
                    int b2 = m / (HOUT * HOUT);
                    int pr2 = m % (HOUT * HOUT);
                    int y2 = pr2 / HOUT, x2 = pr2 - y2 * HOUT;
                    if (MODE == 0) {
                        size_t d = ((size_t)(b2 * HPOUT + y2 + 1) * HPOUT + (x2 + 1)) * OC_T + oc;
                        short hs, ls; split_bf16(v, hs, ls);
                        out_h[d] = hs; out_l[d] = ls;
                    } else {
                        out_f[((size_t)b2 * OC_T + oc) * (HOUT * HOUT) + pr2] = v;
                    }
                }
            }
        }
    }
}

// ---- conv4 (split-K fp32 GEMM) + linear: verbatim from round 7 ----
template<int KTOT, int KS>
__global__ void __launch_bounds__(256)
gemm_splitk(const float* __restrict__ Amat, const float* __restrict__ Bmat,
            float* __restrict__ Cpart, int M, int N)
{
    constexpr int KC = KTOT / KS;
    __shared__ float s_a[32][65];
    __shared__ float s_b[32][65];
    const int tid = threadIdx.x;
    const int tx = tid % 16, ty = tid / 16;
    const int nN = N / 64;
    const int nM = M / 64;
    const int ks = blockIdx.x / (nM * nN);
    const int rb = blockIdx.x % (nM * nN);
    const int bm = rb / nN;
    const int bn = rb % nN;
    const int row0 = bm * 64, col0 = bn * 64;
    const int kbase = ks * KC;

    float acc[4][4] = {};
    for (int k0 = 0; k0 < KC; k0 += 32) {
        for (int i = tid; i < 64 * 8; i += 256) {
            int r = i / 8, c4 = (i % 8) * 4;
            const float4 va = *(const float4*)&Amat[(size_t)(row0 + r) * KTOT + kbase + k0 + c4];
            s_a[c4 + 0][r] = va.x; s_a[c4 + 1][r] = va.y;
            s_a[c4 + 2][r] = va.z; s_a[c4 + 3][r] = va.w;
            const float4 vb = *(const float4*)&Bmat[(size_t)(col0 + r) * KTOT + kbase + k0 + c4];
            s_b[c4 + 0][r] = vb.x; s_b[c4 + 1][r] = vb.y;
            s_b[c4 + 2][r] = vb.z; s_b[c4 + 3][r] = vb.w;
        }
        __syncthreads();
        for (int k = 0; k < 32; ++k) {
            float av[4], bv[4];
            #pragma unroll
            for (int u = 0; u < 4; ++u) av[u] = s_a[k][ty * 4 + u];
            #pragma unroll
            for (int u = 0; u < 4; ++u) bv[u] = s_b[k][tx * 4 + u];
            #pragma unroll
            for (int i = 0; i < 4; ++i)
                #pragma unroll
                for (int j = 0; j < 4; ++j)
                    acc[i][j] += av[i] * bv[j];
        }
        __syncthreads();
    }
    float* cp = Cpart + (size_t)ks * M * N;
    #pragma unroll
    for (int i = 0; i < 4; ++i) {
        int r = row0 + ty * 4 + i;
        #pragma unroll
        for (int j = 0; j < 4; ++j)
            cp[(size_t)r * N + col0 + tx * 4 + j] = acc[i][j];
    }
}

template<int KS>
__global__ void splitk_reduce_relu(const float* __restrict__ Cpart,
                                   const float* __restrict__ bias,
                                   float* __restrict__ out, int M, int N)
{
    int idx = blockIdx.x * blockDim.x + threadIdx.x;
    if (idx >= M * N) return;
    int oc = idx % N;
    float s = bias[oc];
    #pragma unroll
    for (int ks = 0; ks < KS; ++ks)
        s += Cpart[(size_t)ks * M * N + idx];
    out[idx] = s > 0.f ? s : 0.f;
}

__global__ void conv4_naive(const float* __restrict__ x, const float* __restrict__ W4,
                            const float* __restrict__ b4, float* __restrict__ out,
                            int total)
{
    int idx = blockIdx.x * blockDim.x + threadIdx.x;
    if (idx >= total) return;
    int b = idx / 512, oc = idx - b * 512;
    const float* xb = x  + (size_t)b  * 12800;
    const float* wp = W4 + (size_t)oc * 12800;
    float acc = b4[oc];
    for (int k = 0; k < 12800; ++k)
        acc += xb[k] * wp[k];
    out[idx] = acc > 0.f ? acc : 0.f;
}

__global__ void linear_naive(const float* __restrict__ x, const float* __restrict__ Wl,
                             const float* __restrict__ bl,
                             float* __restrict__ out, int total)
{
    int idx = blockIdx.x * blockDim.x + threadIdx.x;
    if (idx >= total) return;
    int b = idx / 10, j = idx - b * 10;
    const float* xb = x  + (size_t)b * 512;
    const float* wj = Wl + (size_t)j * 512;
    float s = bl[j];
    for (int k = 0; k < 512; ++k)
        s += xb[k] * wj[k];
    out[idx] = s;
}

extern "C" void kernel_launch(void* const* d_in, const int* in_sizes, int n_in,
                              void* d_out, int out_size, void* d_ws, size_t ws_size,
                              hipStream_t stream)
{
    const float* A  = (const float*)d_in[0];
    const float* S  = (const float*)d_in[1];
    const float* W1 = (const float*)d_in[2];
    const float* b1 = (const float*)d_in[3];
    const float* W2 = (const float*)d_in[4];
    const float* b2 = (const float*)d_in[5];
    const float* W3 = (const float*)d_in[6];
    const float* b3 = (const float*)d_in[7];
    const float* W4 = (const float*)d_in[8];
    const float* b4 = (const float*)d_in[9];
    const float* Wl = (const float*)d_in[10];
    const float* bl = (const float*)d_in[11];
    float* outp = (float*)d_out;
    char* base = (char*)d_ws;

    const int Btot = 512;
    constexpr int KS = 20;

    // ---- fixed weight-pack region (17,694,720 B) ----
    const size_t W12N = (size_t)384 * 3456;   // W1/W2 elems
    const size_t W3N  = (size_t)512 * 3456;
    size_t off = 0;
    short* w1h = (short*)(base + off); off += W12N * 2;
    short* w1l = (short*)(base + off); off += W12N * 2;
    short* w2h = (short*)(base + off); off += W12N * 2;
    short* w2l = (short*)(base + off); off += W12N * 2;
    short* w3h = (short*)(base + off); off += W3N * 2;
    short* w3l = (short*)(base + off); off += W3N * 2;
    const size_t wreg = off;

    // per-sample: planes x0(2x110592B) x1(2x110592B) x2(2x37632B) + x3/cp/x4
    const size_t PS = 2 * 110592 + 2 * 110592 + 2 * 37632 + 51200 + 40960 + 2048; // 611,840
    int Bc = 512;
    while (Bc > 8 && wreg + (size_t)Bc * PS > ws_size) Bc >>= 1;

    pack_w_kernel<<<(int)((W12N + 255) / 256), 256, 0, stream>>>(W1, w1h, w1l, (int)W12N);
    pack_w_kernel<<<(int)((W12N + 255) / 256), 256, 0, stream>>>(W2, w2h, w2l, (int)W12N);
    pack_w_kernel<<<(int)((W3N  + 255) / 256), 256, 0, stream>>>(W3, w3h, w3l, (int)W3N);

    // chunk-region pointers (contiguous: x0h x0l x1h x1l x2h x2l x3 cp x4)
    size_t o2 = wreg;
    short* x0h = (short*)(base + o2); o2 += (size_t)Bc * 110592;
    short* x0l = (short*)(base + o2); o2 += (size_t)Bc * 110592;
    short* x1h = (short*)(base + o2); o2 += (size_t)Bc * 110592;
    short* x1l = (short*)(base + o2); o2 += (size_t)Bc * 110592;
    short* x2h = (short*)(base + o2); o2 += (size_t)Bc * 37632;
    short* x2l = (short*)(base + o2); o2 += (size_t)Bc * 37632;
    float* x3  = (float*)(base + o2); o2 += (size_t)Bc * 51200;
    float* cp  = (float*)(base + o2); o2 += (size_t)Bc * 40960;
    float* x4  = (float*)(base + o2);

    // zero all plane regions once (borders must read as exact zero)
    long long zwords = (long long)Bc * (2 * 110592 + 2 * 110592 + 2 * 37632) / 4;
    zero_kernel<<<2048, 256, 0, stream>>>((unsigned int*)x0h, zwords);

    for (int b0 = 0; b0 < Btot; b0 += Bc) {
        int t0 = Bc * 38400;
        einsum_pack<<<(t0 + 255) / 256, 256, 0, stream>>>(
            A + (size_t)b0 * 2048, S + (size_t)b0 * 4800, x0h, x0l, t0);

        int M1 = Bc * 100;
        conv_mfma<384, 10, 12, 12, 1, 0>
            <<<dim3((M1 + 127) / 128, 3), 256, 0, stream>>>(
                x0h, x0l, w1h, w1l, b1, x1h, x1l, nullptr, M1);

        int M2 = Bc * 25;
        conv_mfma<384, 5, 12, 7, 2, 0>
            <<<dim3((M2 + 127) / 128, 3), 256, 0, stream>>>(
                x1h, x1l, w2h, w2l, b2, x2h, x2l, nullptr, M2);

        conv_mfma<512, 5, 7, 1, 1, 1>
            <<<dim3((M2 + 127) / 128, 4), 256, 0, stream>>>(
                x2h, x2l, w3h, w3l, b3, nullptr, nullptr, x3, M2);

        if (Bc >= 64) {
            int nblk = (Bc / 64) * 8 * KS;
            gemm_splitk<12800, KS><<<dim3(nblk), 256, 0, stream>>>(x3, W4, cp, Bc, 512);
            int tr = Bc * 512;
            splitk_reduce_relu<KS><<<(tr + 255) / 256, 256, 0, stream>>>(cp, b4, x4, Bc, 512);
        } else {
            int t4 = Bc * 512;
            conv4_naive<<<(t4 + 255) / 256, 256, 0, stream>>>(x3, W4, b4, x4, t4);
        }

        int t5 = Bc * 10;
        linear_naive<<<(t5 + 255) / 256, 256, 0, stream>>>(
            x4, Wl, bl, outp + (size_t)b0 * 10, t5);
    }
}

// Round 11
// 846.652 us; speedup vs baseline: 58.0121x; 1.8474x over previous
//
#include <hip/hip_runtime.h>
#include <hip/hip_bf16.h>

// ---------------------------------------------------------------------------
// Decoder_SICA — ROUND 10: fix r10 staging (full 16-short units) + KS=25.
// 2-product MFMA convs (act bf16, wgt hi/lo), bf16 MFMA split-K conv4.
//   einsum(pack bf16) -> conv1(NT=128) -> conv2(NT=64,s2) -> conv3(NT=64,NCHW)
//   -> gemm4 (bf16 MFMA split-K, KS=25) -> reduce+bias+relu -> linear
// ---------------------------------------------------------------------------

typedef __attribute__((ext_vector_type(8))) short bf16x8;
typedef __attribute__((ext_vector_type(4))) float f32x4;

__device__ __forceinline__ void split_bf16(float v, short& hs, short& ls) {
    __hip_bfloat16 h = __float2bfloat16(v);
    float hf = __bfloat162float(h);
    __hip_bfloat16 l = __float2bfloat16(v - hf);
    hs = __builtin_bit_cast(short, h);
    ls = __builtin_bit_cast(short, l);
}
__device__ __forceinline__ short round_bf16(float v) {
    __hip_bfloat16 h = __float2bfloat16(v);
    return __builtin_bit_cast(short, h);
}

__global__ void zero_kernel(unsigned int* __restrict__ p, long long nwords)
{
    long long i = (long long)blockIdx.x * blockDim.x + threadIdx.x;
    long long stride = (long long)gridDim.x * blockDim.x;
    for (; i < nwords; i += stride) p[i] = 0u;
}

// W (OC,384,3,3) fp32 -> hi/lo bf16 [oc][t*384+ic]
__global__ void pack_w_kernel(const float* __restrict__ W,
                              short* __restrict__ wh, short* __restrict__ wl, int total)
{
    int idx = blockIdx.x * blockDim.x + threadIdx.x;
    if (idx >= total) return;
    int oc = idx / 3456, k = idx - oc * 3456;
    int t = k / 384, ic = k - t * 384;
    float v = W[((size_t)oc * 384 + ic) * 9 + t];
    short hs, ls; split_bf16(v, hs, ls);
    wh[idx] = hs; wl[idx] = ls;
}

// W4 (512,512,5,5) fp32 -> hi/lo bf16 [oc][k], k = ic*25+pix (already flat)
__global__ void pack_w4_kernel(const float* __restrict__ W,
                               short* __restrict__ wh, short* __restrict__ wl, int total)
{
    int idx = blockIdx.x * blockDim.x + threadIdx.x;
    if (idx >= total) return;
    short hs, ls; split_bf16(W[idx], hs, ls);
    wh[idx] = hs; wl[idx] = ls;
}

// einsum -> padded NHWC bf16 plane x0[b][12][12][384], interior only.
__global__ void einsum_pack(const float* __restrict__ A, const float* __restrict__ S,
                            short* __restrict__ oh, int total)
{
    int idx = blockIdx.x * blockDim.x + threadIdx.x;
    if (idx >= total) return;
    int b   = idx / 38400;
    int r   = idx - b * 38400;
    int pix = r / 384;
    int ch  = r - pix * 384;
    int y = pix / 10, x = pix - y * 10;
    int h = y / 5, p = y - h * 5;
    int w = x / 5, q = x - w * 5;
    int n = ch / 48, g = (ch / 3) % 16, o = ch % 3;
    const float* Ab = A + (size_t)b * 2048 + (size_t)(n * 64 + g * 4) * 4 + h * 2 + w;
    const float* Sb = S + ((size_t)(b * 64 + g * 4) * 3 + o) * 25 + p * 5 + q;
    float s = 0.f;
    #pragma unroll
    for (int c = 0; c < 4; ++c)
        s += Ab[c * 4] * Sb[c * 75];
    size_t d = ((size_t)(b * 12 + y + 1) * 12 + (x + 1)) * 384 + ch;
    oh[d] = round_bf16(s);
}

// Implicit-GEMM 3x3 conv via MFMA. A = bf16 activations, W = hi/lo bf16.
// Block: 128 pixels x NT oc, 4 waves (2x2), each 64 x NT/2.
// MODE 0: write padded NHWC bf16. MODE 1: write NCHW-flat bf16.
template<int OC_T, int HOUT, int HPIN, int HPOUT, int STRIDE, int MODE, int NT>
__global__ void __launch_bounds__(256)
conv_mfma(const short* __restrict__ in_h,
          const short* __restrict__ w_h, const short* __restrict__ w_l,
          const float* __restrict__ bias, short* __restrict__ out_h, int M_total)
{
    constexpr int IC = 384;
    constexpr int NF = NT / 32;                 // N-frags per wave
    constexpr int ROWS = 128 + 2 * NT;          // A rows + Wh rows + Wl rows
    constexpr int NU = (ROWS * 2) / 256;        // 16-short staging units / thread
    __shared__ short s[ROWS * 40];

    const int tid = threadIdx.x;
    const int M0 = blockIdx.x * 128;
    const int n0 = blockIdx.y * NT;

    const int lane = tid & 63;
    const int wid  = tid >> 6;
    const int wm = (wid & 1) * 64;
    const int wn = (wid >> 1) * (NT / 2);
    const int l15 = lane & 15, kg = lane >> 4;

    // staging descriptors: unit (row, half) loads 16 shorts
    const short* ubase[NU]; int udst[NU]; bool uisA[NU];
    #pragma unroll
    for (int j = 0; j < NU; ++j) {
        int u = tid + j * 256;
        int row = u >> 1, hf = u & 1;
        if (row < 128) {
            int P = M0 + row; if (P >= M_total) P = M_total - 1;
            int bb = P / (HOUT * HOUT), pr = P % (HOUT * HOUT);
            int py = pr / HOUT, px = pr - py * HOUT;
            ubase[j] = in_h + ((size_t)(bb * HPIN + py * STRIDE) * HPIN + px * STRIDE) * IC + hf * 16;
            uisA[j] = true;
        } else if (row < 128 + NT) {
            ubase[j] = w_h + (size_t)(n0 + row - 128) * 3456 + hf * 16;
            uisA[j] = false;
        } else {
            ubase[j] = w_l + (size_t)(n0 + row - 128 - NT) * 3456 + hf * 16;
            uisA[j] = false;
        }
        udst[j] = row * 40 + hf * 16;
    }

    f32x4 acc[4][NF];
    #pragma unroll
    for (int i = 0; i < 4; ++i)
        #pragma unroll
        for (int j = 0; j < NF; ++j)
            acc[i][j] = (f32x4){0.f, 0.f, 0.f, 0.f};

    for (int t = 0; t < 9; ++t) {
        const int aoff = ((t / 3) * HPIN + (t % 3)) * IC;
        const int woff = t * IC;
        for (int ic0 = 0; ic0 < IC; ic0 += 32) {
            #pragma unroll
            for (int j = 0; j < NU; ++j) {
                const short* src = ubase[j] + (uisA[j] ? aoff : woff) + ic0;
                *(bf16x8*)&s[udst[j]]     = *(const bf16x8*)src;
                *(bf16x8*)&s[udst[j] + 8] = *(const bf16x8*)(src + 8);
            }
            __syncthreads();

            bf16x8 af[4];
            #pragma unroll
            for (int mf = 0; mf < 4; ++mf)
                af[mf] = *(const bf16x8*)&s[(wm + mf * 16 + l15) * 40 + kg * 8];
            #pragma unroll
            for (int nf = 0; nf < NF; ++nf) {
                bf16x8 bh = *(const bf16x8*)&s[(128 + wn + nf * 16 + l15) * 40 + kg * 8];
                bf16x8 bl = *(const bf16x8*)&s[(128 + NT + wn + nf * 16 + l15) * 40 + kg * 8];
                #pragma unroll
                for (int mf = 0; mf < 4; ++mf) {
                    acc[mf][nf] = __builtin_amdgcn_mfma_f32_16x16x32_bf16(af[mf], bh, acc[mf][nf], 0, 0, 0);
                    acc[mf][nf] = __builtin_amdgcn_mfma_f32_16x16x32_bf16(af[mf], bl, acc[mf][nf], 0, 0, 0);
                }
            }
            __syncthreads();
        }
    }

    #pragma unroll
    for (int nf = 0; nf < NF; ++nf) {
        const int oc = n0 + wn + nf * 16 + l15;
        const float bv = bias[oc];
        #pragma unroll
        for (int mf = 0; mf < 4; ++mf) {
            #pragma unroll
            for (int j = 0; j < 4; ++j) {
                int m = M0 + wm + mf * 16 + kg * 4 + j;
                if (m < M_total) {
                    float v = acc[mf][nf][j] + bv;
                    v = v > 0.f ? v : 0.f;
                    int b2 = m / (HOUT * HOUT);
                    int pr2 = m % (HOUT * HOUT);
                    if (MODE == 0) {
                        int y2 = pr2 / HOUT, x2 = pr2 - y2 * HOUT;
                        size_t d = ((size_t)(b2 * HPOUT + y2 + 1) * HPOUT + (x2 + 1)) * OC_T + oc;
                        out_h[d] = round_bf16(v);
                    } else {
                        out_h[((size_t)b2 * OC_T + oc) * (HOUT * HOUT) + pr2] = round_bf16(v);
                    }
                }
            }
        }
    }
}

// Split-K bf16 MFMA GEMM for conv4. KS=25 -> KC=512 (16 k-steps, exact).
template<int KTOT, int KS>
__global__ void __launch_bounds__(256)
gemm4_mfma(const short* __restrict__ Ah, const short* __restrict__ Bh,
           const short* __restrict__ Bl, float* __restrict__ Cpart, int M)
{
    constexpr int KC = KTOT / KS;
    static_assert(KC % 32 == 0, "k-chunk must be divisible by 32");
    constexpr int ROWS = 384;
    __shared__ short s[ROWS * 40];
    const int tid = threadIdx.x;
    const int nM = (M + 127) / 128;
    const int ks = blockIdx.x / (nM * 4);
    const int rb = blockIdx.x % (nM * 4);
    const int M0 = (rb / 4) * 128;
    const int n0 = (rb % 4) * 128;
    const int kbase = ks * KC;

    const int lane = tid & 63;
    const int wid  = tid >> 6;
    const int wm = (wid & 1) * 64;
    const int wn = (wid >> 1) * 64;
    const int l15 = lane & 15, kg = lane >> 4;

    const short* ubase[3]; int udst[3];
    #pragma unroll
    for (int j = 0; j < 3; ++j) {
        int u = tid + j * 256;
        int row = u >> 1, hf = u & 1;
        if (row < 128) {
            int P = M0 + row; if (P >= M) P = M - 1;
            ubase[j] = Ah + (size_t)P * KTOT + kbase + hf * 16;
        } else if (row < 256) {
            ubase[j] = Bh + (size_t)(n0 + row - 128) * KTOT + kbase + hf * 16;
        } else {
            ubase[j] = Bl + (size_t)(n0 + row - 256) * KTOT + kbase + hf * 16;
        }
        udst[j] = row * 40 + hf * 16;
    }

    f32x4 acc[4][4];
    #pragma unroll
    for (int i = 0; i < 4; ++i)
        #pragma unroll
        for (int j = 0; j < 4; ++j)
            acc[i][j] = (f32x4){0.f, 0.f, 0.f, 0.f};

    for (int k0 = 0; k0 < KC; k0 += 32) {
        #pragma unroll
        for (int j = 0; j < 3; ++j) {
            const short* src = ubase[j] + k0;
            *(bf16x8*)&s[udst[j]]     = *(const bf16x8*)src;
            *(bf16x8*)&s[udst[j] + 8] = *(const bf16x8*)(src + 8);
        }
        __syncthreads();
        bf16x8 af[4];
        #pragma unroll
        for (int mf = 0; mf < 4; ++mf)
            af[mf] = *(const bf16x8*)&s[(wm + mf * 16 + l15) * 40 + kg * 8];
        #pragma unroll
        for (int nf = 0; nf < 4; ++nf) {
            bf16x8 bh = *(const bf16x8*)&s[(128 + wn + nf * 16 + l15) * 40 + kg * 8];
            bf16x8 bl = *(const bf16x8*)&s[(256 + wn + nf * 16 + l15) * 40 + kg * 8];
            #pragma unroll
            for (int mf = 0; mf < 4; ++mf) {
                acc[mf][nf] = __builtin_amdgcn_mfma_f32_16x16x32_bf16(af[mf], bh, acc[mf][nf], 0, 0, 0);
                acc[mf][nf] = __builtin_amdgcn_mfma_f32_16x16x32_bf16(af[mf], bl, acc[mf][nf], 0, 0, 0);
            }
        }
        __syncthreads();
    }

    float* cp = Cpart + (size_t)ks * M * 512;
    #pragma unroll
    for (int nf = 0; nf < 4; ++nf) {
        const int n = n0 + wn + nf * 16 + l15;
        #pragma unroll
        for (int mf = 0; mf < 4; ++mf) {
            #pragma unroll
            for (int j = 0; j < 4; ++j) {
                int m = M0 + wm + mf * 16 + kg * 4 + j;
                if (m < M) cp[(size_t)m * 512 + n] = acc[mf][nf][j];
            }
        }
    }
}

template<int KS>
__global__ void splitk_reduce_relu(const float* __restrict__ Cpart,
                                   const float* __restrict__ bias,
                                   float* __restrict__ out, int M, int N)
{
    int idx = blockIdx.x * blockDim.x + threadIdx.x;
    if (idx >= M * N) return;
    int oc = idx % N;
    float s = bias[oc];
    #pragma unroll
    for (int ks = 0; ks < KS; ++ks)
        s += Cpart[(size_t)ks * M * N + idx];
    out[idx] = s > 0.f ? s : 0.f;
}

__global__ void linear_naive(const float* __restrict__ x, const float* __restrict__ Wl,
                             const float* __restrict__ bl,
                             float* __restrict__ out, int total)
{
    int idx = blockIdx.x * blockDim.x + threadIdx.x;
    if (idx >= total) return;
    int b = idx / 10, j = idx - b * 10;
    const float* xb = x  + (size_t)b * 512;
    const float* wj = Wl + (size_t)j * 512;
    float s = bl[j];
    for (int k = 0; k < 512; ++k)
        s += xb[k] * wj[k];
    out[idx] = s;
}

extern "C" void kernel_launch(void* const* d_in, const int* in_sizes, int n_in,
                              void* d_out, int out_size, void* d_ws, size_t ws_size,
                              hipStream_t stream)
{
    const float* A  = (const float*)d_in[0];
    const float* S  = (const float*)d_in[1];
    const float* W1 = (const float*)d_in[2];
    const float* b1 = (const float*)d_in[3];
    const float* W2 = (const float*)d_in[4];
    const float* b2 = (const float*)d_in[5];
    const float* W3 = (const float*)d_in[6];
    const float* b3 = (const float*)d_in[7];
    const float* W4 = (const float*)d_in[8];
    const float* b4 = (const float*)d_in[9];
    const float* Wl = (const float*)d_in[10];
    const float* bl = (const float*)d_in[11];
    float* outp = (float*)d_out;
    char* base = (char*)d_ws;

    const int Btot = 512;
    constexpr int KS = 25;                       // KC = 512, 16 exact k-steps

    const size_t W12N = (size_t)384 * 3456;
    const size_t W3N  = (size_t)512 * 3456;
    const size_t W4N  = (size_t)512 * 12800;
    size_t off = 0;
    short* w1h = (short*)(base + off); off += W12N * 2;
    short* w1l = (short*)(base + off); off += W12N * 2;
    short* w2h = (short*)(base + off); off += W12N * 2;
    short* w2l = (short*)(base + off); off += W12N * 2;
    short* w3h = (short*)(base + off); off += W3N * 2;
    short* w3l = (short*)(base + off); off += W3N * 2;
    short* w4h = (short*)(base + off); off += W4N * 2;
    short* w4l = (short*)(base + off); off += W4N * 2;
    const size_t wreg = off;

    // per-sample bytes: x0h 110592 + x1h 110592 + x2h 37632 + x3h 25600
    //                   + cp KS*512*4 (51200) + x4 2048 = 337,664
    const size_t PS = 337664;
    int Bc = 512;
    while (Bc > 8 && wreg + (size_t)Bc * PS > ws_size) Bc >>= 1;

    pack_w_kernel<<<(int)((W12N + 255) / 256), 256, 0, stream>>>(W1, w1h, w1l, (int)W12N);
    pack_w_kernel<<<(int)((W12N + 255) / 256), 256, 0, stream>>>(W2, w2h, w2l, (int)W12N);
    pack_w_kernel<<<(int)((W3N  + 255) / 256), 256, 0, stream>>>(W3, w3h, w3l, (int)W3N);
    pack_w4_kernel<<<(int)((W4N + 255) / 256), 256, 0, stream>>>(W4, w4h, w4l, (int)W4N);

    size_t o2 = wreg;
    short* x0h = (short*)(base + o2); o2 += (size_t)Bc * 110592;
    short* x1h = (short*)(base + o2); o2 += (size_t)Bc * 110592;
    short* x2h = (short*)(base + o2); o2 += (size_t)Bc * 37632;
    short* x3h = (short*)(base + o2); o2 += (size_t)Bc * 25600;
    float* cp  = (float*)(base + o2); o2 += (size_t)Bc * (KS * 512 * 4);
    float* x4  = (float*)(base + o2);

    // zero padded planes (borders must stay exact zero)
    long long zwords = (long long)Bc * (110592 + 110592 + 37632) / 4;
    zero_kernel<<<2048, 256, 0, stream>>>((unsigned int*)x0h, zwords);

    for (int b0 = 0; b0 < Btot; b0 += Bc) {
        int t0 = Bc * 38400;
        einsum_pack<<<(t0 + 255) / 256, 256, 0, stream>>>(
            A + (size_t)b0 * 2048, S + (size_t)b0 * 4800, x0h, t0);

        int M1 = Bc * 100;
        conv_mfma<384, 10, 12, 12, 1, 0, 128>
            <<<dim3((M1 + 127) / 128, 3), 256, 0, stream>>>(
                x0h, w1h, w1l, b1, x1h, M1);

        int M2 = Bc * 25;
        conv_mfma<384, 5, 12, 7, 2, 0, 64>
            <<<dim3((M2 + 127) / 128, 6), 256, 0, stream>>>(
                x1h, w2h, w2l, b2, x2h, M2);

        conv_mfma<512, 5, 7, 1, 1, 1, 64>
            <<<dim3((M2 + 127) / 128, 8), 256, 0, stream>>>(
                x2h, w3h, w3l, b3, x3h, M2);

        int nM = (Bc + 127) / 128;
        gemm4_mfma<12800, KS><<<dim3(KS * nM * 4), 256, 0, stream>>>(
            x3h, w4h, w4l, cp, Bc);
        int tr = Bc * 512;
        splitk_reduce_relu<KS><<<(tr + 255) / 256, 256, 0, stream>>>(
            cp, b4, x4, Bc, 512);

        int t5 = Bc * 10;
        linear_naive<<<(t5 + 255) / 256, 256, 0, stream>>>(
            x4, Wl, bl, outp + (size_t)b0 * 10, t5);
    }
}

// Round 12
// 816.715 us; speedup vs baseline: 60.1385x; 1.0367x over previous
//
#include <hip/hip_runtime.h>
#include <hip/hip_bf16.h>

// ---------------------------------------------------------------------------
// Decoder_SICA — ROUND 11: W direct-from-global in MFMA-fragment order,
// A LDS double-buffered, 1 barrier/k-step, 2-step B register pipeline.
// 2-product hi/lo weights (exactness), bf16 activations.
// ---------------------------------------------------------------------------

typedef __attribute__((ext_vector_type(8))) short bf16x8;
typedef __attribute__((ext_vector_type(4))) float f32x4;

__device__ __forceinline__ void split_bf16(float v, short& hs, short& ls) {
    __hip_bfloat16 h = __float2bfloat16(v);
    float hf = __bfloat162float(h);
    __hip_bfloat16 l = __float2bfloat16(v - hf);
    hs = __builtin_bit_cast(short, h);
    ls = __builtin_bit_cast(short, l);
}
__device__ __forceinline__ short round_bf16(float v) {
    __hip_bfloat16 h = __float2bfloat16(v);
    return __builtin_bit_cast(short, h);
}

__global__ void zero_kernel(unsigned int* __restrict__ p, long long nwords)
{
    long long i = (long long)blockIdx.x * blockDim.x + threadIdx.x;
    long long stride = (long long)gridDim.x * blockDim.x;
    for (; i < nwords; i += stride) p[i] = 0u;
}

// W (OC,384,3,3) fp32 -> fragment order: [oc/16][s=t*12+ic/32][lane=kg*16+l15][8]
__global__ void pack_w_frag(const float* __restrict__ W,
                            short* __restrict__ wh, short* __restrict__ wl, int total)
{
    int idx = blockIdx.x * blockDim.x + threadIdx.x;
    if (idx >= total) return;
    int oc = idx / 3456, r = idx - oc * 3456;
    int t = r / 384, ic = r - t * 384;
    float v = W[((size_t)oc * 384 + ic) * 9 + t];
    short hs, ls; split_bf16(v, hs, ls);
    int g16 = oc >> 4, l15 = oc & 15;
    int c = ic >> 5, kg = (ic >> 3) & 3, e = ic & 7;
    size_t d = (((size_t)g16 * 108 + (t * 12 + c)) * 64 + kg * 16 + l15) * 8 + e;
    wh[d] = hs; wl[d] = ls;
}

// W4 (512,12800) fp32 -> [oc/16][s=k/32][lane][8], NS=400
__global__ void pack_w4_frag(const float* __restrict__ W,
                             short* __restrict__ wh, short* __restrict__ wl, int total)
{
    int idx = blockIdx.x * blockDim.x + threadIdx.x;
    if (idx >= total) return;
    int oc = idx / 12800, k = idx - oc * 12800;
    short hs, ls; split_bf16(W[idx], hs, ls);
    int g16 = oc >> 4, l15 = oc & 15;
    int s = k >> 5, kg = (k >> 3) & 3, e = k & 7;
    size_t d = (((size_t)g16 * 400 + s) * 64 + kg * 16 + l15) * 8 + e;
    wh[d] = hs; wl[d] = ls;
}

// einsum -> padded NHWC bf16 plane x0[b][12][12][384], interior only.
__global__ void einsum_pack(const float* __restrict__ A, const float* __restrict__ S,
                            short* __restrict__ oh, int total)
{
    int idx = blockIdx.x * blockDim.x + threadIdx.x;
    if (idx >= total) return;
    int b   = idx / 38400;
    int r   = idx - b * 38400;
    int pix = r / 384;
    int ch  = r - pix * 384;
    int y = pix / 10, x = pix - y * 10;
    int h = y / 5, p = y - h * 5;
    int w = x / 5, q = x - w * 5;
    int n = ch / 48, g = (ch / 3) % 16, o = ch % 3;
    const float* Ab = A + (size_t)b * 2048 + (size_t)(n * 64 + g * 4) * 4 + h * 2 + w;
    const float* Sb = S + ((size_t)(b * 64 + g * 4) * 3 + o) * 25 + p * 5 + q;
    float s = 0.f;
    #pragma unroll
    for (int c = 0; c < 4; ++c)
        s += Ab[c * 4] * Sb[c * 75];
    size_t d = ((size_t)(b * 12 + y + 1) * 12 + (x + 1)) * 384 + ch;
    oh[d] = round_bf16(s);
}

// Implicit-GEMM 3x3 conv: A bf16 (LDS, double-buffered), W hi/lo pre-packed
// fragment-order (global, register-pipelined). Block 128 x NT, 4 waves.
template<int OC_T, int HOUT, int HPIN, int HPOUT, int STRIDE, int MODE, int NT>
__global__ void __launch_bounds__(256)
conv_mfma2(const short* __restrict__ in_h,
           const short* __restrict__ wph, const short* __restrict__ wpl,
           const float* __restrict__ bias, short* __restrict__ out_h, int M_total)
{
    constexpr int IC = 384;
    constexpr int NS = 108;
    constexpr int NF = NT / 32;
    __shared__ short s_a[2][128 * 40];

    const int tid = threadIdx.x;
    const int M0 = blockIdx.x * 128;
    const int n0 = blockIdx.y * NT;

    const int lane = tid & 63;
    const int wid  = tid >> 6;
    const int wm = (wid & 1) * 64;
    const int wn = (wid >> 1) * (NT / 2);
    const int l15 = lane & 15, kg = lane >> 4;

    // A staging: thread -> (row, 16-short half)
    const int arow = tid >> 1, ahf = tid & 1;
    int P = M0 + arow; if (P >= M_total) P = M_total - 1;
    const int bb = P / (HOUT * HOUT);
    const int pr = P % (HOUT * HOUT);
    const int py = pr / HOUT, px = pr - py * HOUT;
    const short* abase = in_h
        + ((size_t)(bb * HPIN + py * STRIDE) * HPIN + px * STRIDE) * IC + ahf * 16;
    const int adst = arow * 40 + ahf * 16;

    // packed-W lane pointers
    const short* wbh = wph + (size_t)((n0 + wn) >> 4) * (NS * 512) + lane * 8;
    const short* wbl = wpl + (size_t)((n0 + wn) >> 4) * (NS * 512) + lane * 8;

    f32x4 acc[4][NF];
    #pragma unroll
    for (int i = 0; i < 4; ++i)
        #pragma unroll
        for (int j = 0; j < NF; ++j)
            acc[i][j] = (f32x4){0.f, 0.f, 0.f, 0.f};

    auto stageA = [&](int s1, int buf) {
        int t = s1 / 12, c = s1 - t * 12;
        const short* src = abase + ((t / 3) * HPIN + (t % 3)) * IC + c * 32;
        *(bf16x8*)&s_a[buf][adst]     = *(const bf16x8*)src;
        *(bf16x8*)&s_a[buf][adst + 8] = *(const bf16x8*)(src + 8);
    };
    auto loadB = [&](int s, bf16x8 (&bh)[NF], bf16x8 (&bl)[NF]) {
        #pragma unroll
        for (int nf = 0; nf < NF; ++nf) {
            bh[nf] = *(const bf16x8*)(wbh + (size_t)nf * (NS * 512) + (size_t)s * 512);
            bl[nf] = *(const bf16x8*)(wbl + (size_t)nf * (NS * 512) + (size_t)s * 512);
        }
    };
    auto compute = [&](const bf16x8 (&bh)[NF], const bf16x8 (&bl)[NF], int buf) {
        bf16x8 af[4];
        #pragma unroll
        for (int mf = 0; mf < 4; ++mf)
            af[mf] = *(const bf16x8*)&s_a[buf][(wm + mf * 16 + l15) * 40 + kg * 8];
        #pragma unroll
        for (int nf = 0; nf < NF; ++nf)
            #pragma unroll
            for (int mf = 0; mf < 4; ++mf) {
                acc[mf][nf] = __builtin_amdgcn_mfma_f32_16x16x32_bf16(af[mf], bh[nf], acc[mf][nf], 0, 0, 0);
                acc[mf][nf] = __builtin_amdgcn_mfma_f32_16x16x32_bf16(af[mf], bl[nf], acc[mf][nf], 0, 0, 0);
            }
    };

    bf16x8 bhA[NF], blA[NF], bhB[NF], blB[NF];
    stageA(0, 0);
    loadB(0, bhA, blA);
    __syncthreads();

    for (int sp = 0; sp < NS; sp += 2) {
        stageA(sp + 1, 1);                       // NS even: sp+1 <= NS-1
        loadB(sp + 1, bhB, blB);
        compute(bhA, blA, 0);
        __syncthreads();
        if (sp + 2 < NS) { stageA(sp + 2, 0); loadB(sp + 2, bhA, blA); }
        compute(bhB, blB, 1);
        __syncthreads();
    }

    #pragma unroll
    for (int nf = 0; nf < NF; ++nf) {
        const int oc = n0 + wn + nf * 16 + l15;
        const float bv = bias[oc];
        #pragma unroll
        for (int mf = 0; mf < 4; ++mf) {
            #pragma unroll
            for (int j = 0; j < 4; ++j) {
                int m = M0 + wm + mf * 16 + kg * 4 + j;
                if (m < M_total) {
                    float v = acc[mf][nf][j] + bv;
                    v = v > 0.f ? v : 0.f;
                    int b2 = m / (HOUT * HOUT);
                    int pr2 = m % (HOUT * HOUT);
                    if (MODE == 0) {
                        int y2 = pr2 / HOUT, x2 = pr2 - y2 * HOUT;
                        size_t d = ((size_t)(b2 * HPOUT + y2 + 1) * HPOUT + (x2 + 1)) * OC_T + oc;
                        out_h[d] = round_bf16(v);
                    } else {
                        out_h[((size_t)b2 * OC_T + oc) * (HOUT * HOUT) + pr2] = round_bf16(v);
                    }
                }
            }
        }
    }
}

// Split-K bf16 MFMA GEMM for conv4, same structure. KS=25 -> 16 k-steps.
template<int KS>
__global__ void __launch_bounds__(256)
gemm4_mfma2(const short* __restrict__ Ah, const short* __restrict__ wph,
            const short* __restrict__ wpl, float* __restrict__ Cpart, int M)
{
    constexpr int NS4 = 400;
    constexpr int NSTEP = NS4 / KS;             // 16
    __shared__ short s_a[2][128 * 40];
    const int tid = threadIdx.x;
    const int nM = (M + 127) / 128;
    const int ks = blockIdx.x / (nM * 4);
    const int rb = blockIdx.x % (nM * 4);
    const int M0 = (rb / 4) * 128;
    const int n0 = (rb % 4) * 128;

    const int lane = tid & 63;
    const int wid  = tid >> 6;
    const int wm = (wid & 1) * 64;
    const int wn = (wid >> 1) * 64;
    const int l15 = lane & 15, kg = lane >> 4;

    const int arow = tid >> 1, ahf = tid & 1;
    int P = M0 + arow; if (P >= M) P = M - 1;
    const short* abase = Ah + (size_t)P * 12800 + ahf * 16;
    const int adst = arow * 40 + ahf * 16;

    const short* wbh = wph + (size_t)((n0 + wn) >> 4) * (NS4 * 512) + lane * 8;
    const short* wbl = wpl + (size_t)((n0 + wn) >> 4) * (NS4 * 512) + lane * 8;

    f32x4 acc[4][4];
    #pragma unroll
    for (int i = 0; i < 4; ++i)
        #pragma unroll
        for (int j = 0; j < 4; ++j)
            acc[i][j] = (f32x4){0.f, 0.f, 0.f, 0.f};

    auto stageA = [&](int j, int buf) {
        const short* src = abase + (size_t)(ks * NSTEP + j) * 32;
        *(bf16x8*)&s_a[buf][adst]     = *(const bf16x8*)src;
        *(bf16x8*)&s_a[buf][adst + 8] = *(const bf16x8*)(src + 8);
    };
    auto loadB = [&](int j, bf16x8 (&bh)[4], bf16x8 (&bl)[4]) {
        #pragma unroll
        for (int nf = 0; nf < 4; ++nf) {
            bh[nf] = *(const bf16x8*)(wbh + (size_t)nf * (NS4 * 512) + (size_t)(ks * NSTEP + j) * 512);
            bl[nf] = *(const bf16x8*)(wbl + (size_t)nf * (NS4 * 512) + (size_t)(ks * NSTEP + j) * 512);
        }
    };
    auto compute = [&](const bf16x8 (&bh)[4], const bf16x8 (&bl)[4], int buf) {
        bf16x8 af[4];
        #pragma unroll
        for (int mf = 0; mf < 4; ++mf)
            af[mf] = *(const bf16x8*)&s_a[buf][(wm + mf * 16 + l15) * 40 + kg * 8];
        #pragma unroll
        for (int nf = 0; nf < 4; ++nf)
            #pragma unroll
            for (int mf = 0; mf < 4; ++mf) {
                acc[mf][nf] = __builtin_amdgcn_mfma_f32_16x16x32_bf16(af[mf], bh[nf], acc[mf][nf], 0, 0, 0);
                acc[mf][nf] = __builtin_amdgcn_mfma_f32_16x16x32_bf16(af[mf], bl[nf], acc[mf][nf], 0, 0, 0);
            }
    };

    bf16x8 bhA[4], blA[4], bhB[4], blB[4];
    stageA(0, 0);
    loadB(0, bhA, blA);
    __syncthreads();
    for (int jp = 0; jp < NSTEP; jp += 2) {
        stageA(jp + 1, 1);
        loadB(jp + 1, bhB, blB);
        compute(bhA, blA, 0);
        __syncthreads();
        if (jp + 2 < NSTEP) { stageA(jp + 2, 0); loadB(jp + 2, bhA, blA); }
        compute(bhB, blB, 1);
        __syncthreads();
    }

    float* cp = Cpart + (size_t)ks * M * 512;
    #pragma unroll
    for (int nf = 0; nf < 4; ++nf) {
        const int n = n0 + wn + nf * 16 + l15;
        #pragma unroll
        for (int mf = 0; mf < 4; ++mf) {
            #pragma unroll
            for (int j = 0; j < 4; ++j) {
                int m = M0 + wm + mf * 16 + kg * 4 + j;
                if (m < M) cp[(size_t)m * 512 + n] = acc[mf][nf][j];
            }
        }
    }
}

template<int KS>
__global__ void splitk_reduce_relu(const float* __restrict__ Cpart,
                                   const float* __restrict__ bias,
                                   float* __restrict__ out, int M, int N)
{
    int idx = blockIdx.x * blockDim.x + threadIdx.x;
    if (idx >= M * N) return;
    int oc = idx % N;
    float s = bias[oc];
    #pragma unroll
    for (int ks = 0; ks < KS; ++ks)
        s += Cpart[(size_t)ks * M * N + idx];
    out[idx] = s > 0.f ? s : 0.f;
}

__global__ void linear_naive(const float* __restrict__ x, const float* __restrict__ Wl,
                             const float* __restrict__ bl,
                             float* __restrict__ out, int total)
{
    int idx = blockIdx.x * blockDim.x + threadIdx.x;
    if (idx >= total) return;
    int b = idx / 10, j = idx - b * 10;
    const float* xb = x  + (size_t)b * 512;
    const float* wj = Wl + (size_t)j * 512;
    float s = bl[j];
    for (int k = 0; k < 512; ++k)
        s += xb[k] * wj[k];
    out[idx] = s;
}

extern "C" void kernel_launch(void* const* d_in, const int* in_sizes, int n_in,
                              void* d_out, int out_size, void* d_ws, size_t ws_size,
                              hipStream_t stream)
{
    const float* A  = (const float*)d_in[0];
    const float* S  = (const float*)d_in[1];
    const float* W1 = (const float*)d_in[2];
    const float* b1 = (const float*)d_in[3];
    const float* W2 = (const float*)d_in[4];
    const float* b2 = (const float*)d_in[5];
    const float* W3 = (const float*)d_in[6];
    const float* b3 = (const float*)d_in[7];
    const float* W4 = (const float*)d_in[8];
    const float* b4 = (const float*)d_in[9];
    const float* Wl = (const float*)d_in[10];
    const float* bl = (const float*)d_in[11];
    float* outp = (float*)d_out;
    char* base = (char*)d_ws;

    const int Btot = 512;
    constexpr int KS = 25;

    const size_t W12N = (size_t)384 * 3456;
    const size_t W3N  = (size_t)512 * 3456;
    const size_t W4N  = (size_t)512 * 12800;
    size_t off = 0;
    short* w1h = (short*)(base + off); off += W12N * 2;
    short* w1l = (short*)(base + off); off += W12N * 2;
    short* w2h = (short*)(base + off); off += W12N * 2;
    short* w2l = (short*)(base + off); off += W12N * 2;
    short* w3h = (short*)(base + off); off += W3N * 2;
    short* w3l = (short*)(base + off); off += W3N * 2;
    short* w4h = (short*)(base + off); off += W4N * 2;
    short* w4l = (short*)(base + off); off += W4N * 2;
    const size_t wreg = off;

    const size_t PS = 337664;
    int Bc = 512;
    while (Bc > 8 && wreg + (size_t)Bc * PS > ws_size) Bc >>= 1;

    pack_w_frag<<<(int)((W12N + 255) / 256), 256, 0, stream>>>(W1, w1h, w1l, (int)W12N);
    pack_w_frag<<<(int)((W12N + 255) / 256), 256, 0, stream>>>(W2, w2h, w2l, (int)W12N);
    pack_w_frag<<<(int)((W3N  + 255) / 256), 256, 0, stream>>>(W3, w3h, w3l, (int)W3N);
    pack_w4_frag<<<(int)((W4N + 255) / 256), 256, 0, stream>>>(W4, w4h, w4l, (int)W4N);

    size_t o2 = wreg;
    short* x0h = (short*)(base + o2); o2 += (size_t)Bc * 110592;
    short* x1h = (short*)(base + o2); o2 += (size_t)Bc * 110592;
    short* x2h = (short*)(base + o2); o2 += (size_t)Bc * 37632;
    short* x3h = (short*)(base + o2); o2 += (size_t)Bc * 25600;
    float* cp  = (float*)(base + o2); o2 += (size_t)Bc * (KS * 512 * 4);
    float* x4  = (float*)(base + o2);

    long long zwords = (long long)Bc * (110592 + 110592 + 37632) / 4;
    zero_kernel<<<2048, 256, 0, stream>>>((unsigned int*)x0h, zwords);

    for (int b0 = 0; b0 < Btot; b0 += Bc) {
        int t0 = Bc * 38400;
        einsum_pack<<<(t0 + 255) / 256, 256, 0, stream>>>(
            A + (size_t)b0 * 2048, S + (size_t)b0 * 4800, x0h, t0);

        int M1 = Bc * 100;
        conv_mfma2<384, 10, 12, 12, 1, 0, 128>
            <<<dim3((M1 + 127) / 128, 3), 256, 0, stream>>>(
                x0h, w1h, w1l, b1, x1h, M1);

        int M2 = Bc * 25;
        conv_mfma2<384, 5, 12, 7, 2, 0, 64>
            <<<dim3((M2 + 127) / 128, 6), 256, 0, stream>>>(
                x1h, w2h, w2l, b2, x2h, M2);

        conv_mfma2<512, 5, 7, 1, 1, 1, 64>
            <<<dim3((M2 + 127) / 128, 8), 256, 0, stream>>>(
                x2h, w3h, w3l, b3, x3h, M2);

        int nM = (Bc + 127) / 128;
        gemm4_mfma2<KS><<<dim3(KS * nM * 4), 256, 0, stream>>>(
            x3h, w4h, w4l, cp, Bc);
        int tr = Bc * 512;
        splitk_reduce_relu<KS><<<(tr + 255) / 256, 256, 0, stream>>>(
            cp, b4, x4, Bc, 512);

        int t5 = Bc * 10;
        linear_naive<<<(t5 + 255) / 256, 256, 0, stream>>>(
            x4, Wl, bl, outp + (size_t)b0 * 10, t5);
    }
}

// Round 13
// 707.012 us; speedup vs baseline: 69.4699x; 1.1552x over previous
//
#include <hip/hip_runtime.h>
#include <hip/hip_bf16.h>

// ---------------------------------------------------------------------------
// Decoder_SICA — ROUND 12: single-product bf16 weights for convs (+XCD-chunked
// block swizzle, 1D grid). conv4 stays hi/lo split-K MFMA. fp32 in/out.
// ---------------------------------------------------------------------------

typedef __attribute__((ext_vector_type(8))) short bf16x8;
typedef __attribute__((ext_vector_type(4))) float f32x4;

__device__ __forceinline__ void split_bf16(float v, short& hs, short& ls) {
    __hip_bfloat16 h = __float2bfloat16(v);
    float hf = __bfloat162float(h);
    __hip_bfloat16 l = __float2bfloat16(v - hf);
    hs = __builtin_bit_cast(short, h);
    ls = __builtin_bit_cast(short, l);
}
__device__ __forceinline__ short round_bf16(float v) {
    __hip_bfloat16 h = __float2bfloat16(v);
    return __builtin_bit_cast(short, h);
}

// bijective XCD-chunk swizzle (m204): contiguous work chunk per XCD
__device__ __forceinline__ int xcd_swizzle(int bid, int total) {
    int q = total >> 3, r = total & 7;
    int xcd = bid & 7, idx = bid >> 3;
    return (xcd < r ? xcd * (q + 1) : r * (q + 1) + (xcd - r) * q) + idx;
}

__global__ void zero_kernel(unsigned int* __restrict__ p, long long nwords)
{
    long long i = (long long)blockIdx.x * blockDim.x + threadIdx.x;
    long long stride = (long long)gridDim.x * blockDim.x;
    for (; i < nwords; i += stride) p[i] = 0u;
}

// W (OC,384,3,3) fp32 -> bf16 fragment order [oc/16][s=t*12+ic/32][lane][8]
__global__ void pack_w_frag_h(const float* __restrict__ W,
                              short* __restrict__ wh, int total)
{
    int idx = blockIdx.x * blockDim.x + threadIdx.x;
    if (idx >= total) return;
    int oc = idx / 3456, r = idx - oc * 3456;
    int t = r / 384, ic = r - t * 384;
    float v = W[((size_t)oc * 384 + ic) * 9 + t];
    int g16 = oc >> 4, l15 = oc & 15;
    int c = ic >> 5, kg = (ic >> 3) & 3, e = ic & 7;
    size_t d = (((size_t)g16 * 108 + (t * 12 + c)) * 64 + kg * 16 + l15) * 8 + e;
    wh[d] = round_bf16(v);
}

// W4 (512,12800) fp32 -> hi/lo [oc/16][s=k/32][lane][8], NS=400
__global__ void pack_w4_frag(const float* __restrict__ W,
                             short* __restrict__ wh, short* __restrict__ wl, int total)
{
    int idx = blockIdx.x * blockDim.x + threadIdx.x;
    if (idx >= total) return;
    int oc = idx / 12800, k = idx - oc * 12800;
    short hs, ls; split_bf16(W[idx], hs, ls);
    int g16 = oc >> 4, l15 = oc & 15;
    int s = k >> 5, kg = (k >> 3) & 3, e = k & 7;
    size_t d = (((size_t)g16 * 400 + s) * 64 + kg * 16 + l15) * 8 + e;
    wh[d] = hs; wl[d] = ls;
}

// einsum -> padded NHWC bf16 plane x0[b][12][12][384], interior only.
__global__ void einsum_pack(const float* __restrict__ A, const float* __restrict__ S,
                            short* __restrict__ oh, int total)
{
    int idx = blockIdx.x * blockDim.x + threadIdx.x;
    if (idx >= total) return;
    int b   = idx / 38400;
    int r   = idx - b * 38400;
    int pix = r / 384;
    int ch  = r - pix * 384;
    int y = pix / 10, x = pix - y * 10;
    int h = y / 5, p = y - h * 5;
    int w = x / 5, q = x - w * 5;
    int n = ch / 48, g = (ch / 3) % 16, o = ch % 3;
    const float* Ab = A + (size_t)b * 2048 + (size_t)(n * 64 + g * 4) * 4 + h * 2 + w;
    const float* Sb = S + ((size_t)(b * 64 + g * 4) * 3 + o) * 25 + p * 5 + q;
    float s = 0.f;
    #pragma unroll
    for (int c = 0; c < 4; ++c)
        s += Ab[c * 4] * Sb[c * 75];
    size_t d = ((size_t)(b * 12 + y + 1) * 12 + (x + 1)) * 384 + ch;
    oh[d] = round_bf16(s);
}

// Implicit-GEMM 3x3 conv: A bf16 (LDS dbuf), W bf16 pre-packed frag-order
// (global, register-pipelined, single product). 1D grid, XCD-chunk swizzled.
template<int OC_T, int HOUT, int HPIN, int HPOUT, int STRIDE, int MODE, int NT>
__global__ void __launch_bounds__(256)
conv_mfma3(const short* __restrict__ in_h, const short* __restrict__ wph,
           const float* __restrict__ bias, short* __restrict__ out_h, int M_total)
{
    constexpr int IC = 384;
    constexpr int NS = 108;
    constexpr int NF = NT / 32;
    __shared__ short s_a[2][128 * 40];

    const int nMx = (M_total + 127) >> 7;
    const int swz = xcd_swizzle(blockIdx.x, gridDim.x);
    const int M0 = (swz % nMx) * 128;
    const int n0 = (swz / nMx) * NT;

    const int tid = threadIdx.x;
    const int lane = tid & 63;
    const int wid  = tid >> 6;
    const int wm = (wid & 1) * 64;
    const int wn = (wid >> 1) * (NT / 2);
    const int l15 = lane & 15, kg = lane >> 4;

    const int arow = tid >> 1, ahf = tid & 1;
    int P = M0 + arow; if (P >= M_total) P = M_total - 1;
    const int bb = P / (HOUT * HOUT);
    const int pr = P % (HOUT * HOUT);
    const int py = pr / HOUT, px = pr - py * HOUT;
    const short* abase = in_h
        + ((size_t)(bb * HPIN + py * STRIDE) * HPIN + px * STRIDE) * IC + ahf * 16;
    const int adst = arow * 40 + ahf * 16;

    const short* wbh = wph + (size_t)((n0 + wn) >> 4) * (NS * 512) + lane * 8;

    f32x4 acc[4][NF];
    #pragma unroll
    for (int i = 0; i < 4; ++i)
        #pragma unroll
        for (int j = 0; j < NF; ++j)
            acc[i][j] = (f32x4){0.f, 0.f, 0.f, 0.f};

    auto stageA = [&](int s1, int buf) {
        int t = s1 / 12, c = s1 - t * 12;
        const short* src = abase + ((t / 3) * HPIN + (t % 3)) * IC + c * 32;
        *(bf16x8*)&s_a[buf][adst]     = *(const bf16x8*)src;
        *(bf16x8*)&s_a[buf][adst + 8] = *(const bf16x8*)(src + 8);
    };
    auto loadB = [&](int s, bf16x8 (&bh)[NF]) {
        #pragma unroll
        for (int nf = 0; nf < NF; ++nf)
            bh[nf] = *(const bf16x8*)(wbh + (size_t)nf * (NS * 512) + (size_t)s * 512);
    };
    auto compute = [&](const bf16x8 (&bh)[NF], int buf) {
        bf16x8 af[4];
        #pragma unroll
        for (int mf = 0; mf < 4; ++mf)
            af[mf] = *(const bf16x8*)&s_a[buf][(wm + mf * 16 + l15) * 40 + kg * 8];
        #pragma unroll
        for (int nf = 0; nf < NF; ++nf)
            #pragma unroll
            for (int mf = 0; mf < 4; ++mf)
                acc[mf][nf] = __builtin_amdgcn_mfma_f32_16x16x32_bf16(af[mf], bh[nf], acc[mf][nf], 0, 0, 0);
    };

    bf16x8 bhA[NF], bhB[NF];
    stageA(0, 0);
    loadB(0, bhA);
    __syncthreads();

    for (int sp = 0; sp < NS; sp += 2) {
        stageA(sp + 1, 1);                       // NS even: sp+1 <= NS-1
        loadB(sp + 1, bhB);
        compute(bhA, 0);
        __syncthreads();
        if (sp + 2 < NS) { stageA(sp + 2, 0); loadB(sp + 2, bhA); }
        compute(bhB, 1);
        __syncthreads();
    }

    #pragma unroll
    for (int nf = 0; nf < NF; ++nf) {
        const int oc = n0 + wn + nf * 16 + l15;
        const float bv = bias[oc];
        #pragma unroll
        for (int mf = 0; mf < 4; ++mf) {
            #pragma unroll
            for (int j = 0; j < 4; ++j) {
                int m = M0 + wm + mf * 16 + kg * 4 + j;
                if (m < M_total) {
                    float v = acc[mf][nf][j] + bv;
                    v = v > 0.f ? v : 0.f;
                    int b2 = m / (HOUT * HOUT);
                    int pr2 = m % (HOUT * HOUT);
                    if (MODE == 0) {
                        int y2 = pr2 / HOUT, x2 = pr2 - y2 * HOUT;
                        size_t d = ((size_t)(b2 * HPOUT + y2 + 1) * HPOUT + (x2 + 1)) * OC_T + oc;
                        out_h[d] = round_bf16(v);
                    } else {
                        out_h[((size_t)b2 * OC_T + oc) * (HOUT * HOUT) + pr2] = round_bf16(v);
                    }
                }
            }
        }
    }
}

// Split-K bf16 MFMA GEMM for conv4 (hi/lo kept). KS=25 -> 16 k-steps.
template<int KS>
__global__ void __launch_bounds__(256)
gemm4_mfma2(const short* __restrict__ Ah, const short* __restrict__ wph,
            const short* __restrict__ wpl, float* __restrict__ Cpart, int M)
{
    constexpr int NS4 = 400;
    constexpr int NSTEP = NS4 / KS;             // 16
    __shared__ short s_a[2][128 * 40];
    const int tid = threadIdx.x;
    const int nM = (M + 127) / 128;
    const int ks = blockIdx.x / (nM * 4);
    const int rb = blockIdx.x % (nM * 4);
    const int M0 = (rb / 4) * 128;
    const int n0 = (rb % 4) * 128;

    const int lane = tid & 63;
    const int wid  = tid >> 6;
    const int wm = (wid & 1) * 64;
    const int wn = (wid >> 1) * 64;
    const int l15 = lane & 15, kg = lane >> 4;

    const int arow = tid >> 1, ahf = tid & 1;
    int P = M0 + arow; if (P >= M) P = M - 1;
    const short* abase = Ah + (size_t)P * 12800 + ahf * 16;
    const int adst = arow * 40 + ahf * 16;

    const short* wbh = wph + (size_t)((n0 + wn) >> 4) * (NS4 * 512) + lane * 8;
    const short* wbl = wpl + (size_t)((n0 + wn) >> 4) * (NS4 * 512) + lane * 8;

    f32x4 acc[4][4];
    #pragma unroll
    for (int i = 0; i < 4; ++i)
        #pragma unroll
        for (int j = 0; j < 4; ++j)
            acc[i][j] = (f32x4){0.f, 0.f, 0.f, 0.f};

    auto stageA = [&](int j, int buf) {
        const short* src = abase + (size_t)(ks * NSTEP + j) * 32;
        *(bf16x8*)&s_a[buf][adst]     = *(const bf16x8*)src;
        *(bf16x8*)&s_a[buf][adst + 8] = *(const bf16x8*)(src + 8);
    };
    auto loadB = [&](int j, bf16x8 (&bh)[4], bf16x8 (&bl)[4]) {
        #pragma unroll
        for (int nf = 0; nf < 4; ++nf) {
            bh[nf] = *(const bf16x8*)(wbh + (size_t)nf * (NS4 * 512) + (size_t)(ks * NSTEP + j) * 512);
            bl[nf] = *(const bf16x8*)(wbl + (size_t)nf * (NS4 * 512) + (size_t)(ks * NSTEP + j) * 512);
        }
    };
    auto compute = [&](const bf16x8 (&bh)[4], const bf16x8 (&bl)[4], int buf) {
        bf16x8 af[4];
        #pragma unroll
        for (int mf = 0; mf < 4; ++mf)
            af[mf] = *(const bf16x8*)&s_a[buf][(wm + mf * 16 + l15) * 40 + kg * 8];
        #pragma unroll
        for (int nf = 0; nf < 4; ++nf)
            #pragma unroll
            for (int mf = 0; mf < 4; ++mf) {
                acc[mf][nf] = __builtin_amdgcn_mfma_f32_16x16x32_bf16(af[mf], bh[nf], acc[mf][nf], 0, 0, 0);
                acc[mf][nf] = __builtin_amdgcn_mfma_f32_16x16x32_bf16(af[mf], bl[nf], acc[mf][nf], 0, 0, 0);
            }
    };

    bf16x8 bhA[4], blA[4], bhB[4], blB[4];
    stageA(0, 0);
    loadB(0, bhA, blA);
    __syncthreads();
    for (int jp = 0; jp < NSTEP; jp += 2) {
        stageA(jp + 1, 1);
        loadB(jp + 1, bhB, blB);
        compute(bhA, blA, 0);
        __syncthreads();
        if (jp + 2 < NSTEP) { stageA(jp + 2, 0); loadB(jp + 2, bhA, blA); }
        compute(bhB, blB, 1);
        __syncthreads();
    }

    float* cp = Cpart + (size_t)ks * M * 512;
    #pragma unroll
    for (int nf = 0; nf < 4; ++nf) {
        const int n = n0 + wn + nf * 16 + l15;
        #pragma unroll
        for (int mf = 0; mf < 4; ++mf) {
            #pragma unroll
            for (int j = 0; j < 4; ++j) {
                int m = M0 + wm + mf * 16 + kg * 4 + j;
                if (m < M) cp[(size_t)m * 512 + n] = acc[mf][nf][j];
            }
        }
    }
}

template<int KS>
__global__ void splitk_reduce_relu(const float* __restrict__ Cpart,
                                   const float* __restrict__ bias,
                                   float* __restrict__ out, int M, int N)
{
    int idx = blockIdx.x * blockDim.x + threadIdx.x;
    if (idx >= M * N) return;
    int oc = idx % N;
    float s = bias[oc];
    #pragma unroll
    for (int ks = 0; ks < KS; ++ks)
        s += Cpart[(size_t)ks * M * N + idx];
    out[idx] = s > 0.f ? s : 0.f;
}

__global__ void linear_naive(const float* __restrict__ x, const float* __restrict__ Wl,
                             const float* __restrict__ bl,
                             float* __restrict__ out, int total)
{
    int idx = blockIdx.x * blockDim.x + threadIdx.x;
    if (idx >= total) return;
    int b = idx / 10, j = idx - b * 10;
    const float* xb = x  + (size_t)b * 512;
    const float* wj = Wl + (size_t)j * 512;
    float s = bl[j];
    for (int k = 0; k < 512; ++k)
        s += xb[k] * wj[k];
    out[idx] = s;
}

extern "C" void kernel_launch(void* const* d_in, const int* in_sizes, int n_in,
                              void* d_out, int out_size, void* d_ws, size_t ws_size,
                              hipStream_t stream)
{
    const float* A  = (const float*)d_in[0];
    const float* S  = (const float*)d_in[1];
    const float* W1 = (const float*)d_in[2];
    const float* b1 = (const float*)d_in[3];
    const float* W2 = (const float*)d_in[4];
    const float* b2 = (const float*)d_in[5];
    const float* W3 = (const float*)d_in[6];
    const float* b3 = (const float*)d_in[7];
    const float* W4 = (const float*)d_in[8];
    const float* b4 = (const float*)d_in[9];
    const float* Wl = (const float*)d_in[10];
    const float* bl = (const float*)d_in[11];
    float* outp = (float*)d_out;
    char* base = (char*)d_ws;

    const int Btot = 512;
    constexpr int KS = 25;

    const size_t W12N = (size_t)384 * 3456;
    const size_t W3N  = (size_t)512 * 3456;
    const size_t W4N  = (size_t)512 * 12800;
    size_t off = 0;
    short* w1h = (short*)(base + off); off += W12N * 2;
    short* w2h = (short*)(base + off); off += W12N * 2;
    short* w3h = (short*)(base + off); off += W3N * 2;
    short* w4h = (short*)(base + off); off += W4N * 2;
    short* w4l = (short*)(base + off); off += W4N * 2;
    const size_t wreg = off;

    const size_t PS = 337664;
    int Bc = 512;
    while (Bc > 8 && wreg + (size_t)Bc * PS > ws_size) Bc >>= 1;

    pack_w_frag_h<<<(int)((W12N + 255) / 256), 256, 0, stream>>>(W1, w1h, (int)W12N);
    pack_w_frag_h<<<(int)((W12N + 255) / 256), 256, 0, stream>>>(W2, w2h, (int)W12N);
    pack_w_frag_h<<<(int)((W3N  + 255) / 256), 256, 0, stream>>>(W3, w3h, (int)W3N);
    pack_w4_frag<<<(int)((W4N + 255) / 256), 256, 0, stream>>>(W4, w4h, w4l, (int)W4N);

    size_t o2 = wreg;
    short* x0h = (short*)(base + o2); o2 += (size_t)Bc * 110592;
    short* x1h = (short*)(base + o2); o2 += (size_t)Bc * 110592;
    short* x2h = (short*)(base + o2); o2 += (size_t)Bc * 37632;
    short* x3h = (short*)(base + o2); o2 += (size_t)Bc * 25600;
    float* cp  = (float*)(base + o2); o2 += (size_t)Bc * (KS * 512 * 4);
    float* x4  = (float*)(base + o2);

    long long zwords = (long long)Bc * (110592 + 110592 + 37632) / 4;
    zero_kernel<<<2048, 256, 0, stream>>>((unsigned int*)x0h, zwords);

    for (int b0 = 0; b0 < Btot; b0 += Bc) {
        int t0 = Bc * 38400;
        einsum_pack<<<(t0 + 255) / 256, 256, 0, stream>>>(
            A + (size_t)b0 * 2048, S + (size_t)b0 * 4800, x0h, t0);

        int M1 = Bc * 100;
        int nMx1 = (M1 + 127) / 128;
        conv_mfma3<384, 10, 12, 12, 1, 0, 128>
            <<<dim3(nMx1 * 3), 256, 0, stream>>>(x0h, w1h, b1, x1h, M1);

        int M2 = Bc * 25;
        int nMx2 = (M2 + 127) / 128;
        conv_mfma3<384, 5, 12, 7, 2, 0, 64>
            <<<dim3(nMx2 * 6), 256, 0, stream>>>(x1h, w2h, b2, x2h, M2);

        conv_mfma3<512, 5, 7, 1, 1, 1, 64>
            <<<dim3(nMx2 * 8), 256, 0, stream>>>(x2h, w3h, b3, x3h, M2);

        int nM = (Bc + 127) / 128;
        gemm4_mfma2<KS><<<dim3(KS * nM * 4), 256, 0, stream>>>(
            x3h, w4h, w4l, cp, Bc);
        int tr = Bc * 512;
        splitk_reduce_relu<KS><<<(tr + 255) / 256, 256, 0, stream>>>(
            cp, b4, x4, Bc, 512);

        int t5 = Bc * 10;
        linear_naive<<<(t5 + 255) / 256, 256, 0, stream>>>(
            x4, Wl, bl, outp + (size_t)b0 * 10, t5);
    }
}

// Round 14
// 613.688 us; speedup vs baseline: 80.0342x; 1.1521x over previous
//
#include <hip/hip_runtime.h>
#include <hip/hip_bf16.h>

// ---------------------------------------------------------------------------
// Decoder_SICA — ROUND 13: tap-stationary LDS A-staging (stage window once,
// 9 taps read shifted) + m-major XCD-chunk swizzle (oc-groups share A in L2).
// Single-product bf16 conv weights; conv4 hi/lo split-K MFMA. fp32 in/out.
// ---------------------------------------------------------------------------

typedef __attribute__((ext_vector_type(8))) short bf16x8;
typedef __attribute__((ext_vector_type(4))) float f32x4;

__device__ __forceinline__ void split_bf16(float v, short& hs, short& ls) {
    __hip_bfloat16 h = __float2bfloat16(v);
    float hf = __bfloat162float(h);
    __hip_bfloat16 l = __float2bfloat16(v - hf);
    hs = __builtin_bit_cast(short, h);
    ls = __builtin_bit_cast(short, l);
}
__device__ __forceinline__ short round_bf16(float v) {
    __hip_bfloat16 h = __float2bfloat16(v);
    return __builtin_bit_cast(short, h);
}

// bijective XCD-chunk swizzle (m204): contiguous work chunk per XCD
__device__ __forceinline__ int xcd_swizzle(int bid, int total) {
    int q = total >> 3, r = total & 7;
    int xcd = bid & 7, idx = bid >> 3;
    return (xcd < r ? xcd * (q + 1) : r * (q + 1) + (xcd - r) * q) + idx;
}

__global__ void zero_kernel(unsigned int* __restrict__ p, long long nwords)
{
    long long i = (long long)blockIdx.x * blockDim.x + threadIdx.x;
    long long stride = (long long)gridDim.x * blockDim.x;
    for (; i < nwords; i += stride) p[i] = 0u;
}

// W (OC,384,3,3) fp32 -> bf16 fragment order [oc/16][s=t*12+ic/32][lane][8]
__global__ void pack_w_frag_h(const float* __restrict__ W,
                              short* __restrict__ wh, int total)
{
    int idx = blockIdx.x * blockDim.x + threadIdx.x;
    if (idx >= total) return;
    int oc = idx / 3456, r = idx - oc * 3456;
    int t = r / 384, ic = r - t * 384;
    float v = W[((size_t)oc * 384 + ic) * 9 + t];
    int g16 = oc >> 4, l15 = oc & 15;
    int c = ic >> 5, kg = (ic >> 3) & 3, e = ic & 7;
    size_t d = (((size_t)g16 * 108 + (t * 12 + c)) * 64 + kg * 16 + l15) * 8 + e;
    wh[d] = round_bf16(v);
}

// W4 (512,12800) fp32 -> hi/lo [oc/16][s=k/32][lane][8], NS=400
__global__ void pack_w4_frag(const float* __restrict__ W,
                             short* __restrict__ wh, short* __restrict__ wl, int total)
{
    int idx = blockIdx.x * blockDim.x + threadIdx.x;
    if (idx >= total) return;
    int oc = idx / 12800, k = idx - oc * 12800;
    short hs, ls; split_bf16(W[idx], hs, ls);
    int g16 = oc >> 4, l15 = oc & 15;
    int s = k >> 5, kg = (k >> 3) & 3, e = k & 7;
    size_t d = (((size_t)g16 * 400 + s) * 64 + kg * 16 + l15) * 8 + e;
    wh[d] = hs; wl[d] = ls;
}

// einsum -> padded NHWC bf16 plane x0[b][12][12][384], interior only.
__global__ void einsum_pack(const float* __restrict__ A, const float* __restrict__ S,
                            short* __restrict__ oh, int total)
{
    int idx = blockIdx.x * blockDim.x + threadIdx.x;
    if (idx >= total) return;
    int b   = idx / 38400;
    int r   = idx - b * 38400;
    int pix = r / 384;
    int ch  = r - pix * 384;
    int y = pix / 10, x = pix - y * 10;
    int h = y / 5, p = y - h * 5;
    int w = x / 5, q = x - w * 5;
    int n = ch / 48, g = (ch / 3) % 16, o = ch % 3;
    const float* Ab = A + (size_t)b * 2048 + (size_t)(n * 64 + g * 4) * 4 + h * 2 + w;
    const float* Sb = S + ((size_t)(b * 64 + g * 4) * 3 + o) * 25 + p * 5 + q;
    float s = 0.f;
    #pragma unroll
    for (int c = 0; c < 4; ++c)
        s += Ab[c * 4] * Sb[c * 75];
    size_t d = ((size_t)(b * 12 + y + 1) * 12 + (x + 1)) * 384 + ch;
    oh[d] = round_bf16(s);
}

// Tap-stationary implicit-GEMM 3x3 conv. Block = NSAMP samples (M_BLK=100 px,
// padded to 128 MFMA rows) x NT oc. Patch staged in LDS once per ic-chunk,
// 9 taps read row-shifted. W bf16 frag-order from global, 1-tap prefetch.
template<int OC_T, int HOUT, int HPIN, int HPOUT, int STRIDE, int MODE, int NT, int NSAMP>
__global__ void __launch_bounds__(256)
conv_mfma4(const short* __restrict__ in_h, const short* __restrict__ wph,
           const float* __restrict__ bias, short* __restrict__ out_h)
{
    constexpr int IC = 384;
    constexpr int NS = 108;
    constexpr int NF = NT / 32;
    constexpr int PIX = HOUT * HOUT;
    constexpr int M_BLK = NSAMP * PIX;          // 100
    constexpr int PROWS = NSAMP * HPIN * HPIN;
    constexpr int G = OC_T / NT;
    constexpr int NU = (PROWS * 2 + 255) / 256;
    __shared__ short s_a[PROWS * 40];

    const int swz = xcd_swizzle(blockIdx.x, gridDim.x);
    const int mt = swz / G;                     // m-major: oc-groups adjacent
    const int g  = swz % G;
    const int n0 = g * NT;
    const int bb0 = mt * NSAMP;

    const int tid = threadIdx.x;
    const int lane = tid & 63;
    const int wid  = tid >> 6;
    const int wm = (wid & 1) * 64;
    const int wn = (wid >> 1) * (NT / 2);
    const int l15 = lane & 15, kg = lane >> 4;

    // staging descriptors: unit (row, 16-short half)
    size_t usrc[NU]; int udst[NU]; bool uval[NU];
    #pragma unroll
    for (int j = 0; j < NU; ++j) {
        int u = tid + j * 256;
        int row = u >> 1, hf = u & 1;
        uval[j] = row < PROWS;
        int rc = uval[j] ? row : 0;
        int sN = rc / (HPIN * HPIN), rr = rc % (HPIN * HPIN);
        usrc[j] = ((size_t)(bb0 + sN) * (HPIN * HPIN) + rr) * IC + hf * 16;
        udst[j] = rc * 40 + hf * 16;
    }

    // per-mf patch row bases
    int prow[4];
    #pragma unroll
    for (int mf = 0; mf < 4; ++mf) {
        int p = wm + mf * 16 + l15;
        int pc = p < M_BLK ? p : M_BLK - 1;
        int sN = pc / PIX, pr = pc % PIX;
        int py = pr / HOUT, px = pr - py * HOUT;
        prow[mf] = sN * (HPIN * HPIN) + py * STRIDE * HPIN + px * STRIDE;
    }

    const short* wb = wph + (size_t)((n0 + wn) >> 4) * (NS * 512) + lane * 8;

    f32x4 acc[4][NF];
    #pragma unroll
    for (int i = 0; i < 4; ++i)
        #pragma unroll
        for (int j = 0; j < NF; ++j)
            acc[i][j] = (f32x4){0.f, 0.f, 0.f, 0.f};

    for (int c = 0; c < 12; ++c) {
        if (c) __syncthreads();
        #pragma unroll
        for (int j = 0; j < NU; ++j) if (uval[j]) {
            const short* src = in_h + usrc[j] + c * 32;
            *(bf16x8*)&s_a[udst[j]]     = *(const bf16x8*)src;
            *(bf16x8*)&s_a[udst[j] + 8] = *(const bf16x8*)(src + 8);
        }
        __syncthreads();

        bf16x8 bcur[NF], bnxt[NF];
        #pragma unroll
        for (int nf = 0; nf < NF; ++nf)
            bcur[nf] = *(const bf16x8*)(wb + (size_t)nf * (NS * 512) + (size_t)c * 512);
        #pragma unroll
        for (int t = 0; t < 9; ++t) {
            if (t < 8) {
                #pragma unroll
                for (int nf = 0; nf < NF; ++nf)
                    bnxt[nf] = *(const bf16x8*)(wb + (size_t)nf * (NS * 512)
                                                + (size_t)((t + 1) * 12 + c) * 512);
            }
            const int troff = (t / 3) * HPIN + (t % 3);
            bf16x8 af[4];
            #pragma unroll
            for (int mf = 0; mf < 4; ++mf)
                af[mf] = *(const bf16x8*)&s_a[(prow[mf] + troff) * 40 + kg * 8];
            #pragma unroll
            for (int nf = 0; nf < NF; ++nf)
                #pragma unroll
                for (int mf = 0; mf < 4; ++mf)
                    acc[mf][nf] = __builtin_amdgcn_mfma_f32_16x16x32_bf16(
                        af[mf], bcur[nf], acc[mf][nf], 0, 0, 0);
            #pragma unroll
            for (int nf = 0; nf < NF; ++nf) bcur[nf] = bnxt[nf];
        }
    }

    #pragma unroll
    for (int nf = 0; nf < NF; ++nf) {
        const int oc = n0 + wn + nf * 16 + l15;
        const float bv = bias[oc];
        #pragma unroll
        for (int mf = 0; mf < 4; ++mf) {
            #pragma unroll
            for (int j = 0; j < 4; ++j) {
                int p_out = wm + mf * 16 + kg * 4 + j;
                if (p_out < M_BLK) {
                    float v = acc[mf][nf][j] + bv;
                    v = v > 0.f ? v : 0.f;
                    int b2 = bb0 + p_out / PIX;
                    int pr2 = p_out % PIX;
                    if (MODE == 0) {
                        int y2 = pr2 / HOUT, x2 = pr2 - y2 * HOUT;
                        size_t d = ((size_t)(b2 * HPOUT + y2 + 1) * HPOUT + (x2 + 1)) * OC_T + oc;
                        out_h[d] = round_bf16(v);
                    } else {
                        out_h[((size_t)b2 * OC_T + oc) * PIX + pr2] = round_bf16(v);
                    }
                }
            }
        }
    }
}

// Split-K bf16 MFMA GEMM for conv4 (hi/lo). KS=25 -> 16 k-steps.
template<int KS>
__global__ void __launch_bounds__(256)
gemm4_mfma2(const short* __restrict__ Ah, const short* __restrict__ wph,
            const short* __restrict__ wpl, float* __restrict__ Cpart, int M)
{
    constexpr int NS4 = 400;
    constexpr int NSTEP = NS4 / KS;             // 16
    __shared__ short s_a[2][128 * 40];
    const int tid = threadIdx.x;
    const int nM = (M + 127) / 128;
    const int ks = blockIdx.x / (nM * 4);
    const int rb = blockIdx.x % (nM * 4);
    const int M0 = (rb / 4) * 128;
    const int n0 = (rb % 4) * 128;

    const int lane = tid & 63;
    const int wid  = tid >> 6;
    const int wm = (wid & 1) * 64;
    const int wn = (wid >> 1) * 64;
    const int l15 = lane & 15, kg = lane >> 4;

    const int arow = tid >> 1, ahf = tid & 1;
    int P = M0 + arow; if (P >= M) P = M - 1;
    const short* abase = Ah + (size_t)P * 12800 + ahf * 16;
    const int adst = arow * 40 + ahf * 16;

    const short* wbh = wph + (size_t)((n0 + wn) >> 4) * (NS4 * 512) + lane * 8;
    const short* wbl = wpl + (size_t)((n0 + wn) >> 4) * (NS4 * 512) + lane * 8;

    f32x4 acc[4][4];
    #pragma unroll
    for (int i = 0; i < 4; ++i)
        #pragma unroll
        for (int j = 0; j < 4; ++j)
            acc[i][j] = (f32x4){0.f, 0.f, 0.f, 0.f};

    auto stageA = [&](int j, int buf) {
        const short* src = abase + (size_t)(ks * NSTEP + j) * 32;
        *(bf16x8*)&s_a[buf][adst]     = *(const bf16x8*)src;
        *(bf16x8*)&s_a[buf][adst + 8] = *(const bf16x8*)(src + 8);
    };
    auto loadB = [&](int j, bf16x8 (&bh)[4], bf16x8 (&bl)[4]) {
        #pragma unroll
        for (int nf = 0; nf < 4; ++nf) {
            bh[nf] = *(const bf16x8*)(wbh + (size_t)nf * (NS4 * 512) + (size_t)(ks * NSTEP + j) * 512);
            bl[nf] = *(const bf16x8*)(wbl + (size_t)nf * (NS4 * 512) + (size_t)(ks * NSTEP + j) * 512);
        }
    };
    auto compute = [&](const bf16x8 (&bh)[4], const bf16x8 (&bl)[4], int buf) {
        bf16x8 af[4];
        #pragma unroll
        for (int mf = 0; mf < 4; ++mf)
            af[mf] = *(const bf16x8*)&s_a[buf][(wm + mf * 16 + l15) * 40 + kg * 8];
        #pragma unroll
        for (int nf = 0; nf < 4; ++nf)
            #pragma unroll
            for (int mf = 0; mf < 4; ++mf) {
                acc[mf][nf] = __builtin_amdgcn_mfma_f32_16x16x32_bf16(af[mf], bh[nf], acc[mf][nf], 0, 0, 0);
                acc[mf][nf] = __builtin_amdgcn_mfma_f32_16x16x32_bf16(af[mf], bl[nf], acc[mf][nf], 0, 0, 0);
            }
    };

    bf16x8 bhA[4], blA[4], bhB[4], blB[4];
    stageA(0, 0);
    loadB(0, bhA, blA);
    __syncthreads();
    for (int jp = 0; jp < NSTEP; jp += 2) {
        stageA(jp + 1, 1);
        loadB(jp + 1, bhB, blB);
        compute(bhA, blA, 0);
        __syncthreads();
        if (jp + 2 < NSTEP) { stageA(jp + 2, 0); loadB(jp + 2, bhA, blA); }
        compute(bhB, blB, 1);
        __syncthreads();
    }

    float* cp = Cpart + (size_t)ks * M * 512;
    #pragma unroll
    for (int nf = 0; nf < 4; ++nf) {
        const int n = n0 + wn + nf * 16 + l15;
        #pragma unroll
        for (int mf = 0; mf < 4; ++mf) {
            #pragma unroll
            for (int j = 0; j < 4; ++j) {
                int m = M0 + wm + mf * 16 + kg * 4 + j;
                if (m < M) cp[(size_t)m * 512 + n] = acc[mf][nf][j];
            }
        }
    }
}

template<int KS>
__global__ void splitk_reduce_relu(const float* __restrict__ Cpart,
                                   const float* __restrict__ bias,
                                   float* __restrict__ out, int M, int N)
{
    int idx = blockIdx.x * blockDim.x + threadIdx.x;
    if (idx >= M * N) return;
    int oc = idx % N;
    float s = bias[oc];
    #pragma unroll
    for (int ks = 0; ks < KS; ++ks)
        s += Cpart[(size_t)ks * M * N + idx];
    out[idx] = s > 0.f ? s : 0.f;
}

__global__ void linear_naive(const float* __restrict__ x, const float* __restrict__ Wl,
                             const float* __restrict__ bl,
                             float* __restrict__ out, int total)
{
    int idx = blockIdx.x * blockDim.x + threadIdx.x;
    if (idx >= total) return;
    int b = idx / 10, j = idx - b * 10;
    const float* xb = x  + (size_t)b * 512;
    const float* wj = Wl + (size_t)j * 512;
    float s = bl[j];
    for (int k = 0; k < 512; ++k)
        s += xb[k] * wj[k];
    out[idx] = s;
}

extern "C" void kernel_launch(void* const* d_in, const int* in_sizes, int n_in,
                              void* d_out, int out_size, void* d_ws, size_t ws_size,
                              hipStream_t stream)
{
    const float* A  = (const float*)d_in[0];
    const float* S  = (const float*)d_in[1];
    const float* W1 = (const float*)d_in[2];
    const float* b1 = (const float*)d_in[3];
    const float* W2 = (const float*)d_in[4];
    const float* b2 = (const float*)d_in[5];
    const float* W3 = (const float*)d_in[6];
    const float* b3 = (const float*)d_in[7];
    const float* W4 = (const float*)d_in[8];
    const float* b4 = (const float*)d_in[9];
    const float* Wl = (const float*)d_in[10];
    const float* bl = (const float*)d_in[11];
    float* outp = (float*)d_out;
    char* base = (char*)d_ws;

    const int Btot = 512;
    constexpr int KS = 25;

    const size_t W12N = (size_t)384 * 3456;
    const size_t W3N  = (size_t)512 * 3456;
    const size_t W4N  = (size_t)512 * 12800;
    size_t off = 0;
    short* w1h = (short*)(base + off); off += W12N * 2;
    short* w2h = (short*)(base + off); off += W12N * 2;
    short* w3h = (short*)(base + off); off += W3N * 2;
    short* w4h = (short*)(base + off); off += W4N * 2;
    short* w4l = (short*)(base + off); off += W4N * 2;
    const size_t wreg = off;

    const size_t PS = 337664;
    int Bc = 512;
    while (Bc > 8 && wreg + (size_t)Bc * PS > ws_size) Bc >>= 1;

    pack_w_frag_h<<<(int)((W12N + 255) / 256), 256, 0, stream>>>(W1, w1h, (int)W12N);
    pack_w_frag_h<<<(int)((W12N + 255) / 256), 256, 0, stream>>>(W2, w2h, (int)W12N);
    pack_w_frag_h<<<(int)((W3N  + 255) / 256), 256, 0, stream>>>(W3, w3h, (int)W3N);
    pack_w4_frag<<<(int)((W4N + 255) / 256), 256, 0, stream>>>(W4, w4h, w4l, (int)W4N);

    size_t o2 = wreg;
    short* x0h = (short*)(base + o2); o2 += (size_t)Bc * 110592;
    short* x1h = (short*)(base + o2); o2 += (size_t)Bc * 110592;
    short* x2h = (short*)(base + o2); o2 += (size_t)Bc * 37632;
    short* x3h = (short*)(base + o2); o2 += (size_t)Bc * 25600;
    float* cp  = (float*)(base + o2); o2 += (size_t)Bc * (KS * 512 * 4);
    float* x4  = (float*)(base + o2);

    long long zwords = (long long)Bc * (110592 + 110592 + 37632) / 4;
    zero_kernel<<<2048, 256, 0, stream>>>((unsigned int*)x0h, zwords);

    for (int b0 = 0; b0 < Btot; b0 += Bc) {
        int t0 = Bc * 38400;
        einsum_pack<<<(t0 + 255) / 256, 256, 0, stream>>>(
            A + (size_t)b0 * 2048, S + (size_t)b0 * 4800, x0h, t0);

        // conv1: 1 sample/block, NT=128, G=3 -> grid Bc*3
        conv_mfma4<384, 10, 12, 12, 1, 0, 128, 1>
            <<<dim3(Bc * 3), 256, 0, stream>>>(x0h, w1h, b1, x1h);

        // conv2: 4 samples/block, NT=64, G=6 -> grid (Bc/4)*6
        conv_mfma4<384, 5, 12, 7, 2, 0, 64, 4>
            <<<dim3((Bc / 4) * 6), 256, 0, stream>>>(x1h, w2h, b2, x2h);

        // conv3: 4 samples/block, NT=64, G=8, NCHW out -> grid (Bc/4)*8
        conv_mfma4<512, 5, 7, 1, 1, 1, 64, 4>
            <<<dim3((Bc / 4) * 8), 256, 0, stream>>>(x2h, w3h, b3, x3h);

        int nM = (Bc + 127) / 128;
        gemm4_mfma2<KS><<<dim3(KS * nM * 4), 256, 0, stream>>>(
            x3h, w4h, w4l, cp, Bc);
        int tr = Bc * 512;
        splitk_reduce_relu<KS><<<(tr + 255) / 256, 256, 0, stream>>>(
            cp, b4, x4, Bc, 512);

        int t5 = Bc * 10;
        linear_naive<<<(t5 + 255) / 256, 256, 0, stream>>>(
            x4, Wl, bl, outp + (size_t)b0 * 10, t5);
    }
}

// Round 15
// 506.147 us; speedup vs baseline: 97.0390x; 1.2125x over previous
//
#include <hip/hip_runtime.h>
#include <hip/hip_bf16.h>

// ---------------------------------------------------------------------------
// Decoder_SICA — ROUND 14: pipelined chunk loop for convs.
//  conv1/conv3: LDS double-buffer + T14 (1 barrier/chunk).
//  conv2: single buffer + issue-early global loads.
//  s_setprio around MFMA clusters. Single-product bf16 conv weights;
//  conv4 hi/lo split-K MFMA. fp32 in/out.
// ---------------------------------------------------------------------------

typedef __attribute__((ext_vector_type(8))) short bf16x8;
typedef __attribute__((ext_vector_type(4))) float f32x4;

__device__ __forceinline__ void split_bf16(float v, short& hs, short& ls) {
    __hip_bfloat16 h = __float2bfloat16(v);
    float hf = __bfloat162float(h);
    __hip_bfloat16 l = __float2bfloat16(v - hf);
    hs = __builtin_bit_cast(short, h);
    ls = __builtin_bit_cast(short, l);
}
__device__ __forceinline__ short round_bf16(float v) {
    __hip_bfloat16 h = __float2bfloat16(v);
    return __builtin_bit_cast(short, h);
}

__device__ __forceinline__ int xcd_swizzle(int bid, int total) {
    int q = total >> 3, r = total & 7;
    int xcd = bid & 7, idx = bid >> 3;
    return (xcd < r ? xcd * (q + 1) : r * (q + 1) + (xcd - r) * q) + idx;
}

__global__ void zero_kernel(unsigned int* __restrict__ p, long long nwords)
{
    long long i = (long long)blockIdx.x * blockDim.x + threadIdx.x;
    long long stride = (long long)gridDim.x * blockDim.x;
    for (; i < nwords; i += stride) p[i] = 0u;
}

// W (OC,384,3,3) fp32 -> bf16 fragment order [oc/16][s=t*12+ic/32][lane][8]
__global__ void pack_w_frag_h(const float* __restrict__ W,
                              short* __restrict__ wh, int total)
{
    int idx = blockIdx.x * blockDim.x + threadIdx.x;
    if (idx >= total) return;
    int oc = idx / 3456, r = idx - oc * 3456;
    int t = r / 384, ic = r - t * 384;
    float v = W[((size_t)oc * 384 + ic) * 9 + t];
    int g16 = oc >> 4, l15 = oc & 15;
    int c = ic >> 5, kg = (ic >> 3) & 3, e = ic & 7;
    size_t d = (((size_t)g16 * 108 + (t * 12 + c)) * 64 + kg * 16 + l15) * 8 + e;
    wh[d] = round_bf16(v);
}

// W4 (512,12800) fp32 -> hi/lo [oc/16][s=k/32][lane][8], NS=400
__global__ void pack_w4_frag(const float* __restrict__ W,
                             short* __restrict__ wh, short* __restrict__ wl, int total)
{
    int idx = blockIdx.x * blockDim.x + threadIdx.x;
    if (idx >= total) return;
    int oc = idx / 12800, k = idx - oc * 12800;
    short hs, ls; split_bf16(W[idx], hs, ls);
    int g16 = oc >> 4, l15 = oc & 15;
    int s = k >> 5, kg = (k >> 3) & 3, e = k & 7;
    size_t d = (((size_t)g16 * 400 + s) * 64 + kg * 16 + l15) * 8 + e;
    wh[d] = hs; wl[d] = ls;
}

// einsum -> padded NHWC bf16 plane x0[b][12][12][384], interior only.
__global__ void einsum_pack(const float* __restrict__ A, const float* __restrict__ S,
                            short* __restrict__ oh, int total)
{
    int idx = blockIdx.x * blockDim.x + threadIdx.x;
    if (idx >= total) return;
    int b   = idx / 38400;
    int r   = idx - b * 38400;
    int pix = r / 384;
    int ch  = r - pix * 384;
    int y = pix / 10, x = pix - y * 10;
    int h = y / 5, p = y - h * 5;
    int w = x / 5, q = x - w * 5;
    int n = ch / 48, g = (ch / 3) % 16, o = ch % 3;
    const float* Ab = A + (size_t)b * 2048 + (size_t)(n * 64 + g * 4) * 4 + h * 2 + w;
    const float* Sb = S + ((size_t)(b * 64 + g * 4) * 3 + o) * 25 + p * 5 + q;
    float s = 0.f;
    #pragma unroll
    for (int c = 0; c < 4; ++c)
        s += Ab[c * 4] * Sb[c * 75];
    size_t d = ((size_t)(b * 12 + y + 1) * 12 + (x + 1)) * 384 + ch;
    oh[d] = round_bf16(s);
}

// Tap-stationary implicit-GEMM 3x3 conv, pipelined chunk loop.
// DBUF=1: LDS double-buffer, 1 barrier/chunk. DBUF=0: single buffer,
// issue-early global loads. W bf16 frag-order from global, 1-tap prefetch.
template<int OC_T, int HOUT, int HPIN, int HPOUT, int STRIDE, int MODE, int NT,
         int NSAMP, int DBUF>
__global__ void __launch_bounds__(256)
conv_mfma5(const short* __restrict__ in_h, const short* __restrict__ wph,
           const float* __restrict__ bias, short* __restrict__ out_h)
{
    constexpr int IC = 384;
    constexpr int NS = 108;
    constexpr int NF = NT / 32;
    constexpr int PIX = HOUT * HOUT;
    constexpr int M_BLK = NSAMP * PIX;
    constexpr int PROWS = NSAMP * HPIN * HPIN;
    constexpr int G = OC_T / NT;
    constexpr int NU = (PROWS * 2 + 255) / 256;
    constexpr int BUFSZ = PROWS * 40;
    __shared__ short s_a[(DBUF ? 2 : 1) * BUFSZ];

    const int swz = xcd_swizzle(blockIdx.x, gridDim.x);
    const int mt = swz / G;
    const int g  = swz % G;
    const int n0 = g * NT;
    const int bb0 = mt * NSAMP;

    const int tid = threadIdx.x;
    const int lane = tid & 63;
    const int wid  = tid >> 6;
    const int wm = (wid & 1) * 64;
    const int wn = (wid >> 1) * (NT / 2);
    const int l15 = lane & 15, kg = lane >> 4;

    size_t usrc[NU]; int udst[NU]; bool uval[NU];
    #pragma unroll
    for (int j = 0; j < NU; ++j) {
        int u = tid + j * 256;
        int row = u >> 1, hf = u & 1;
        uval[j] = row < PROWS;
        int rc = uval[j] ? row : 0;
        int sN = rc / (HPIN * HPIN), rr = rc % (HPIN * HPIN);
        usrc[j] = ((size_t)(bb0 + sN) * (HPIN * HPIN) + rr) * IC + hf * 16;
        udst[j] = rc * 40 + hf * 16;
    }

    int prow[4];
    #pragma unroll
    for (int mf = 0; mf < 4; ++mf) {
        int p = wm + mf * 16 + l15;
        int pc = p < M_BLK ? p : M_BLK - 1;
        int sN = pc / PIX, pr = pc % PIX;
        int py = pr / HOUT, px = pr - py * HOUT;
        prow[mf] = sN * (HPIN * HPIN) + py * STRIDE * HPIN + px * STRIDE;
    }

    const short* wb = wph + (size_t)((n0 + wn) >> 4) * (NS * 512) + lane * 8;

    f32x4 acc[4][NF];
    #pragma unroll
    for (int i = 0; i < 4; ++i)
        #pragma unroll
        for (int j = 0; j < NF; ++j)
            acc[i][j] = (f32x4){0.f, 0.f, 0.f, 0.f};

    bf16x8 sreg[NU][2];
    auto loadG = [&](int c) {
        #pragma unroll
        for (int j = 0; j < NU; ++j) if (uval[j]) {
            const short* src = in_h + usrc[j] + c * 32;
            sreg[j][0] = *(const bf16x8*)src;
            sreg[j][1] = *(const bf16x8*)(src + 8);
        }
    };
    auto writeL = [&](int off) {
        #pragma unroll
        for (int j = 0; j < NU; ++j) if (uval[j]) {
            *(bf16x8*)&s_a[off + udst[j]]     = sreg[j][0];
            *(bf16x8*)&s_a[off + udst[j] + 8] = sreg[j][1];
        }
    };
    auto compute = [&](int c, int off) {
        bf16x8 bcur[NF], bnxt[NF];
        #pragma unroll
        for (int nf = 0; nf < NF; ++nf)
            bcur[nf] = *(const bf16x8*)(wb + (size_t)nf * (NS * 512) + (size_t)c * 512);
        #pragma unroll
        for (int t = 0; t < 9; ++t) {
            if (t < 8) {
                #pragma unroll
                for (int nf = 0; nf < NF; ++nf)
                    bnxt[nf] = *(const bf16x8*)(wb + (size_t)nf * (NS * 512)
                                                + (size_t)((t + 1) * 12 + c) * 512);
            }
            const int troff = (t / 3) * HPIN + (t % 3);
            bf16x8 af[4];
            #pragma unroll
            for (int mf = 0; mf < 4; ++mf)
                af[mf] = *(const bf16x8*)&s_a[off + (prow[mf] + troff) * 40 + kg * 8];
            __builtin_amdgcn_s_setprio(1);
            #pragma unroll
            for (int nf = 0; nf < NF; ++nf)
                #pragma unroll
                for (int mf = 0; mf < 4; ++mf)
                    acc[mf][nf] = __builtin_amdgcn_mfma_f32_16x16x32_bf16(
                        af[mf], bcur[nf], acc[mf][nf], 0, 0, 0);
            __builtin_amdgcn_s_setprio(0);
            #pragma unroll
            for (int nf = 0; nf < NF; ++nf) bcur[nf] = bnxt[nf];
        }
    };

    if (DBUF) {
        loadG(0); writeL(0);
        __syncthreads();
        int buf = 0;
        for (int c = 0; c < 12; ++c) {
            if (c + 1 < 12) loadG(c + 1);          // issue loads (hidden by MFMA)
            compute(c, buf * BUFSZ);
            if (c + 1 < 12) writeL((buf ^ 1) * BUFSZ);
            __syncthreads();
            buf ^= 1;
        }
    } else {
        loadG(0);
        for (int c = 0; c < 12; ++c) {
            if (c) __syncthreads();
            writeL(0);
            __syncthreads();
            if (c + 1 < 12) loadG(c + 1);          // issue early for next chunk
            compute(c, 0);
        }
    }

    #pragma unroll
    for (int nf = 0; nf < NF; ++nf) {
        const int oc = n0 + wn + nf * 16 + l15;
        const float bv = bias[oc];
        #pragma unroll
        for (int mf = 0; mf < 4; ++mf) {
            #pragma unroll
            for (int j = 0; j < 4; ++j) {
                int p_out = wm + mf * 16 + kg * 4 + j;
                if (p_out < M_BLK) {
                    float v = acc[mf][nf][j] + bv;
                    v = v > 0.f ? v : 0.f;
                    int b2 = bb0 + p_out / PIX;
                    int pr2 = p_out % PIX;
                    if (MODE == 0) {
                        int y2 = pr2 / HOUT, x2 = pr2 - y2 * HOUT;
                        size_t d = ((size_t)(b2 * HPOUT + y2 + 1) * HPOUT + (x2 + 1)) * OC_T + oc;
                        out_h[d] = round_bf16(v);
                    } else {
                        out_h[((size_t)b2 * OC_T + oc) * PIX + pr2] = round_bf16(v);
                    }
                }
            }
        }
    }
}

// Split-K bf16 MFMA GEMM for conv4 (hi/lo). KS=25 -> 16 k-steps.
template<int KS>
__global__ void __launch_bounds__(256)
gemm4_mfma2(const short* __restrict__ Ah, const short* __restrict__ wph,
            const short* __restrict__ wpl, float* __restrict__ Cpart, int M)
{
    constexpr int NS4 = 400;
    constexpr int NSTEP = NS4 / KS;             // 16
    __shared__ short s_a[2][128 * 40];
    const int tid = threadIdx.x;
    const int nM = (M + 127) / 128;
    const int ks = blockIdx.x / (nM * 4);
    const int rb = blockIdx.x % (nM * 4);
    const int M0 = (rb / 4) * 128;
    const int n0 = (rb % 4) * 128;

    const int lane = tid & 63;
    const int wid  = tid >> 6;
    const int wm = (wid & 1) * 64;
    const int wn = (wid >> 1) * 64;
    const int l15 = lane & 15, kg = lane >> 4;

    const int arow = tid >> 1, ahf = tid & 1;
    int P = M0 + arow; if (P >= M) P = M - 1;
    const short* abase = Ah + (size_t)P * 12800 + ahf * 16;
    const int adst = arow * 40 + ahf * 16;

    const short* wbh = wph + (size_t)((n0 + wn) >> 4) * (NS4 * 512) + lane * 8;
    const short* wbl = wpl + (size_t)((n0 + wn) >> 4) * (NS4 * 512) + lane * 8;

    f32x4 acc[4][4];
    #pragma unroll
    for (int i = 0; i < 4; ++i)
        #pragma unroll
        for (int j = 0; j < 4; ++j)
            acc[i][j] = (f32x4){0.f, 0.f, 0.f, 0.f};

    auto stageA = [&](int j, int buf) {
        const short* src = abase + (size_t)(ks * NSTEP + j) * 32;
        *(bf16x8*)&s_a[buf][adst]     = *(const bf16x8*)src;
        *(bf16x8*)&s_a[buf][adst + 8] = *(const bf16x8*)(src + 8);
    };
    auto loadB = [&](int j, bf16x8 (&bh)[4], bf16x8 (&bl)[4]) {
        #pragma unroll
        for (int nf = 0; nf < 4; ++nf) {
            bh[nf] = *(const bf16x8*)(wbh + (size_t)nf * (NS4 * 512) + (size_t)(ks * NSTEP + j) * 512);
            bl[nf] = *(const bf16x8*)(wbl + (size_t)nf * (NS4 * 512) + (size_t)(ks * NSTEP + j) * 512);
        }
    };
    auto compute = [&](const bf16x8 (&bh)[4], const bf16x8 (&bl)[4], int buf) {
        bf16x8 af[4];
        #pragma unroll
        for (int mf = 0; mf < 4; ++mf)
            af[mf] = *(const bf16x8*)&s_a[buf][(wm + mf * 16 + l15) * 40 + kg * 8];
        __builtin_amdgcn_s_setprio(1);
        #pragma unroll
        for (int nf = 0; nf < 4; ++nf)
            #pragma unroll
            for (int mf = 0; mf < 4; ++mf) {
                acc[mf][nf] = __builtin_amdgcn_mfma_f32_16x16x32_bf16(af[mf], bh[nf], acc[mf][nf], 0, 0, 0);
                acc[mf][nf] = __builtin_amdgcn_mfma_f32_16x16x32_bf16(af[mf], bl[nf], acc[mf][nf], 0, 0, 0);
            }
        __builtin_amdgcn_s_setprio(0);
    };

    bf16x8 bhA[4], blA[4], bhB[4], blB[4];
    stageA(0, 0);
    loadB(0, bhA, blA);
    __syncthreads();
    for (int jp = 0; jp < NSTEP; jp += 2) {
        stageA(jp + 1, 1);
        loadB(jp + 1, bhB, blB);
        compute(bhA, blA, 0);
        __syncthreads();
        if (jp + 2 < NSTEP) { stageA(jp + 2, 0); loadB(jp + 2, bhA, blA); }
        compute(bhB, blB, 1);
        __syncthreads();
    }

    float* cp = Cpart + (size_t)ks * M * 512;
    #pragma unroll
    for (int nf = 0; nf < 4; ++nf) {
        const int n = n0 + wn + nf * 16 + l15;
        #pragma unroll
        for (int mf = 0; mf < 4; ++mf) {
            #pragma unroll
            for (int j = 0; j < 4; ++j) {
                int m = M0 + wm + mf * 16 + kg * 4 + j;
                if (m < M) cp[(size_t)m * 512 + n] = acc[mf][nf][j];
            }
        }
    }
}

template<int KS>
__global__ void splitk_reduce_relu(const float* __restrict__ Cpart,
                                   const float* __restrict__ bias,
                                   float* __restrict__ out, int M, int N)
{
    int idx = blockIdx.x * blockDim.x + threadIdx.x;
    if (idx >= M * N) return;
    int oc = idx % N;
    float s = bias[oc];
    #pragma unroll
    for (int ks = 0; ks < KS; ++ks)
        s += Cpart[(size_t)ks * M * N + idx];
    out[idx] = s > 0.f ? s : 0.f;
}

__global__ void linear_naive(const float* __restrict__ x, const float* __restrict__ Wl,
                             const float* __restrict__ bl,
                             float* __restrict__ out, int total)
{
    int idx = blockIdx.x * blockDim.x + threadIdx.x;
    if (idx >= total) return;
    int b = idx / 10, j = idx - b * 10;
    const float* xb = x  + (size_t)b * 512;
    const float* wj = Wl + (size_t)j * 512;
    float s = bl[j];
    for (int k = 0; k < 512; ++k)
        s += xb[k] * wj[k];
    out[idx] = s;
}

extern "C" void kernel_launch(void* const* d_in, const int* in_sizes, int n_in,
                              void* d_out, int out_size, void* d_ws, size_t ws_size,
                              hipStream_t stream)
{
    const float* A  = (const float*)d_in[0];
    const float* S  = (const float*)d_in[1];
    const float* W1 = (const float*)d_in[2];
    const float* b1 = (const float*)d_in[3];
    const float* W2 = (const float*)d_in[4];
    const float* b2 = (const float*)d_in[5];
    const float* W3 = (const float*)d_in[6];
    const float* b3 = (const float*)d_in[7];
    const float* W4 = (const float*)d_in[8];
    const float* b4 = (const float*)d_in[9];
    const float* Wl = (const float*)d_in[10];
    const float* bl = (const float*)d_in[11];
    float* outp = (float*)d_out;
    char* base = (char*)d_ws;

    const int Btot = 512;
    constexpr int KS = 25;

    const size_t W12N = (size_t)384 * 3456;
    const size_t W3N  = (size_t)512 * 3456;
    const size_t W4N  = (size_t)512 * 12800;
    size_t off = 0;
    short* w1h = (short*)(base + off); off += W12N * 2;
    short* w2h = (short*)(base + off); off += W12N * 2;
    short* w3h = (short*)(base + off); off += W3N * 2;
    short* w4h = (short*)(base + off); off += W4N * 2;
    short* w4l = (short*)(base + off); off += W4N * 2;
    const size_t wreg = off;

    const size_t PS = 337664;
    int Bc = 512;
    while (Bc > 8 && wreg + (size_t)Bc * PS > ws_size) Bc >>= 1;

    pack_w_frag_h<<<(int)((W12N + 255) / 256), 256, 0, stream>>>(W1, w1h, (int)W12N);
    pack_w_frag_h<<<(int)((W12N + 255) / 256), 256, 0, stream>>>(W2, w2h, (int)W12N);
    pack_w_frag_h<<<(int)((W3N  + 255) / 256), 256, 0, stream>>>(W3, w3h, (int)W3N);
    pack_w4_frag<<<(int)((W4N + 255) / 256), 256, 0, stream>>>(W4, w4h, w4l, (int)W4N);

    size_t o2 = wreg;
    short* x0h = (short*)(base + o2); o2 += (size_t)Bc * 110592;
    short* x1h = (short*)(base + o2); o2 += (size_t)Bc * 110592;
    short* x2h = (short*)(base + o2); o2 += (size_t)Bc * 37632;
    short* x3h = (short*)(base + o2); o2 += (size_t)Bc * 25600;
    float* cp  = (float*)(base + o2); o2 += (size_t)Bc * (KS * 512 * 4);
    float* x4  = (float*)(base + o2);

    long long zwords = (long long)Bc * (110592 + 110592 + 37632) / 4;
    zero_kernel<<<2048, 256, 0, stream>>>((unsigned int*)x0h, zwords);

    for (int b0 = 0; b0 < Btot; b0 += Bc) {
        int t0 = Bc * 38400;
        einsum_pack<<<(t0 + 255) / 256, 256, 0, stream>>>(
            A + (size_t)b0 * 2048, S + (size_t)b0 * 4800, x0h, t0);

        // conv1: 1 sample/block, NT=128, dbuf (LDS 23 KB), grid Bc*3
        conv_mfma5<384, 10, 12, 12, 1, 0, 128, 1, 1>
            <<<dim3(Bc * 3), 256, 0, stream>>>(x0h, w1h, b1, x1h);

        // conv2: 4 samples/block, NT=64, single-buf + early loads (46 KB)
        conv_mfma5<384, 5, 12, 7, 2, 0, 64, 4, 0>
            <<<dim3((Bc / 4) * 6), 256, 0, stream>>>(x1h, w2h, b2, x2h);

        // conv3: 4 samples/block, NT=64, dbuf (31 KB), NCHW out
        conv_mfma5<512, 5, 7, 1, 1, 1, 64, 4, 1>
            <<<dim3((Bc / 4) * 8), 256, 0, stream>>>(x2h, w3h, b3, x3h);

        int nM = (Bc + 127) / 128;
        gemm4_mfma2<KS><<<dim3(KS * nM * 4), 256, 0, stream>>>(
            x3h, w4h, w4l, cp, Bc);
        int tr = Bc * 512;
        splitk_reduce_relu<KS><<<(tr + 255) / 256, 256, 0, stream>>>(
            cp, b4, x4, Bc, 512);

        int t5 = Bc * 10;
        linear_naive<<<(t5 + 255) / 256, 256, 0, stream>>>(
            x4, Wl, bl, outp + (size_t)b0 * 10, t5);
    }
}

// Round 16
// 467.095 us; speedup vs baseline: 105.1522x; 1.0836x over previous
//
#include <hip/hip_runtime.h>
#include <hip/hip_bf16.h>

// ---------------------------------------------------------------------------
// Decoder_SICA — ROUND 15: fast einsum (block/sample, LDS-staged S, reg A,
// compile-time component select, coalesced bf16 stores). Convs/gemm4 = r14.
// ---------------------------------------------------------------------------

typedef __attribute__((ext_vector_type(8))) short bf16x8;
typedef __attribute__((ext_vector_type(4))) float f32x4;

__device__ __forceinline__ void split_bf16(float v, short& hs, short& ls) {
    __hip_bfloat16 h = __float2bfloat16(v);
    float hf = __bfloat162float(h);
    __hip_bfloat16 l = __float2bfloat16(v - hf);
    hs = __builtin_bit_cast(short, h);
    ls = __builtin_bit_cast(short, l);
}
__device__ __forceinline__ short round_bf16(float v) {
    __hip_bfloat16 h = __float2bfloat16(v);
    return __builtin_bit_cast(short, h);
}

__device__ __forceinline__ int xcd_swizzle(int bid, int total) {
    int q = total >> 3, r = total & 7;
    int xcd = bid & 7, idx = bid >> 3;
    return (xcd < r ? xcd * (q + 1) : r * (q + 1) + (xcd - r) * q) + idx;
}

__global__ void zero_kernel(unsigned int* __restrict__ p, long long nwords)
{
    long long i = (long long)blockIdx.x * blockDim.x + threadIdx.x;
    long long stride = (long long)gridDim.x * blockDim.x;
    for (; i < nwords; i += stride) p[i] = 0u;
}

// W (OC,384,3,3) fp32 -> bf16 fragment order [oc/16][s=t*12+ic/32][lane][8]
__global__ void pack_w_frag_h(const float* __restrict__ W,
                              short* __restrict__ wh, int total)
{
    int idx = blockIdx.x * blockDim.x + threadIdx.x;
    if (idx >= total) return;
    int oc = idx / 3456, r = idx - oc * 3456;
    int t = r / 384, ic = r - t * 384;
    float v = W[((size_t)oc * 384 + ic) * 9 + t];
    int g16 = oc >> 4, l15 = oc & 15;
    int c = ic >> 5, kg = (ic >> 3) & 3, e = ic & 7;
    size_t d = (((size_t)g16 * 108 + (t * 12 + c)) * 64 + kg * 16 + l15) * 8 + e;
    wh[d] = round_bf16(v);
}

// W4 (512,12800) fp32 -> hi/lo [oc/16][s=k/32][lane][8], NS=400
__global__ void pack_w4_frag(const float* __restrict__ W,
                             short* __restrict__ wh, short* __restrict__ wl, int total)
{
    int idx = blockIdx.x * blockDim.x + threadIdx.x;
    if (idx >= total) return;
    int oc = idx / 12800, k = idx - oc * 12800;
    short hs, ls; split_bf16(W[idx], hs, ls);
    int g16 = oc >> 4, l15 = oc & 15;
    int s = k >> 5, kg = (k >> 3) & 3, e = k & 7;
    size_t d = (((size_t)g16 * 400 + s) * 64 + kg * 16 + l15) * 8 + e;
    wh[d] = hs; wl[d] = ls;
}

// einsum -> padded NHWC bf16 plane x0[b][12][12][384], interior only.
// Block = 1 sample, 384 threads = 1 channel each. S in LDS, A in registers.
__global__ void __launch_bounds__(384)
einsum_pack3(const float* __restrict__ A, const float* __restrict__ S,
             short* __restrict__ oh)
{
    __shared__ float sS[4800];
    const int b  = blockIdx.x;
    const int ch = threadIdx.x;            // 0..383

    const float4* S4 = (const float4*)(S + (size_t)b * 4800);
    for (int i = threadIdx.x; i < 1200; i += 384)
        ((float4*)sS)[i] = S4[i];

    // ch = n*48 + g*3 + o
    const int n = ch / 48, rr = ch - n * 48;
    const int g = rr / 3,  o = rr - g * 3;

    // A fragment: av[c] = A4[n*64 + g*4 + c] (components = h*2+w)
    const float4* A4 = (const float4*)(A + (size_t)b * 2048) + (n * 64 + g * 4);
    float4 av0 = A4[0], av1 = A4[1], av2 = A4[2], av3 = A4[3];

    __syncthreads();

    const float* Sb = sS + g * 300 + o * 25;

    #pragma unroll
    for (int h = 0; h < 2; ++h) {
        #pragma unroll
        for (int w = 0; w < 2; ++w) {
            // compile-time component select (h,w unrolled)
            const float a0 = (h == 0 && w == 0) ? av0.x : (h == 0 && w == 1) ? av0.y
                           : (h == 1 && w == 0) ? av0.z : av0.w;
            const float a1 = (h == 0 && w == 0) ? av1.x : (h == 0 && w == 1) ? av1.y
                           : (h == 1 && w == 0) ? av1.z : av1.w;
            const float a2 = (h == 0 && w == 0) ? av2.x : (h == 0 && w == 1) ? av2.y
                           : (h == 1 && w == 0) ? av2.z : av2.w;
            const float a3 = (h == 0 && w == 0) ? av3.x : (h == 0 && w == 1) ? av3.y
                           : (h == 1 && w == 0) ? av3.z : av3.w;
            // output rows y = h*5+pp, cols x = w*5+q
            size_t dbase = ((size_t)(b * 12 + h * 5 + 1) * 12 + (w * 5 + 1)) * 384 + ch;
            #pragma unroll
            for (int pp = 0; pp < 5; ++pp) {
                #pragma unroll
                for (int q = 0; q < 5; ++q) {
                    const int soff = pp * 5 + q;
                    float s = a0 * Sb[soff] + a1 * Sb[75 + soff]
                            + a2 * Sb[150 + soff] + a3 * Sb[225 + soff];
                    oh[dbase + (size_t)(pp * 12 + q) * 384] = round_bf16(s);
                }
            }
        }
    }
}

// Tap-stationary implicit-GEMM 3x3 conv, pipelined chunk loop (r14).
template<int OC_T, int HOUT, int HPIN, int HPOUT, int STRIDE, int MODE, int NT,
         int NSAMP, int DBUF>
__global__ void __launch_bounds__(256)
conv_mfma5(const short* __restrict__ in_h, const short* __restrict__ wph,
           const float* __restrict__ bias, short* __restrict__ out_h)
{
    constexpr int IC = 384;
    constexpr int NS = 108;
    constexpr int NF = NT / 32;
    constexpr int PIX = HOUT * HOUT;
    constexpr int M_BLK = NSAMP * PIX;
    constexpr int PROWS = NSAMP * HPIN * HPIN;
    constexpr int G = OC_T / NT;
    constexpr int NU = (PROWS * 2 + 255) / 256;
    constexpr int BUFSZ = PROWS * 40;
    __shared__ short s_a[(DBUF ? 2 : 1) * BUFSZ];

    const int swz = xcd_swizzle(blockIdx.x, gridDim.x);
    const int mt = swz / G;
    const int g  = swz % G;
    const int n0 = g * NT;
    const int bb0 = mt * NSAMP;

    const int tid = threadIdx.x;
    const int lane = tid & 63;
    const int wid  = tid >> 6;
    const int wm = (wid & 1) * 64;
    const int wn = (wid >> 1) * (NT / 2);
    const int l15 = lane & 15, kg = lane >> 4;

    size_t usrc[NU]; int udst[NU]; bool uval[NU];
    #pragma unroll
    for (int j = 0; j < NU; ++j) {
        int u = tid + j * 256;
        int row = u >> 1, hf = u & 1;
        uval[j] = row < PROWS;
        int rc = uval[j] ? row : 0;
        int sN = rc / (HPIN * HPIN), rr = rc % (HPIN * HPIN);
        usrc[j] = ((size_t)(bb0 + sN) * (HPIN * HPIN) + rr) * IC + hf * 16;
        udst[j] = rc * 40 + hf * 16;
    }

    int prow[4];
    #pragma unroll
    for (int mf = 0; mf < 4; ++mf) {
        int p = wm + mf * 16 + l15;
        int pc = p < M_BLK ? p : M_BLK - 1;
        int sN = pc / PIX, pr = pc % PIX;
        int py = pr / HOUT, px = pr - py * HOUT;
        prow[mf] = sN * (HPIN * HPIN) + py * STRIDE * HPIN + px * STRIDE;
    }

    const short* wb = wph + (size_t)((n0 + wn) >> 4) * (NS * 512) + lane * 8;

    f32x4 acc[4][NF];
    #pragma unroll
    for (int i = 0; i < 4; ++i)
        #pragma unroll
        for (int j = 0; j < NF; ++j)
            acc[i][j] = (f32x4){0.f, 0.f, 0.f, 0.f};

    bf16x8 sreg[NU][2];
    auto loadG = [&](int c) {
        #pragma unroll
        for (int j = 0; j < NU; ++j) if (uval[j]) {
            const short* src = in_h + usrc[j] + c * 32;
            sreg[j][0] = *(const bf16x8*)src;
            sreg[j][1] = *(const bf16x8*)(src + 8);
        }
    };
    auto writeL = [&](int off) {
        #pragma unroll
        for (int j = 0; j < NU; ++j) if (uval[j]) {
            *(bf16x8*)&s_a[off + udst[j]]     = sreg[j][0];
            *(bf16x8*)&s_a[off + udst[j] + 8] = sreg[j][1];
        }
    };
    auto compute = [&](int c, int off) {
        bf16x8 bcur[NF], bnxt[NF];
        #pragma unroll
        for (int nf = 0; nf < NF; ++nf)
            bcur[nf] = *(const bf16x8*)(wb + (size_t)nf * (NS * 512) + (size_t)c * 512);
        #pragma unroll
        for (int t = 0; t < 9; ++t) {
            if (t < 8) {
                #pragma unroll
                for (int nf = 0; nf < NF; ++nf)
                    bnxt[nf] = *(const bf16x8*)(wb + (size_t)nf * (NS * 512)
                                                + (size_t)((t + 1) * 12 + c) * 512);
            }
            const int troff = (t / 3) * HPIN + (t % 3);
            bf16x8 af[4];
            #pragma unroll
            for (int mf = 0; mf < 4; ++mf)
                af[mf] = *(const bf16x8*)&s_a[off + (prow[mf] + troff) * 40 + kg * 8];
            __builtin_amdgcn_s_setprio(1);
            #pragma unroll
            for (int nf = 0; nf < NF; ++nf)
                #pragma unroll
                for (int mf = 0; mf < 4; ++mf)
                    acc[mf][nf] = __builtin_amdgcn_mfma_f32_16x16x32_bf16(
                        af[mf], bcur[nf], acc[mf][nf], 0, 0, 0);
            __builtin_amdgcn_s_setprio(0);
            #pragma unroll
            for (int nf = 0; nf < NF; ++nf) bcur[nf] = bnxt[nf];
        }
    };

    if (DBUF) {
        loadG(0); writeL(0);
        __syncthreads();
        int buf = 0;
        for (int c = 0; c < 12; ++c) {
            if (c + 1 < 12) loadG(c + 1);
            compute(c, buf * BUFSZ);
            if (c + 1 < 12) writeL((buf ^ 1) * BUFSZ);
            __syncthreads();
            buf ^= 1;
        }
    } else {
        loadG(0);
        for (int c = 0; c < 12; ++c) {
            if (c) __syncthreads();
            writeL(0);
            __syncthreads();
            if (c + 1 < 12) loadG(c + 1);
            compute(c, 0);
        }
    }

    #pragma unroll
    for (int nf = 0; nf < NF; ++nf) {
        const int oc = n0 + wn + nf * 16 + l15;
        const float bv = bias[oc];
        #pragma unroll
        for (int mf = 0; mf < 4; ++mf) {
            #pragma unroll
            for (int j = 0; j < 4; ++j) {
                int p_out = wm + mf * 16 + kg * 4 + j;
                if (p_out < M_BLK) {
                    float v = acc[mf][nf][j] + bv;
                    v = v > 0.f ? v : 0.f;
                    int b2 = bb0 + p_out / PIX;
                    int pr2 = p_out % PIX;
                    if (MODE == 0) {
                        int y2 = pr2 / HOUT, x2 = pr2 - y2 * HOUT;
                        size_t d = ((size_t)(b2 * HPOUT + y2 + 1) * HPOUT + (x2 + 1)) * OC_T + oc;
                        out_h[d] = round_bf16(v);
                    } else {
                        out_h[((size_t)b2 * OC_T + oc) * PIX + pr2] = round_bf16(v);
                    }
                }
            }
        }
    }
}

// Split-K bf16 MFMA GEMM for conv4 (hi/lo). KS=25 -> 16 k-steps.
template<int KS>
__global__ void __launch_bounds__(256)
gemm4_mfma2(const short* __restrict__ Ah, const short* __restrict__ wph,
            const short* __restrict__ wpl, float* __restrict__ Cpart, int M)
{
    constexpr int NS4 = 400;
    constexpr int NSTEP = NS4 / KS;             // 16
    __shared__ short s_a[2][128 * 40];
    const int tid = threadIdx.x;
    const int nM = (M + 127) / 128;
    const int ks = blockIdx.x / (nM * 4);
    const int rb = blockIdx.x % (nM * 4);
    const int M0 = (rb / 4) * 128;
    const int n0 = (rb % 4) * 128;

    const int lane = tid & 63;
    const int wid  = tid >> 6;
    const int wm = (wid & 1) * 64;
    const int wn = (wid >> 1) * 64;
    const int l15 = lane & 15, kg = lane >> 4;

    const int arow = tid >> 1, ahf = tid & 1;
    int P = M0 + arow; if (P >= M) P = M - 1;
    const short* abase = Ah + (size_t)P * 12800 + ahf * 16;
    const int adst = arow * 40 + ahf * 16;

    const short* wbh = wph + (size_t)((n0 + wn) >> 4) * (NS4 * 512) + lane * 8;
    const short* wbl = wpl + (size_t)((n0 + wn) >> 4) * (NS4 * 512) + lane * 8;

    f32x4 acc[4][4];
    #pragma unroll
    for (int i = 0; i < 4; ++i)
        #pragma unroll
        for (int j = 0; j < 4; ++j)
            acc[i][j] = (f32x4){0.f, 0.f, 0.f, 0.f};

    auto stageA = [&](int j, int buf) {
        const short* src = abase + (size_t)(ks * NSTEP + j) * 32;
        *(bf16x8*)&s_a[buf][adst]     = *(const bf16x8*)src;
        *(bf16x8*)&s_a[buf][adst + 8] = *(const bf16x8*)(src + 8);
    };
    auto loadB = [&](int j, bf16x8 (&bh)[4], bf16x8 (&bl)[4]) {
        #pragma unroll
        for (int nf = 0; nf < 4; ++nf) {
            bh[nf] = *(const bf16x8*)(wbh + (size_t)nf * (NS4 * 512) + (size_t)(ks * NSTEP + j) * 512);
            bl[nf] = *(const bf16x8*)(wbl + (size_t)nf * (NS4 * 512) + (size_t)(ks * NSTEP + j) * 512);
        }
    };
    auto compute = [&](const bf16x8 (&bh)[4], const bf16x8 (&bl)[4], int buf) {
        bf16x8 af[4];
        #pragma unroll
        for (int mf = 0; mf < 4; ++mf)
            af[mf] = *(const bf16x8*)&s_a[buf][(wm + mf * 16 + l15) * 40 + kg * 8];
        __builtin_amdgcn_s_setprio(1);
        #pragma unroll
        for (int nf = 0; nf < 4; ++nf)
            #pragma unroll
            for (int mf = 0; mf < 4; ++mf) {
                acc[mf][nf] = __builtin_amdgcn_mfma_f32_16x16x32_bf16(af[mf], bh[nf], acc[mf][nf], 0, 0, 0);
                acc[mf][nf] = __builtin_amdgcn_mfma_f32_16x16x32_bf16(af[mf], bl[nf], acc[mf][nf], 0, 0, 0);
            }
        __builtin_amdgcn_s_setprio(0);
    };

    bf16x8 bhA[4], blA[4], bhB[4], blB[4];
    stageA(0, 0);
    loadB(0, bhA, blA);
    __syncthreads();
    for (int jp = 0; jp < NSTEP; jp += 2) {
        stageA(jp + 1, 1);
        loadB(jp + 1, bhB, blB);
        compute(bhA, blA, 0);
        __syncthreads();
        if (jp + 2 < NSTEP) { stageA(jp + 2, 0); loadB(jp + 2, bhA, blA); }
        compute(bhB, blB, 1);
        __syncthreads();
    }

    float* cp = Cpart + (size_t)ks * M * 512;
    #pragma unroll
    for (int nf = 0; nf < 4; ++nf) {
        const int n = n0 + wn + nf * 16 + l15;
        #pragma unroll
        for (int mf = 0; mf < 4; ++mf) {
            #pragma unroll
            for (int j = 0; j < 4; ++j) {
                int m = M0 + wm + mf * 16 + kg * 4 + j;
                if (m < M) cp[(size_t)m * 512 + n] = acc[mf][nf][j];
            }
        }
    }
}

template<int KS>
__global__ void splitk_reduce_relu(const float* __restrict__ Cpart,
                                   const float* __restrict__ bias,
                                   float* __restrict__ out, int M, int N)
{
    int idx = blockIdx.x * blockDim.x + threadIdx.x;
    if (idx >= M * N) return;
    int oc = idx % N;
    float s = bias[oc];
    #pragma unroll
    for (int ks = 0; ks < KS; ++ks)
        s += Cpart[(size_t)ks * M * N + idx];
    out[idx] = s > 0.f ? s : 0.f;
}

__global__ void linear_naive(const float* __restrict__ x, const float* __restrict__ Wl,
                             const float* __restrict__ bl,
                             float* __restrict__ out, int total)
{
    int idx = blockIdx.x * blockDim.x + threadIdx.x;
    if (idx >= total) return;
    int b = idx / 10, j = idx - b * 10;
    const float* xb = x  + (size_t)b * 512;
    const float* wj = Wl + (size_t)j * 512;
    float s = bl[j];
    for (int k = 0; k < 512; ++k)
        s += xb[k] * wj[k];
    out[idx] = s;
}

extern "C" void kernel_launch(void* const* d_in, const int* in_sizes, int n_in,
                              void* d_out, int out_size, void* d_ws, size_t ws_size,
                              hipStream_t stream)
{
    const float* A  = (const float*)d_in[0];
    const float* S  = (const float*)d_in[1];
    const float* W1 = (const float*)d_in[2];
    const float* b1 = (const float*)d_in[3];
    const float* W2 = (const float*)d_in[4];
    const float* b2 = (const float*)d_in[5];
    const float* W3 = (const float*)d_in[6];
    const float* b3 = (const float*)d_in[7];
    const float* W4 = (const float*)d_in[8];
    const float* b4 = (const float*)d_in[9];
    const float* Wl = (const float*)d_in[10];
    const float* bl = (const float*)d_in[11];
    float* outp = (float*)d_out;
    char* base = (char*)d_ws;

    const int Btot = 512;
    constexpr int KS = 25;

    const size_t W12N = (size_t)384 * 3456;
    const size_t W3N  = (size_t)512 * 3456;
    const size_t W4N  = (size_t)512 * 12800;
    size_t off = 0;
    short* w1h = (short*)(base + off); off += W12N * 2;
    short* w2h = (short*)(base + off); off += W12N * 2;
    short* w3h = (short*)(base + off); off += W3N * 2;
    short* w4h = (short*)(base + off); off += W4N * 2;
    short* w4l = (short*)(base + off); off += W4N * 2;
    const size_t wreg = off;

    const size_t PS = 337664;
    int Bc = 512;
    while (Bc > 8 && wreg + (size_t)Bc * PS > ws_size) Bc >>= 1;

    pack_w_frag_h<<<(int)((W12N + 255) / 256), 256, 0, stream>>>(W1, w1h, (int)W12N);
    pack_w_frag_h<<<(int)((W12N + 255) / 256), 256, 0, stream>>>(W2, w2h, (int)W12N);
    pack_w_frag_h<<<(int)((W3N  + 255) / 256), 256, 0, stream>>>(W3, w3h, (int)W3N);
    pack_w4_frag<<<(int)((W4N + 255) / 256), 256, 0, stream>>>(W4, w4h, w4l, (int)W4N);

    size_t o2 = wreg;
    short* x0h = (short*)(base + o2); o2 += (size_t)Bc * 110592;
    short* x1h = (short*)(base + o2); o2 += (size_t)Bc * 110592;
    short* x2h = (short*)(base + o2); o2 += (size_t)Bc * 37632;
    short* x3h = (short*)(base + o2); o2 += (size_t)Bc * 25600;
    float* cp  = (float*)(base + o2); o2 += (size_t)Bc * (KS * 512 * 4);
    float* x4  = (float*)(base + o2);

    long long zwords = (long long)Bc * (110592 + 110592 + 37632) / 4;
    zero_kernel<<<2048, 256, 0, stream>>>((unsigned int*)x0h, zwords);

    for (int b0 = 0; b0 < Btot; b0 += Bc) {
        einsum_pack3<<<dim3(Bc), 384, 0, stream>>>(
            A + (size_t)b0 * 2048, S + (size_t)b0 * 4800, x0h);

        // conv1: 1 sample/block, NT=128, dbuf (LDS 23 KB), grid Bc*3
        conv_mfma5<384, 10, 12, 12, 1, 0, 128, 1, 1>
            <<<dim3(Bc * 3), 256, 0, stream>>>(x0h, w1h, b1, x1h);

        // conv2: 4 samples/block, NT=64, single-buf + early loads (46 KB)
        conv_mfma5<384, 5, 12, 7, 2, 0, 64, 4, 0>
            <<<dim3((Bc / 4) * 6), 256, 0, stream>>>(x1h, w2h, b2, x2h);

        // conv3: 4 samples/block, NT=64, dbuf (31 KB), NCHW out
        conv_mfma5<512, 5, 7, 1, 1, 1, 64, 4, 1>
            <<<dim3((Bc / 4) * 8), 256, 0, stream>>>(x2h, w3h, b3, x3h);

        int nM = (Bc + 127) / 128;
        gemm4_mfma2<KS><<<dim3(KS * nM * 4), 256, 0, stream>>>(
            x3h, w4h, w4l, cp, Bc);
        int tr = Bc * 512;
        splitk_reduce_relu<KS><<<(tr + 255) / 256, 256, 0, stream>>>(
            cp, b4, x4, Bc, 512);

        int t5 = Bc * 10;
        linear_naive<<<(t5 + 255) / 256, 256, 0, stream>>>(
            x4, Wl, bl, outp + (size_t)b0 * 10, t5);
    }
}

// Round 17
// 427.533 us; speedup vs baseline: 114.8825x; 1.0925x over previous
//
#include <hip/hip_runtime.h>
#include <hip/hip_bf16.h>

// ---------------------------------------------------------------------------
// Decoder_SICA — ROUND 16: conv3 NT=128, single-product gemm4, border-only
// zeroing. einsum/conv1/conv2 = r15 (verified).
// ---------------------------------------------------------------------------

typedef __attribute__((ext_vector_type(8))) short bf16x8;
typedef __attribute__((ext_vector_type(4))) float f32x4;

__device__ __forceinline__ short round_bf16(float v) {
    __hip_bfloat16 h = __float2bfloat16(v);
    return __builtin_bit_cast(short, h);
}

__device__ __forceinline__ int xcd_swizzle(int bid, int total) {
    int q = total >> 3, r = total & 7;
    int xcd = bid & 7, idx = bid >> 3;
    return (xcd < r ? xcd * (q + 1) : r * (q + 1) + (xcd - r) * q) + idx;
}

// zero only the border cells of padded NHWC planes [Bc][HP][HP][C]
template<int HP, int C>
__global__ void zero_border(short* __restrict__ p, int Bc)
{
    constexpr int NB = 2 * HP + 2 * (HP - 2);
    constexpr int C8 = C / 8;
    int idx = blockIdx.x * blockDim.x + threadIdx.x;
    int total = Bc * NB * C8;
    if (idx >= total) return;
    int c8 = idx % C8;
    int t  = idx / C8;
    int pb = t % NB;
    int b  = t / NB;
    int r, c;
    if (pb < HP)          { r = 0;      c = pb; }
    else if (pb < 2 * HP) { r = HP - 1; c = pb - HP; }
    else { int s = pb - 2 * HP; r = 1 + (s >> 1); c = (s & 1) ? HP - 1 : 0; }
    size_t d = (((size_t)b * HP + r) * HP + c) * C + c8 * 8;
    *(bf16x8*)&p[d] = (bf16x8){0, 0, 0, 0, 0, 0, 0, 0};
}

// W (OC,384,3,3) fp32 -> bf16 fragment order [oc/16][s=t*12+ic/32][lane][8]
__global__ void pack_w_frag_h(const float* __restrict__ W,
                              short* __restrict__ wh, int total)
{
    int idx = blockIdx.x * blockDim.x + threadIdx.x;
    if (idx >= total) return;
    int oc = idx / 3456, r = idx - oc * 3456;
    int t = r / 384, ic = r - t * 384;
    float v = W[((size_t)oc * 384 + ic) * 9 + t];
    int g16 = oc >> 4, l15 = oc & 15;
    int c = ic >> 5, kg = (ic >> 3) & 3, e = ic & 7;
    size_t d = (((size_t)g16 * 108 + (t * 12 + c)) * 64 + kg * 16 + l15) * 8 + e;
    wh[d] = round_bf16(v);
}

// W4 (512,12800) fp32 -> bf16 [oc/16][s=k/32][lane][8], NS=400
__global__ void pack_w4_frag_h(const float* __restrict__ W,
                               short* __restrict__ wh, int total)
{
    int idx = blockIdx.x * blockDim.x + threadIdx.x;
    if (idx >= total) return;
    int oc = idx / 12800, k = idx - oc * 12800;
    int g16 = oc >> 4, l15 = oc & 15;
    int s = k >> 5, kg = (k >> 3) & 3, e = k & 7;
    size_t d = (((size_t)g16 * 400 + s) * 64 + kg * 16 + l15) * 8 + e;
    wh[d] = round_bf16(W[idx]);
}

// einsum -> padded NHWC bf16 plane x0[b][12][12][384], interior only.
__global__ void __launch_bounds__(384)
einsum_pack3(const float* __restrict__ A, const float* __restrict__ S,
             short* __restrict__ oh)
{
    __shared__ float sS[4800];
    const int b  = blockIdx.x;
    const int ch = threadIdx.x;

    const float4* S4 = (const float4*)(S + (size_t)b * 4800);
    for (int i = threadIdx.x; i < 1200; i += 384)
        ((float4*)sS)[i] = S4[i];

    const int n = ch / 48, rr = ch - n * 48;
    const int g = rr / 3,  o = rr - g * 3;

    const float4* A4 = (const float4*)(A + (size_t)b * 2048) + (n * 64 + g * 4);
    float4 av0 = A4[0], av1 = A4[1], av2 = A4[2], av3 = A4[3];

    __syncthreads();

    const float* Sb = sS + g * 300 + o * 25;

    #pragma unroll
    for (int h = 0; h < 2; ++h) {
        #pragma unroll
        for (int w = 0; w < 2; ++w) {
            const float a0 = (h == 0 && w == 0) ? av0.x : (h == 0 && w == 1) ? av0.y
                           : (h == 1 && w == 0) ? av0.z : av0.w;
            const float a1 = (h == 0 && w == 0) ? av1.x : (h == 0 && w == 1) ? av1.y
                           : (h == 1 && w == 0) ? av1.z : av1.w;
            const float a2 = (h == 0 && w == 0) ? av2.x : (h == 0 && w == 1) ? av2.y
                           : (h == 1 && w == 0) ? av2.z : av2.w;
            const float a3 = (h == 0 && w == 0) ? av3.x : (h == 0 && w == 1) ? av3.y
                           : (h == 1 && w == 0) ? av3.z : av3.w;
            size_t dbase = ((size_t)(b * 12 + h * 5 + 1) * 12 + (w * 5 + 1)) * 384 + ch;
            #pragma unroll
            for (int pp = 0; pp < 5; ++pp) {
                #pragma unroll
                for (int q = 0; q < 5; ++q) {
                    const int soff = pp * 5 + q;
                    float s = a0 * Sb[soff] + a1 * Sb[75 + soff]
                            + a2 * Sb[150 + soff] + a3 * Sb[225 + soff];
                    oh[dbase + (size_t)(pp * 12 + q) * 384] = round_bf16(s);
                }
            }
        }
    }
}

// Tap-stationary implicit-GEMM 3x3 conv, pipelined chunk loop.
template<int OC_T, int HOUT, int HPIN, int HPOUT, int STRIDE, int MODE, int NT,
         int NSAMP, int DBUF>
__global__ void __launch_bounds__(256)
conv_mfma5(const short* __restrict__ in_h, const short* __restrict__ wph,
           const float* __restrict__ bias, short* __restrict__ out_h)
{
    constexpr int IC = 384;
    constexpr int NS = 108;
    constexpr int NF = NT / 32;
    constexpr int PIX = HOUT * HOUT;
    constexpr int M_BLK = NSAMP * PIX;
    constexpr int PROWS = NSAMP * HPIN * HPIN;
    constexpr int G = OC_T / NT;
    constexpr int NU = (PROWS * 2 + 255) / 256;
    constexpr int BUFSZ = PROWS * 40;
    __shared__ short s_a[(DBUF ? 2 : 1) * BUFSZ];

    const int swz = xcd_swizzle(blockIdx.x, gridDim.x);
    const int mt = swz / G;
    const int g  = swz % G;
    const int n0 = g * NT;
    const int bb0 = mt * NSAMP;

    const int tid = threadIdx.x;
    const int lane = tid & 63;
    const int wid  = tid >> 6;
    const int wm = (wid & 1) * 64;
    const int wn = (wid >> 1) * (NT / 2);
    const int l15 = lane & 15, kg = lane >> 4;

    size_t usrc[NU]; int udst[NU]; bool uval[NU];
    #pragma unroll
    for (int j = 0; j < NU; ++j) {
        int u = tid + j * 256;
        int row = u >> 1, hf = u & 1;
        uval[j] = row < PROWS;
        int rc = uval[j] ? row : 0;
        int sN = rc / (HPIN * HPIN), rr = rc % (HPIN * HPIN);
        usrc[j] = ((size_t)(bb0 + sN) * (HPIN * HPIN) + rr) * IC + hf * 16;
        udst[j] = rc * 40 + hf * 16;
    }

    int prow[4];
    #pragma unroll
    for (int mf = 0; mf < 4; ++mf) {
        int p = wm + mf * 16 + l15;
        int pc = p < M_BLK ? p : M_BLK - 1;
        int sN = pc / PIX, pr = pc % PIX;
        int py = pr / HOUT, px = pr - py * HOUT;
        prow[mf] = sN * (HPIN * HPIN) + py * STRIDE * HPIN + px * STRIDE;
    }

    const short* wb = wph + (size_t)((n0 + wn) >> 4) * (NS * 512) + lane * 8;

    f32x4 acc[4][NF];
    #pragma unroll
    for (int i = 0; i < 4; ++i)
        #pragma unroll
        for (int j = 0; j < NF; ++j)
            acc[i][j] = (f32x4){0.f, 0.f, 0.f, 0.f};

    bf16x8 sreg[NU][2];
    auto loadG = [&](int c) {
        #pragma unroll
        for (int j = 0; j < NU; ++j) if (uval[j]) {
            const short* src = in_h + usrc[j] + c * 32;
            sreg[j][0] = *(const bf16x8*)src;
            sreg[j][1] = *(const bf16x8*)(src + 8);
        }
    };
    auto writeL = [&](int off) {
        #pragma unroll
        for (int j = 0; j < NU; ++j) if (uval[j]) {
            *(bf16x8*)&s_a[off + udst[j]]     = sreg[j][0];
            *(bf16x8*)&s_a[off + udst[j] + 8] = sreg[j][1];
        }
    };
    auto compute = [&](int c, int off) {
        bf16x8 bcur[NF], bnxt[NF];
        #pragma unroll
        for (int nf = 0; nf < NF; ++nf)
            bcur[nf] = *(const bf16x8*)(wb + (size_t)nf * (NS * 512) + (size_t)c * 512);
        #pragma unroll
        for (int t = 0; t < 9; ++t) {
            if (t < 8) {
                #pragma unroll
                for (int nf = 0; nf < NF; ++nf)
                    bnxt[nf] = *(const bf16x8*)(wb + (size_t)nf * (NS * 512)
                                                + (size_t)((t + 1) * 12 + c) * 512);
            }
            const int troff = (t / 3) * HPIN + (t % 3);
            bf16x8 af[4];
            #pragma unroll
            for (int mf = 0; mf < 4; ++mf)
                af[mf] = *(const bf16x8*)&s_a[off + (prow[mf] + troff) * 40 + kg * 8];
            __builtin_amdgcn_s_setprio(1);
            #pragma unroll
            for (int nf = 0; nf < NF; ++nf)
                #pragma unroll
                for (int mf = 0; mf < 4; ++mf)
                    acc[mf][nf] = __builtin_amdgcn_mfma_f32_16x16x32_bf16(
                        af[mf], bcur[nf], acc[mf][nf], 0, 0, 0);
            __builtin_amdgcn_s_setprio(0);
            #pragma unroll
            for (int nf = 0; nf < NF; ++nf) bcur[nf] = bnxt[nf];
        }
    };

    if (DBUF) {
        loadG(0); writeL(0);
        __syncthreads();
        int buf = 0;
        for (int c = 0; c < 12; ++c) {
            if (c + 1 < 12) loadG(c + 1);
            compute(c, buf * BUFSZ);
            if (c + 1 < 12) writeL((buf ^ 1) * BUFSZ);
            __syncthreads();
            buf ^= 1;
        }
    } else {
        loadG(0);
        for (int c = 0; c < 12; ++c) {
            if (c) __syncthreads();
            writeL(0);
            __syncthreads();
            if (c + 1 < 12) loadG(c + 1);
            compute(c, 0);
        }
    }

    #pragma unroll
    for (int nf = 0; nf < NF; ++nf) {
        const int oc = n0 + wn + nf * 16 + l15;
        const float bv = bias[oc];
        #pragma unroll
        for (int mf = 0; mf < 4; ++mf) {
            #pragma unroll
            for (int j = 0; j < 4; ++j) {
                int p_out = wm + mf * 16 + kg * 4 + j;
                if (p_out < M_BLK) {
                    float v = acc[mf][nf][j] + bv;
                    v = v > 0.f ? v : 0.f;
                    int b2 = bb0 + p_out / PIX;
                    int pr2 = p_out % PIX;
                    if (MODE == 0) {
                        int y2 = pr2 / HOUT, x2 = pr2 - y2 * HOUT;
                        size_t d = ((size_t)(b2 * HPOUT + y2 + 1) * HPOUT + (x2 + 1)) * OC_T + oc;
                        out_h[d] = round_bf16(v);
                    } else {
                        out_h[((size_t)b2 * OC_T + oc) * PIX + pr2] = round_bf16(v);
                    }
                }
            }
        }
    }
}

// Split-K bf16 MFMA GEMM for conv4, single-product. KS=25 -> 16 k-steps.
template<int KS>
__global__ void __launch_bounds__(256)
gemm4_mfma3(const short* __restrict__ Ah, const short* __restrict__ wph,
            float* __restrict__ Cpart, int M)
{
    constexpr int NS4 = 400;
    constexpr int NSTEP = NS4 / KS;             // 16
    __shared__ short s_a[2][128 * 40];
    const int tid = threadIdx.x;
    const int nM = (M + 127) / 128;
    const int ks = blockIdx.x / (nM * 4);
    const int rb = blockIdx.x % (nM * 4);
    const int M0 = (rb / 4) * 128;
    const int n0 = (rb % 4) * 128;

    const int lane = tid & 63;
    const int wid  = tid >> 6;
    const int wm = (wid & 1) * 64;
    const int wn = (wid >> 1) * 64;
    const int l15 = lane & 15, kg = lane >> 4;

    const int arow = tid >> 1, ahf = tid & 1;
    int P = M0 + arow; if (P >= M) P = M - 1;
    const short* abase = Ah + (size_t)P * 12800 + ahf * 16;
    const int adst = arow * 40 + ahf * 16;

    const short* wbh = wph + (size_t)((n0 + wn) >> 4) * (NS4 * 512) + lane * 8;

    f32x4 acc[4][4];
    #pragma unroll
    for (int i = 0; i < 4; ++i)
        #pragma unroll
        for (int j = 0; j < 4; ++j)
            acc[i][j] = (f32x4){0.f, 0.f, 0.f, 0.f};

    auto stageA = [&](int j, int buf) {
        const short* src = abase + (size_t)(ks * NSTEP + j) * 32;
        *(bf16x8*)&s_a[buf][adst]     = *(const bf16x8*)src;
        *(bf16x8*)&s_a[buf][adst + 8] = *(const bf16x8*)(src + 8);
    };
    auto loadB = [&](int j, bf16x8 (&bh)[4]) {
        #pragma unroll
        for (int nf = 0; nf < 4; ++nf)
            bh[nf] = *(const bf16x8*)(wbh + (size_t)nf * (NS4 * 512)
                                      + (size_t)(ks * NSTEP + j) * 512);
    };
    auto compute = [&](const bf16x8 (&bh)[4], int buf) {
        bf16x8 af[4];
        #pragma unroll
        for (int mf = 0; mf < 4; ++mf)
            af[mf] = *(const bf16x8*)&s_a[buf][(wm + mf * 16 + l15) * 40 + kg * 8];
        __builtin_amdgcn_s_setprio(1);
        #pragma unroll
        for (int nf = 0; nf < 4; ++nf)
            #pragma unroll
            for (int mf = 0; mf < 4; ++mf)
                acc[mf][nf] = __builtin_amdgcn_mfma_f32_16x16x32_bf16(
                    af[mf], bh[nf], acc[mf][nf], 0, 0, 0);
        __builtin_amdgcn_s_setprio(0);
    };

    bf16x8 bhA[4], bhB[4];
    stageA(0, 0);
    loadB(0, bhA);
    __syncthreads();
    for (int jp = 0; jp < NSTEP; jp += 2) {
        stageA(jp + 1, 1);
        loadB(jp + 1, bhB);
        compute(bhA, 0);
        __syncthreads();
        if (jp + 2 < NSTEP) { stageA(jp + 2, 0); loadB(jp + 2, bhA); }
        compute(bhB, 1);
        __syncthreads();
    }

    float* cp = Cpart + (size_t)ks * M * 512;
    #pragma unroll
    for (int nf = 0; nf < 4; ++nf) {
        const int n = n0 + wn + nf * 16 + l15;
        #pragma unroll
        for (int mf = 0; mf < 4; ++mf) {
            #pragma unroll
            for (int j = 0; j < 4; ++j) {
                int m = M0 + wm + mf * 16 + kg * 4 + j;
                if (m < M) cp[(size_t)m * 512 + n] = acc[mf][nf][j];
            }
        }
    }
}

template<int KS>
__global__ void splitk_reduce_relu(const float* __restrict__ Cpart,
                                   const float* __restrict__ bias,
                                   float* __restrict__ out, int M, int N)
{
    int idx = blockIdx.x * blockDim.x + threadIdx.x;
    if (idx >= M * N) return;
    int oc = idx % N;
    float s = bias[oc];
    #pragma unroll
    for (int ks = 0; ks < KS; ++ks)
        s += Cpart[(size_t)ks * M * N + idx];
    out[idx] = s > 0.f ? s : 0.f;
}

__global__ void linear_naive(const float* __restrict__ x, const float* __restrict__ Wl,
                             const float* __restrict__ bl,
                             float* __restrict__ out, int total)
{
    int idx = blockIdx.x * blockDim.x + threadIdx.x;
    if (idx >= total) return;
    int b = idx / 10, j = idx - b * 10;
    const float* xb = x  + (size_t)b * 512;
    const float* wj = Wl + (size_t)j * 512;
    float s = bl[j];
    for (int k = 0; k < 512; ++k)
        s += xb[k] * wj[k];
    out[idx] = s;
}

extern "C" void kernel_launch(void* const* d_in, const int* in_sizes, int n_in,
                              void* d_out, int out_size, void* d_ws, size_t ws_size,
                              hipStream_t stream)
{
    const float* A  = (const float*)d_in[0];
    const float* S  = (const float*)d_in[1];
    const float* W1 = (const float*)d_in[2];
    const float* b1 = (const float*)d_in[3];
    const float* W2 = (const float*)d_in[4];
    const float* b2 = (const float*)d_in[5];
    const float* W3 = (const float*)d_in[6];
    const float* b3 = (const float*)d_in[7];
    const float* W4 = (const float*)d_in[8];
    const float* b4 = (const float*)d_in[9];
    const float* Wl = (const float*)d_in[10];
    const float* bl = (const float*)d_in[11];
    float* outp = (float*)d_out;
    char* base = (char*)d_ws;

    const int Btot = 512;
    constexpr int KS = 25;

    const size_t W12N = (size_t)384 * 3456;
    const size_t W3N  = (size_t)512 * 3456;
    const size_t W4N  = (size_t)512 * 12800;
    size_t off = 0;
    short* w1h = (short*)(base + off); off += W12N * 2;
    short* w2h = (short*)(base + off); off += W12N * 2;
    short* w3h = (short*)(base + off); off += W3N * 2;
    short* w4h = (short*)(base + off); off += W4N * 2;
    const size_t wreg = off;

    const size_t PS = 337664;
    int Bc = 512;
    while (Bc > 8 && wreg + (size_t)Bc * PS > ws_size) Bc >>= 1;

    pack_w_frag_h<<<(int)((W12N + 255) / 256), 256, 0, stream>>>(W1, w1h, (int)W12N);
    pack_w_frag_h<<<(int)((W12N + 255) / 256), 256, 0, stream>>>(W2, w2h, (int)W12N);
    pack_w_frag_h<<<(int)((W3N  + 255) / 256), 256, 0, stream>>>(W3, w3h, (int)W3N);
    pack_w4_frag_h<<<(int)((W4N + 255) / 256), 256, 0, stream>>>(W4, w4h, (int)W4N);

    size_t o2 = wreg;
    short* x0h = (short*)(base + o2); o2 += (size_t)Bc * 110592;
    short* x1h = (short*)(base + o2); o2 += (size_t)Bc * 110592;
    short* x2h = (short*)(base + o2); o2 += (size_t)Bc * 37632;
    short* x3h = (short*)(base + o2); o2 += (size_t)Bc * 25600;
    float* cp  = (float*)(base + o2); o2 += (size_t)Bc * (KS * 512 * 4);
    float* x4  = (float*)(base + o2);

    // border-only zeroing of padded planes (interiors rewritten every launch)
    {
        int t0 = Bc * 44 * 48;
        zero_border<12, 384><<<(t0 + 255) / 256, 256, 0, stream>>>(x0h, Bc);
        zero_border<12, 384><<<(t0 + 255) / 256, 256, 0, stream>>>(x1h, Bc);
        int t2 = Bc * 24 * 48;
        zero_border<7, 384><<<(t2 + 255) / 256, 256, 0, stream>>>(x2h, Bc);
    }

    for (int b0 = 0; b0 < Btot; b0 += Bc) {
        einsum_pack3<<<dim3(Bc), 384, 0, stream>>>(
            A + (size_t)b0 * 2048, S + (size_t)b0 * 4800, x0h);

        // conv1: 1 sample/block, NT=128, dbuf (LDS 23 KB), grid Bc*3
        conv_mfma5<384, 10, 12, 12, 1, 0, 128, 1, 1>
            <<<dim3(Bc * 3), 256, 0, stream>>>(x0h, w1h, b1, x1h);

        // conv2: 4 samples/block, NT=64, single-buf + early loads (46 KB)
        conv_mfma5<384, 5, 12, 7, 2, 0, 64, 4, 0>
            <<<dim3((Bc / 4) * 6), 256, 0, stream>>>(x1h, w2h, b2, x2h);

        // conv3: 4 samples/block, NT=128 (G=4), dbuf (31 KB), NCHW out
        conv_mfma5<512, 5, 7, 1, 1, 1, 128, 4, 1>
            <<<dim3((Bc / 4) * 4), 256, 0, stream>>>(x2h, w3h, b3, x3h);

        int nM = (Bc + 127) / 128;
        gemm4_mfma3<KS><<<dim3(KS * nM * 4), 256, 0, stream>>>(
            x3h, w4h, cp, Bc);
        int tr = Bc * 512;
        splitk_reduce_relu<KS><<<(tr + 255) / 256, 256, 0, stream>>>(
            cp, b4, x4, Bc, 512);

        int t5 = Bc * 10;
        linear_naive<<<(t5 + 255) / 256, 256, 0, stream>>>(
            x4, Wl, bl, outp + (size_t)b0 * 10, t5);
    }
}

// Round 18
// 406.271 us; speedup vs baseline: 120.8949x; 1.0523x over previous
//
#include <hip/hip_runtime.h>
#include <hip/hip_bf16.h>

// ---------------------------------------------------------------------------
// Decoder_SICA — ROUND 17: cross-chunk B prefetch, conv2 NT=96, 8x-vectorized
// weight packs. Rest = r16 (verified).
// ---------------------------------------------------------------------------

typedef __attribute__((ext_vector_type(8))) short bf16x8;
typedef __attribute__((ext_vector_type(4))) float f32x4;

__device__ __forceinline__ short round_bf16(float v) {
    __hip_bfloat16 h = __float2bfloat16(v);
    return __builtin_bit_cast(short, h);
}

__device__ __forceinline__ int xcd_swizzle(int bid, int total) {
    int q = total >> 3, r = total & 7;
    int xcd = bid & 7, idx = bid >> 3;
    return (xcd < r ? xcd * (q + 1) : r * (q + 1) + (xcd - r) * q) + idx;
}

// zero only the border cells of padded NHWC planes [Bc][HP][HP][C]
template<int HP, int C>
__global__ void zero_border(short* __restrict__ p, int Bc)
{
    constexpr int NB = 2 * HP + 2 * (HP - 2);
    constexpr int C8 = C / 8;
    int idx = blockIdx.x * blockDim.x + threadIdx.x;
    int total = Bc * NB * C8;
    if (idx >= total) return;
    int c8 = idx % C8;
    int t  = idx / C8;
    int pb = t % NB;
    int b  = t / NB;
    int r, c;
    if (pb < HP)          { r = 0;      c = pb; }
    else if (pb < 2 * HP) { r = HP - 1; c = pb - HP; }
    else { int s = pb - 2 * HP; r = 1 + (s >> 1); c = (s & 1) ? HP - 1 : 0; }
    size_t d = (((size_t)b * HP + r) * HP + c) * C + c8 * 8;
    *(bf16x8*)&p[d] = (bf16x8){0, 0, 0, 0, 0, 0, 0, 0};
}

// W (OC,384,3,3) fp32 -> bf16 frag order [oc/16][s=t*12+ic/32][lane][8], 8/thread
__global__ void pack_w_frag_h8(const float* __restrict__ W,
                               short* __restrict__ wh, int total8)
{
    int idx = blockIdx.x * blockDim.x + threadIdx.x;
    if (idx >= total8) return;
    int oc = idx / 432, r = idx - oc * 432;     // 3456/8 = 432
    int t = r / 48, ic8 = r - t * 48;
    int ic = ic8 * 8;
    bf16x8 out;
    #pragma unroll
    for (int e = 0; e < 8; ++e)
        out[e] = round_bf16(W[((size_t)oc * 384 + ic + e) * 9 + t]);
    int g16 = oc >> 4, l15 = oc & 15;
    int c = ic >> 5, kg = (ic >> 3) & 3;
    size_t d = (((size_t)g16 * 108 + (t * 12 + c)) * 64 + kg * 16 + l15) * 8;
    *(bf16x8*)&wh[d] = out;
}

// W4 (512,12800) fp32 -> bf16 [oc/16][s=k/32][lane][8], 8/thread (float4 reads)
__global__ void pack_w4_frag_h8(const float* __restrict__ W,
                                short* __restrict__ wh, int total8)
{
    int idx = blockIdx.x * blockDim.x + threadIdx.x;
    if (idx >= total8) return;
    int oc = idx / 1600, k8 = idx - oc * 1600;
    int k = k8 * 8;
    const float4 f0 = *(const float4*)&W[(size_t)oc * 12800 + k];
    const float4 f1 = *(const float4*)&W[(size_t)oc * 12800 + k + 4];
    bf16x8 out;
    out[0] = round_bf16(f0.x); out[1] = round_bf16(f0.y);
    out[2] = round_bf16(f0.z); out[3] = round_bf16(f0.w);
    out[4] = round_bf16(f1.x); out[5] = round_bf16(f1.y);
    out[6] = round_bf16(f1.z); out[7] = round_bf16(f1.w);
    int g16 = oc >> 4, l15 = oc & 15;
    int s = k >> 5, kg = (k >> 3) & 3;
    size_t d = (((size_t)g16 * 400 + s) * 64 + kg * 16 + l15) * 8;
    *(bf16x8*)&wh[d] = out;
}

// einsum -> padded NHWC bf16 plane x0[b][12][12][384], interior only.
__global__ void __launch_bounds__(384)
einsum_pack3(const float* __restrict__ A, const float* __restrict__ S,
             short* __restrict__ oh)
{
    __shared__ float sS[4800];
    const int b  = blockIdx.x;
    const int ch = threadIdx.x;

    const float4* S4 = (const float4*)(S + (size_t)b * 4800);
    for (int i = threadIdx.x; i < 1200; i += 384)
        ((float4*)sS)[i] = S4[i];

    const int n = ch / 48, rr = ch - n * 48;
    const int g = rr / 3,  o = rr - g * 3;

    const float4* A4 = (const float4*)(A + (size_t)b * 2048) + (n * 64 + g * 4);
    float4 av0 = A4[0], av1 = A4[1], av2 = A4[2], av3 = A4[3];

    __syncthreads();

    const float* Sb = sS + g * 300 + o * 25;

    #pragma unroll
    for (int h = 0; h < 2; ++h) {
        #pragma unroll
        for (int w = 0; w < 2; ++w) {
            const float a0 = (h == 0 && w == 0) ? av0.x : (h == 0 && w == 1) ? av0.y
                           : (h == 1 && w == 0) ? av0.z : av0.w;
            const float a1 = (h == 0 && w == 0) ? av1.x : (h == 0 && w == 1) ? av1.y
                           : (h == 1 && w == 0) ? av1.z : av1.w;
            const float a2 = (h == 0 && w == 0) ? av2.x : (h == 0 && w == 1) ? av2.y
                           : (h == 1 && w == 0) ? av2.z : av2.w;
            const float a3 = (h == 0 && w == 0) ? av3.x : (h == 0 && w == 1) ? av3.y
                           : (h == 1 && w == 0) ? av3.z : av3.w;
            size_t dbase = ((size_t)(b * 12 + h * 5 + 1) * 12 + (w * 5 + 1)) * 384 + ch;
            #pragma unroll
            for (int pp = 0; pp < 5; ++pp) {
                #pragma unroll
                for (int q = 0; q < 5; ++q) {
                    const int soff = pp * 5 + q;
                    float s = a0 * Sb[soff] + a1 * Sb[75 + soff]
                            + a2 * Sb[150 + soff] + a3 * Sb[225 + soff];
                    oh[dbase + (size_t)(pp * 12 + q) * 384] = round_bf16(s);
                }
            }
        }
    }
}

// Tap-stationary implicit-GEMM 3x3 conv, pipelined chunk loop with
// cross-chunk B prefetch (B pipeline never drains across barriers).
template<int OC_T, int HOUT, int HPIN, int HPOUT, int STRIDE, int MODE, int NT,
         int NSAMP, int DBUF>
__global__ void __launch_bounds__(256)
conv_mfma5(const short* __restrict__ in_h, const short* __restrict__ wph,
           const float* __restrict__ bias, short* __restrict__ out_h)
{
    constexpr int IC = 384;
    constexpr int NS = 108;
    constexpr int NF = NT / 32;
    constexpr int PIX = HOUT * HOUT;
    constexpr int M_BLK = NSAMP * PIX;
    constexpr int PROWS = NSAMP * HPIN * HPIN;
    constexpr int G = OC_T / NT;
    constexpr int NU = (PROWS * 2 + 255) / 256;
    constexpr int BUFSZ = PROWS * 40;
    __shared__ short s_a[(DBUF ? 2 : 1) * BUFSZ];

    const int swz = xcd_swizzle(blockIdx.x, gridDim.x);
    const int mt = swz / G;
    const int g  = swz % G;
    const int n0 = g * NT;
    const int bb0 = mt * NSAMP;

    const int tid = threadIdx.x;
    const int lane = tid & 63;
    const int wid  = tid >> 6;
    const int wm = (wid & 1) * 64;
    const int wn = (wid >> 1) * (NT / 2);
    const int l15 = lane & 15, kg = lane >> 4;

    size_t usrc[NU]; int udst[NU]; bool uval[NU];
    #pragma unroll
    for (int j = 0; j < NU; ++j) {
        int u = tid + j * 256;
        int row = u >> 1, hf = u & 1;
        uval[j] = row < PROWS;
        int rc = uval[j] ? row : 0;
        int sN = rc / (HPIN * HPIN), rr = rc % (HPIN * HPIN);
        usrc[j] = ((size_t)(bb0 + sN) * (HPIN * HPIN) + rr) * IC + hf * 16;
        udst[j] = rc * 40 + hf * 16;
    }

    int prow[4];
    #pragma unroll
    for (int mf = 0; mf < 4; ++mf) {
        int p = wm + mf * 16 + l15;
        int pc = p < M_BLK ? p : M_BLK - 1;
        int sN = pc / PIX, pr = pc % PIX;
        int py = pr / HOUT, px = pr - py * HOUT;
        prow[mf] = sN * (HPIN * HPIN) + py * STRIDE * HPIN + px * STRIDE;
    }

    const short* wb = wph + (size_t)((n0 + wn) >> 4) * (NS * 512) + lane * 8;

    f32x4 acc[4][NF];
    #pragma unroll
    for (int i = 0; i < 4; ++i)
        #pragma unroll
        for (int j = 0; j < NF; ++j)
            acc[i][j] = (f32x4){0.f, 0.f, 0.f, 0.f};

    bf16x8 sreg[NU][2];
    auto loadG = [&](int c) {
        #pragma unroll
        for (int j = 0; j < NU; ++j) if (uval[j]) {
            const short* src = in_h + usrc[j] + c * 32;
            sreg[j][0] = *(const bf16x8*)src;
            sreg[j][1] = *(const bf16x8*)(src + 8);
        }
    };
    auto writeL = [&](int off) {
        #pragma unroll
        for (int j = 0; j < NU; ++j) if (uval[j]) {
            *(bf16x8*)&s_a[off + udst[j]]     = sreg[j][0];
            *(bf16x8*)&s_a[off + udst[j] + 8] = sreg[j][1];
        }
    };
    auto loadB = [&](int s, bf16x8 (&bh)[NF]) {
        #pragma unroll
        for (int nf = 0; nf < NF; ++nf)
            bh[nf] = *(const bf16x8*)(wb + (size_t)nf * (NS * 512) + (size_t)s * 512);
    };
    // bcur must be pre-loaded with tap-0 of chunk c before calling.
    auto compute = [&](int c, int off, bf16x8 (&bcur)[NF]) {
        bf16x8 bnxt[NF];
        #pragma unroll
        for (int t = 0; t < 9; ++t) {
            // prefetch next tap; at t=8 prefetch tap-0 of chunk c+1
            const int sn = (t < 8) ? ((t + 1) * 12 + c) : (c < 11 ? (c + 1) : 0);
            loadB(sn, bnxt);
            const int troff = (t / 3) * HPIN + (t % 3);
            bf16x8 af[4];
            #pragma unroll
            for (int mf = 0; mf < 4; ++mf)
                af[mf] = *(const bf16x8*)&s_a[off + (prow[mf] + troff) * 40 + kg * 8];
            __builtin_amdgcn_s_setprio(1);
            #pragma unroll
            for (int nf = 0; nf < NF; ++nf)
                #pragma unroll
                for (int mf = 0; mf < 4; ++mf)
                    acc[mf][nf] = __builtin_amdgcn_mfma_f32_16x16x32_bf16(
                        af[mf], bcur[nf], acc[mf][nf], 0, 0, 0);
            __builtin_amdgcn_s_setprio(0);
            #pragma unroll
            for (int nf = 0; nf < NF; ++nf) bcur[nf] = bnxt[nf];
        }
    };

    bf16x8 bpipe[NF];
    loadB(0, bpipe);                             // tap-0, chunk-0

    if (DBUF) {
        loadG(0); writeL(0);
        __syncthreads();
        int buf = 0;
        for (int c = 0; c < 12; ++c) {
            if (c + 1 < 12) loadG(c + 1);
            compute(c, buf * BUFSZ, bpipe);
            if (c + 1 < 12) writeL((buf ^ 1) * BUFSZ);
            __syncthreads();
            buf ^= 1;
        }
    } else {
        loadG(0);
        for (int c = 0; c < 12; ++c) {
            if (c) __syncthreads();
            writeL(0);
            __syncthreads();
            if (c + 1 < 12) loadG(c + 1);
            compute(c, 0, bpipe);
        }
    }

    #pragma unroll
    for (int nf = 0; nf < NF; ++nf) {
        const int oc = n0 + wn + nf * 16 + l15;
        const float bv = bias[oc];
        #pragma unroll
        for (int mf = 0; mf < 4; ++mf) {
            #pragma unroll
            for (int j = 0; j < 4; ++j) {
                int p_out = wm + mf * 16 + kg * 4 + j;
                if (p_out < M_BLK) {
                    float v = acc[mf][nf][j] + bv;
                    v = v > 0.f ? v : 0.f;
                    int b2 = bb0 + p_out / PIX;
                    int pr2 = p_out % PIX;
                    if (MODE == 0) {
                        int y2 = pr2 / HOUT, x2 = pr2 - y2 * HOUT;
                        size_t d = ((size_t)(b2 * HPOUT + y2 + 1) * HPOUT + (x2 + 1)) * OC_T + oc;
                        out_h[d] = round_bf16(v);
                    } else {
                        out_h[((size_t)b2 * OC_T + oc) * PIX + pr2] = round_bf16(v);
                    }
                }
            }
        }
    }
}

// Split-K bf16 MFMA GEMM for conv4, single-product. KS=25 -> 16 k-steps.
template<int KS>
__global__ void __launch_bounds__(256)
gemm4_mfma3(const short* __restrict__ Ah, const short* __restrict__ wph,
            float* __restrict__ Cpart, int M)
{
    constexpr int NS4 = 400;
    constexpr int NSTEP = NS4 / KS;             // 16
    __shared__ short s_a[2][128 * 40];
    const int tid = threadIdx.x;
    const int nM = (M + 127) / 128;
    const int ks = blockIdx.x / (nM * 4);
    const int rb = blockIdx.x % (nM * 4);
    const int M0 = (rb / 4) * 128;
    const int n0 = (rb % 4) * 128;

    const int lane = tid & 63;
    const int wid  = tid >> 6;
    const int wm = (wid & 1) * 64;
    const int wn = (wid >> 1) * 64;
    const int l15 = lane & 15, kg = lane >> 4;

    const int arow = tid >> 1, ahf = tid & 1;
    int P = M0 + arow; if (P >= M) P = M - 1;
    const short* abase = Ah + (size_t)P * 12800 + ahf * 16;
    const int adst = arow * 40 + ahf * 16;

    const short* wbh = wph + (size_t)((n0 + wn) >> 4) * (NS4 * 512) + lane * 8;

    f32x4 acc[4][4];
    #pragma unroll
    for (int i = 0; i < 4; ++i)
        #pragma unroll
        for (int j = 0; j < 4; ++j)
            acc[i][j] = (f32x4){0.f, 0.f, 0.f, 0.f};

    auto stageA = [&](int j, int buf) {
        const short* src = abase + (size_t)(ks * NSTEP + j) * 32;
        *(bf16x8*)&s_a[buf][adst]     = *(const bf16x8*)src;
        *(bf16x8*)&s_a[buf][adst + 8] = *(const bf16x8*)(src + 8);
    };
    auto loadB = [&](int j, bf16x8 (&bh)[4]) {
        #pragma unroll
        for (int nf = 0; nf < 4; ++nf)
            bh[nf] = *(const bf16x8*)(wbh + (size_t)nf * (NS4 * 512)
                                      + (size_t)(ks * NSTEP + j) * 512);
    };
    auto compute = [&](const bf16x8 (&bh)[4], int buf) {
        bf16x8 af[4];
        #pragma unroll
        for (int mf = 0; mf < 4; ++mf)
            af[mf] = *(const bf16x8*)&s_a[buf][(wm + mf * 16 + l15) * 40 + kg * 8];
        __builtin_amdgcn_s_setprio(1);
        #pragma unroll
        for (int nf = 0; nf < 4; ++nf)
            #pragma unroll
            for (int mf = 0; mf < 4; ++mf)
                acc[mf][nf] = __builtin_amdgcn_mfma_f32_16x16x32_bf16(
                    af[mf], bh[nf], acc[mf][nf], 0, 0, 0);
        __builtin_amdgcn_s_setprio(0);
    };

    bf16x8 bhA[4], bhB[4];
    stageA(0, 0);
    loadB(0, bhA);
    __syncthreads();
    for (int jp = 0; jp < NSTEP; jp += 2) {
        stageA(jp + 1, 1);
        loadB(jp + 1, bhB);
        compute(bhA, 0);
        __syncthreads();
        if (jp + 2 < NSTEP) { stageA(jp + 2, 0); loadB(jp + 2, bhA); }
        compute(bhB, 1);
        __syncthreads();
    }

    float* cp = Cpart + (size_t)ks * M * 512;
    #pragma unroll
    for (int nf = 0; nf < 4; ++nf) {
        const int n = n0 + wn + nf * 16 + l15;
        #pragma unroll
        for (int mf = 0; mf < 4; ++mf) {
            #pragma unroll
            for (int j = 0; j < 4; ++j) {
                int m = M0 + wm + mf * 16 + kg * 4 + j;
                if (m < M) cp[(size_t)m * 512 + n] = acc[mf][nf][j];
            }
        }
    }
}

template<int KS>
__global__ void splitk_reduce_relu(const float* __restrict__ Cpart,
                                   const float* __restrict__ bias,
                                   float* __restrict__ out, int M, int N)
{
    int idx = blockIdx.x * blockDim.x + threadIdx.x;
    if (idx >= M * N) return;
    int oc = idx % N;
    float s = bias[oc];
    #pragma unroll
    for (int ks = 0; ks < KS; ++ks)
        s += Cpart[(size_t)ks * M * N + idx];
    out[idx] = s > 0.f ? s : 0.f;
}

__global__ void linear_naive(const float* __restrict__ x, const float* __restrict__ Wl,
                             const float* __restrict__ bl,
                             float* __restrict__ out, int total)
{
    int idx = blockIdx.x * blockDim.x + threadIdx.x;
    if (idx >= total) return;
    int b = idx / 10, j = idx - b * 10;
    const float* xb = x  + (size_t)b * 512;
    const float* wj = Wl + (size_t)j * 512;
    float s = bl[j];
    for (int k = 0; k < 512; ++k)
        s += xb[k] * wj[k];
    out[idx] = s;
}

extern "C" void kernel_launch(void* const* d_in, const int* in_sizes, int n_in,
                              void* d_out, int out_size, void* d_ws, size_t ws_size,
                              hipStream_t stream)
{
    const float* A  = (const float*)d_in[0];
    const float* S  = (const float*)d_in[1];
    const float* W1 = (const float*)d_in[2];
    const float* b1 = (const float*)d_in[3];
    const float* W2 = (const float*)d_in[4];
    const float* b2 = (const float*)d_in[5];
    const float* W3 = (const float*)d_in[6];
    const float* b3 = (const float*)d_in[7];
    const float* W4 = (const float*)d_in[8];
    const float* b4 = (const float*)d_in[9];
    const float* Wl = (const float*)d_in[10];
    const float* bl = (const float*)d_in[11];
    float* outp = (float*)d_out;
    char* base = (char*)d_ws;

    const int Btot = 512;
    constexpr int KS = 25;

    const size_t W12N = (size_t)384 * 3456;
    const size_t W3N  = (size_t)512 * 3456;
    const size_t W4N  = (size_t)512 * 12800;
    size_t off = 0;
    short* w1h = (short*)(base + off); off += W12N * 2;
    short* w2h = (short*)(base + off); off += W12N * 2;
    short* w3h = (short*)(base + off); off += W3N * 2;
    short* w4h = (short*)(base + off); off += W4N * 2;
    const size_t wreg = off;

    const size_t PS = 337664;
    int Bc = 512;
    while (Bc > 8 && wreg + (size_t)Bc * PS > ws_size) Bc >>= 1;

    pack_w_frag_h8<<<(int)((W12N / 8 + 255) / 256), 256, 0, stream>>>(W1, w1h, (int)(W12N / 8));
    pack_w_frag_h8<<<(int)((W12N / 8 + 255) / 256), 256, 0, stream>>>(W2, w2h, (int)(W12N / 8));
    pack_w_frag_h8<<<(int)((W3N  / 8 + 255) / 256), 256, 0, stream>>>(W3, w3h, (int)(W3N / 8));
    pack_w4_frag_h8<<<(int)((W4N / 8 + 255) / 256), 256, 0, stream>>>(W4, w4h, (int)(W4N / 8));

    size_t o2 = wreg;
    short* x0h = (short*)(base + o2); o2 += (size_t)Bc * 110592;
    short* x1h = (short*)(base + o2); o2 += (size_t)Bc * 110592;
    short* x2h = (short*)(base + o2); o2 += (size_t)Bc * 37632;
    short* x3h = (short*)(base + o2); o2 += (size_t)Bc * 25600;
    float* cp  = (float*)(base + o2); o2 += (size_t)Bc * (KS * 512 * 4);
    float* x4  = (float*)(base + o2);

    // border-only zeroing of padded planes (interiors rewritten every launch)
    {
        int t0 = Bc * 44 * 48;
        zero_border<12, 384><<<(t0 + 255) / 256, 256, 0, stream>>>(x0h, Bc);
        zero_border<12, 384><<<(t0 + 255) / 256, 256, 0, stream>>>(x1h, Bc);
        int t2 = Bc * 24 * 48;
        zero_border<7, 384><<<(t2 + 255) / 256, 256, 0, stream>>>(x2h, Bc);
    }

    for (int b0 = 0; b0 < Btot; b0 += Bc) {
        einsum_pack3<<<dim3(Bc), 384, 0, stream>>>(
            A + (size_t)b0 * 2048, S + (size_t)b0 * 4800, x0h);

        // conv1: 1 sample/block, NT=128, dbuf (LDS 23 KB), grid Bc*3
        conv_mfma5<384, 10, 12, 12, 1, 0, 128, 1, 1>
            <<<dim3(Bc * 3), 256, 0, stream>>>(x0h, w1h, b1, x1h);

        // conv2: 4 samples/block, NT=96 (G=4, NF=3), single-buf (46 KB)
        conv_mfma5<384, 5, 12, 7, 2, 0, 96, 4, 0>
            <<<dim3((Bc / 4) * 4), 256, 0, stream>>>(x1h, w2h, b2, x2h);

        // conv3: 4 samples/block, NT=128 (G=4), dbuf (31 KB), NCHW out
        conv_mfma5<512, 5, 7, 1, 1, 1, 128, 4, 1>
            <<<dim3((Bc / 4) * 4), 256, 0, stream>>>(x2h, w3h, b3, x3h);

        int nM = (Bc + 127) / 128;
        gemm4_mfma3<KS><<<dim3(KS * nM * 4), 256, 0, stream>>>(
            x3h, w4h, cp, Bc);
        int tr = Bc * 512;
        splitk_reduce_relu<KS><<<(tr + 255) / 256, 256, 0, stream>>>(
            cp, b4, x4, Bc, 512);

        int t5 = Bc * 10;
        linear_naive<<<(t5 + 255) / 256, 256, 0, stream>>>(
            x4, Wl, bl, outp + (size_t)b0 * 10, t5);
    }
}